// Round 1
// baseline (940.277 us; speedup 1.0000x reference)
//
#include <hip/hip_runtime.h>

// Problem constants
constexpr int B_  = 8;
constexpr int C_  = 512;
constexpr int T_  = 1024;   // H*W
constexpr int S_  = 1024;
constexpr int D_  = 512;
constexpr int NH_ = 8;
constexpr int HD_ = 64;
constexpr int BT_ = B_ * T_;   // 8192
constexpr float LAMBDA_GEO_ = 8.0f;
constexpr float COMPAT_MUL_ = 0.0125f;   // COMPAT_SCALE / sqrt(HD) = 0.1/8

// ---------------------------------------------------------------------------
// mask handling: harness may deliver the jax bool mask as int32 / float32 /
// raw bytes. Detect once per launch on device, branch all readers on mode.
__device__ __forceinline__ int is_valid(const void* mask, int mode, int idx) {
    if (mode == 0) return ((const int*)mask)[idx] != 0;
    if (mode == 1) return ((const float*)mask)[idx] != 0.0f;
    return ((const unsigned char*)mask)[idx] != 0;
}

__global__ void mode_k(const unsigned int* __restrict__ m, int nwords,
                       int* __restrict__ mode, float* __restrict__ scal) {
    __shared__ int bad_i, bad_f;
    if (threadIdx.x == 0) { bad_i = 0; bad_f = 0; }
    __syncthreads();
    for (int i = threadIdx.x; i < nwords; i += 256) {
        unsigned v = m[i];
        if (v > 1u) bad_i = 1;                          // not {0,1} ints
        if (v != 0u && v != 0x3f800000u) bad_f = 1;     // not {0.0f,1.0f}
    }
    __syncthreads();
    if (threadIdx.x == 0) {
        *mode = (!bad_i) ? 0 : ((!bad_f) ? 1 : 2);
        scal[0] = 0.0f; scal[1] = 0.0f;   // zero loss accumulators each call
    }
}

// ---------------------------------------------------------------------------
// front_feat (B,C,T) -> front_flat (B*T, C)
__global__ __launch_bounds__(256) void front_transpose_k(const float* __restrict__ in,
                                                         float* __restrict__ out) {
    __shared__ float tile[32][33];
    int t0 = blockIdx.x * 32, c0 = blockIdx.y * 32, b = blockIdx.z;
    int tx = threadIdx.x & 31, ty = threadIdx.x >> 5;
    const float* ip = in + (size_t)b * C_ * T_;
    for (int i = ty; i < 32; i += 8)
        tile[i][tx] = ip[(size_t)(c0 + i) * T_ + t0 + tx];
    __syncthreads();
    float* op = out + (size_t)b * T_ * C_;
    for (int i = ty; i < 32; i += 8)
        op[(size_t)(t0 + i) * C_ + c0 + tx] = tile[tx][i];
}

// ---------------------------------------------------------------------------
// Generic fp32 GEMM: C[M,N] = A[M,K] @ B[K,N] + bias (+ addend). BM=128 BN=64 BK=16.
template <bool ADD>
__global__ __launch_bounds__(256) void gemm_k(const float* __restrict__ A,
                                              const float* __restrict__ Bw,
                                              const float* __restrict__ bias,
                                              const float* __restrict__ addend,
                                              float* __restrict__ Cout,
                                              int M, int N, int K) {
    __shared__ float As[16][132];
    __shared__ float Bs[16][68];
    int tid = threadIdx.x;
    int m0 = blockIdx.x * 128, n0 = blockIdx.y * 64;
    int tm = tid >> 4, tn = tid & 15;
    int ar = tid >> 1, ac = (tid & 1) * 8;
    int br = tid >> 4, bc = (tid & 15) * 4;
    float acc[8][4] = {};
    for (int k0 = 0; k0 < K; k0 += 16) {
        float4 a0 = *(const float4*)(A + (size_t)(m0 + ar) * K + k0 + ac);
        float4 a1 = *(const float4*)(A + (size_t)(m0 + ar) * K + k0 + ac + 4);
        float4 bv = *(const float4*)(Bw + (size_t)(k0 + br) * N + n0 + bc);
        As[ac + 0][ar] = a0.x; As[ac + 1][ar] = a0.y;
        As[ac + 2][ar] = a0.z; As[ac + 3][ar] = a0.w;
        As[ac + 4][ar] = a1.x; As[ac + 5][ar] = a1.y;
        As[ac + 6][ar] = a1.z; As[ac + 7][ar] = a1.w;
        *(float4*)&Bs[br][bc] = bv;
        __syncthreads();
#pragma unroll
        for (int kk = 0; kk < 16; ++kk) {
            float4 aa0 = *(const float4*)&As[kk][tm * 8];
            float4 aa1 = *(const float4*)&As[kk][tm * 8 + 4];
            float4 bb  = *(const float4*)&Bs[kk][tn * 4];
            float a_[8] = {aa0.x, aa0.y, aa0.z, aa0.w, aa1.x, aa1.y, aa1.z, aa1.w};
            float b_[4] = {bb.x, bb.y, bb.z, bb.w};
#pragma unroll
            for (int i = 0; i < 8; ++i)
#pragma unroll
                for (int j = 0; j < 4; ++j)
                    acc[i][j] += a_[i] * b_[j];
        }
        __syncthreads();
    }
#pragma unroll
    for (int i = 0; i < 8; ++i) {
        int row = m0 + tm * 8 + i;
        float* crow = Cout + (size_t)row * N + n0 + tn * 4;
#pragma unroll
        for (int j = 0; j < 4; ++j) {
            float v = acc[i][j] + bias[n0 + tn * 4 + j];
            if constexpr (ADD) v += addend[(size_t)row * N + n0 + tn * 4 + j];
            crow[j] = v;
        }
    }
}

// ---------------------------------------------------------------------------
// In-place LayerNorm over rows of 512
__global__ __launch_bounds__(256) void ln_k(float* __restrict__ X,
                                            const float* __restrict__ g,
                                            const float* __restrict__ bv) {
    int row = blockIdx.x, tid = threadIdx.x;
    float* xr = X + (size_t)row * D_;
    float x0 = xr[tid], x1 = xr[tid + 256];
    float s = x0 + x1, sq = x0 * x0 + x1 * x1;
    __shared__ float rs[4], rq[4];
    for (int o = 32; o; o >>= 1) { s += __shfl_down(s, o); sq += __shfl_down(sq, o); }
    int wid = tid >> 6, lane = tid & 63;
    if (lane == 0) { rs[wid] = s; rq[wid] = sq; }
    __syncthreads();
    if (tid == 0) {
        float ts = 0, tq = 0;
        for (int w = 0; w < 4; ++w) { ts += rs[w]; tq += rq[w]; }
        rs[0] = ts; rq[0] = tq;
    }
    __syncthreads();
    float mean = rs[0] * (1.0f / D_);
    float var  = rq[0] * (1.0f / D_) - mean * mean;
    float r = rsqrtf(var + 1e-5f);
    xr[tid]       = (x0 - mean) * r * g[tid] + bv[tid];
    xr[tid + 256] = (x1 - mean) * r * g[tid + 256] + bv[tid + 256];
}

// ---------------------------------------------------------------------------
// plucker hidden: silu(plucker @ pl_w1 + pl_b1)  (K=6)
__global__ __launch_bounds__(256) void plh_k(const float* __restrict__ pl,
                                             const float* __restrict__ w1,
                                             const float* __restrict__ b1,
                                             float* __restrict__ out) {
    int m = blockIdx.x;
    int n = blockIdx.y * 256 + threadIdx.x;
    const float* p = pl + (size_t)m * 6;
    float acc = b1[n];
#pragma unroll
    for (int j = 0; j < 6; ++j) acc += p[j] * w1[j * D_ + n];
    out[(size_t)m * D_ + n] = acc / (1.0f + __expf(-acc));
}

// sigma head: 0.03 + 0.32*sigmoid(ctx . sig_w + sig_b). One wave per row.
__global__ __launch_bounds__(256) void sigma_k(const float* __restrict__ ctx,
                                               const float* __restrict__ w,
                                               const float* __restrict__ bb,
                                               float* __restrict__ sig) {
    int wid = threadIdx.x >> 6, lane = threadIdx.x & 63;
    int row = blockIdx.x * 4 + wid;
    const float* xr = ctx + (size_t)row * D_;
    float acc = 0;
#pragma unroll
    for (int i = 0; i < 8; ++i) { int c = i * 64 + lane; acc += xr[c] * w[c]; }
    for (int o = 32; o; o >>= 1) acc += __shfl_down(acc, o);
    if (lane == 0) {
        float z = acc + bb[0];
        sig[row] = 0.03f + 0.32f / (1.0f + __expf(-z));
    }
}

// dustbin head: ctx @ db_w + db_b -> (row, 8). One wave per row.
__global__ __launch_bounds__(256) void db_k(const float* __restrict__ ctx,
                                            const float* __restrict__ w,
                                            const float* __restrict__ bb,
                                            float* __restrict__ dbo) {
    int wid = threadIdx.x >> 6, lane = threadIdx.x & 63;
    int row = blockIdx.x * 4 + wid;
    const float* xr = ctx + (size_t)row * D_;
    float p_[8] = {};
#pragma unroll
    for (int i = 0; i < 8; ++i) {
        int c = i * 64 + lane;
        float x = xr[c];
        const float* wr = w + (size_t)c * NH_;
#pragma unroll
        for (int h = 0; h < 8; ++h) p_[h] += x * wr[h];
    }
#pragma unroll
    for (int h = 0; h < 8; ++h) {
        float v = p_[h];
        for (int o = 32; o; o >>= 1) v += __shfl_down(v, o);
        if (lane == 0) dbo[(size_t)row * NH_ + h] = v + bb[h];
    }
}

// ---------------------------------------------------------------------------
// Fused attention: per block (b, h, 32 q-tokens); online softmax over S chunks
// of 32 with dustbin logit as the initial (m=db, l=1) state.
__global__ __launch_bounds__(256) void attn_k(
    const float* __restrict__ Q, const float* __restrict__ Km, const float* __restrict__ V,
    const float* __restrict__ sig, const float* __restrict__ dbl_in,
    const float* __restrict__ bev_xy, const float* __restrict__ sat_xy,
    const void* __restrict__ mask, const int* __restrict__ mode,
    float* __restrict__ readout, float* __restrict__ dbp) {
    int t0 = blockIdx.x * 32;
    int h  = blockIdx.y;
    int b  = blockIdx.z;
    int tid = threadIdx.x;

    __shared__ float qs[32][68];
    __shared__ float ks[32][68];
    __shared__ float vs[32][68];
    __shared__ float ptile[32][33];
    __shared__ float mrow[32], lrow[32], srow[32], grow[32];
    __shared__ float bx[32], by[32], dbrow[32], vldrow[32];
    __shared__ float sx[32], sy[32];

    int md = *mode;
    int tt = tid >> 3;   // owned q-row (0..31) in both phases
    int sq = tid & 7;

    {   // load q tile
        const float* src = Q + (((size_t)b * T_ + t0 + tt) * D_ + h * HD_ + sq * 8);
        float4 a0 = *(const float4*)src;
        float4 a1 = *(const float4*)(src + 4);
        *(float4*)&qs[tt][sq * 8]     = a0;
        *(float4*)&qs[tt][sq * 8 + 4] = a1;
    }
    if (tid < 32) {
        int t = tid;
        int row = b * T_ + t0 + t;
        float s_ = sig[row];
        grow[t] = -LAMBDA_GEO_ / fmaxf(s_ * s_, 1e-6f);
        bx[t] = bev_xy[(size_t)row * 2 + 0];
        by[t] = bev_xy[(size_t)row * 2 + 1];
        float dbv = dbl_in[(size_t)row * NH_ + h];
        dbrow[t] = dbv;
        mrow[t] = dbv;
        lrow[t] = 1.0f;
        vldrow[t] = is_valid(mask, md, row) ? 1.0f : 0.0f;
    }
    float acc[8] = {};
    __syncthreads();

    for (int s0 = 0; s0 < S_; s0 += 32) {
        {   // stage K/V chunk + sat_xy
            const float* ksrc = Km + (((size_t)b * S_ + s0 + tt) * D_ + h * HD_ + sq * 8);
            const float* vsrc = V  + (((size_t)b * S_ + s0 + tt) * D_ + h * HD_ + sq * 8);
            float4 k0 = *(const float4*)ksrc; float4 k1 = *(const float4*)(ksrc + 4);
            float4 v0 = *(const float4*)vsrc; float4 v1 = *(const float4*)(vsrc + 4);
            *(float4*)&ks[tt][sq * 8]     = k0; *(float4*)&ks[tt][sq * 8 + 4] = k1;
            *(float4*)&vs[tt][sq * 8]     = v0; *(float4*)&vs[tt][sq * 8 + 4] = v1;
        }
        if (tid < 32) {
            sx[tid] = sat_xy[((size_t)b * S_ + s0 + tid) * 2 + 0];
            sy[tid] = sat_xy[((size_t)b * S_ + s0 + tid) * 2 + 1];
        }
        __syncthreads();

        // logits for 4 s-values: s = sq + 8r  (stride-8 keeps LDS banks spread)
        float lg[4];
#pragma unroll
        for (int r = 0; r < 4; ++r) {
            int s = sq + 8 * r;
            float4 av = {0, 0, 0, 0};
#pragma unroll
            for (int di = 0; di < 16; ++di) {
                float4 qv = *(const float4*)&qs[tt][di * 4];
                float4 kv = *(const float4*)&ks[s][di * 4];
                av.x += qv.x * kv.x; av.y += qv.y * kv.y;
                av.z += qv.z * kv.z; av.w += qv.w * kv.w;
            }
            float dot = av.x + av.y + av.z + av.w;
            float dx = bx[tt] - sx[s], dy = by[tt] - sy[s];
            float lgv = dot * COMPAT_MUL_ + grow[tt] * (dx * dx + dy * dy);
            lg[r] = (vldrow[tt] != 0.0f) ? lgv : -10000.0f;
        }
        float cmax = fmaxf(fmaxf(lg[0], lg[1]), fmaxf(lg[2], lg[3]));
        for (int o = 1; o < 8; o <<= 1) cmax = fmaxf(cmax, __shfl_xor(cmax, o));
        float m_old = mrow[tt];
        float m_new = fmaxf(m_old, cmax);
        float p[4], psum = 0;
#pragma unroll
        for (int r = 0; r < 4; ++r) { p[r] = __expf(lg[r] - m_new); psum += p[r]; }
        for (int o = 1; o < 8; o <<= 1) psum += __shfl_xor(psum, o);
        float scl = __expf(m_old - m_new);
        if (sq == 0) { mrow[tt] = m_new; lrow[tt] = lrow[tt] * scl + psum; srow[tt] = scl; }
#pragma unroll
        for (int r = 0; r < 4; ++r) ptile[tt][sq + 8 * r] = p[r];
        __syncthreads();

        // accumulate read: acc[d] = acc[d]*scale + sum_s p[t][s]*v[s][d]
        float scl2 = srow[tt];
#pragma unroll
        for (int j = 0; j < 8; ++j) acc[j] *= scl2;
#pragma unroll
        for (int s = 0; s < 32; ++s) {
            float pv = ptile[tt][s];
            float4 v0 = *(const float4*)&vs[s][sq * 8];
            float4 v1 = *(const float4*)&vs[s][sq * 8 + 4];
            acc[0] += pv * v0.x; acc[1] += pv * v0.y;
            acc[2] += pv * v0.z; acc[3] += pv * v0.w;
            acc[4] += pv * v1.x; acc[5] += pv * v1.y;
            acc[6] += pv * v1.z; acc[7] += pv * v1.w;
        }
        __syncthreads();
    }

    float linv = 1.0f / lrow[tt];
    float* dst = readout + (((size_t)b * T_ + t0 + tt) * D_ + h * HD_ + sq * 8);
#pragma unroll
    for (int j = 0; j < 8; ++j) dst[j] = acc[j] * linv;
    if (tid < 32) {
        int t = tid;
        dbp[((size_t)(b * T_ + t0 + t)) * NH_ + h] = __expf(dbrow[t] - mrow[t]) / lrow[t];
    }
}

// ---------------------------------------------------------------------------
// confidence + invalid-loss partials
__global__ __launch_bounds__(256) void conf_k(const float* __restrict__ dbp,
                                              const void* __restrict__ mask,
                                              const int* __restrict__ mode,
                                              float* __restrict__ confout,
                                              float* __restrict__ scal) {
    int row = blockIdx.x * 256 + threadIdx.x;
    const float* dr = dbp + (size_t)row * NH_;
    float s = 0;
#pragma unroll
    for (int h = 0; h < 8; ++h) s += dr[h];
    float cf = 1.0f - s * (1.0f / NH_);
    confout[row] = cf;
    int md = *mode;
    float inv = is_valid(mask, md, row) ? 0.0f : 1.0f;
    float a = cf * inv, bs = inv;
    __shared__ float ra[4], rb[4];
    for (int o = 32; o; o >>= 1) { a += __shfl_down(a, o); bs += __shfl_down(bs, o); }
    int wid = threadIdx.x >> 6, lane = threadIdx.x & 63;
    if (lane == 0) { ra[wid] = a; rb[wid] = bs; }
    __syncthreads();
    if (threadIdx.x == 0) {
        float ta = 0, tb = 0;
        for (int w = 0; w < 4; ++w) { ta += ra[w]; tb += rb[w]; }
        atomicAdd(&scal[0], ta);
        atomicAdd(&scal[1], tb);
    }
}

// final epilogue: transpose RF (B,T,C)->(B,C,T); out0 = ff + conf*rf; out1 = rf
__global__ __launch_bounds__(256) void final_k(const float* __restrict__ ff,
                                               const float* __restrict__ RF,
                                               const float* __restrict__ conf,
                                               float* __restrict__ out0,
                                               float* __restrict__ out1) {
    __shared__ float tile[32][33];
    int t0 = blockIdx.x * 32, c0 = blockIdx.y * 32, b = blockIdx.z;
    int tx = threadIdx.x & 31, ty = threadIdx.x >> 5;
    for (int j = ty; j < 32; j += 8)
        tile[j][tx] = RF[((size_t)b * T_ + t0 + j) * C_ + c0 + tx];
    __syncthreads();
    size_t base = (size_t)b * C_ * T_;
    float cf = conf[b * T_ + t0 + tx];
    for (int i = ty; i < 32; i += 8) {
        size_t idx = base + (size_t)(c0 + i) * T_ + t0 + tx;
        float rf = tile[tx][i];
        out1[idx] = rf;
        out0[idx] = ff[idx] + cf * rf;
    }
}

__global__ void loss_k(const float* __restrict__ scal, float* __restrict__ out) {
    out[0] = scal[0] / fmaxf(scal[1], 1.0f) * 0.05f;
}

// ---------------------------------------------------------------------------
extern "C" void kernel_launch(void* const* d_in, const int* in_sizes, int n_in,
                              void* d_out, int out_size, void* d_ws, size_t ws_size,
                              hipStream_t stream) {
    const float* front_feat = (const float*)d_in[0];
    const float* sat_tokens = (const float*)d_in[1];
    const float* sat_xy     = (const float*)d_in[2];
    const float* bev_xy     = (const float*)d_in[3];
    const void*  mask       = d_in[4];
    const float* plucker    = (const float*)d_in[5];
    const float* fa_w = (const float*)d_in[6];
    const float* fa_b = (const float*)d_in[7];
    const float* fa_g = (const float*)d_in[8];
    const float* fa_lb = (const float*)d_in[9];
    const float* sa_w = (const float*)d_in[10];
    const float* sa_b = (const float*)d_in[11];
    const float* sa_g = (const float*)d_in[12];
    const float* sa_lb = (const float*)d_in[13];
    const float* q_w = (const float*)d_in[14];
    const float* q_b = (const float*)d_in[15];
    const float* k_w = (const float*)d_in[16];
    const float* k_b = (const float*)d_in[17];
    const float* v_w = (const float*)d_in[18];
    const float* v_b = (const float*)d_in[19];
    const float* pl_w1 = (const float*)d_in[20];
    const float* pl_b1 = (const float*)d_in[21];
    const float* pl_w2 = (const float*)d_in[22];
    const float* pl_b2 = (const float*)d_in[23];
    const float* sig_w = (const float*)d_in[24];
    const float* sig_b = (const float*)d_in[25];
    const float* db_w = (const float*)d_in[26];
    const float* db_b = (const float*)d_in[27];
    const float* out_w = (const float*)d_in[28];
    const float* out_b = (const float*)d_in[29];

    const size_t SLOT = (size_t)BT_ * D_;    // 4,194,304 floats
    float* ws = (float*)d_ws;
    float* s0 = ws;
    float* s1 = ws + SLOT;
    float* s2 = ws + 2 * SLOT;
    float* s3 = ws + 3 * SLOT;
    float* w_sigma = ws + 4 * SLOT;                        // BT_
    float* w_db    = w_sigma + BT_;                        // BT_*NH_
    float* w_dbp   = w_db + (size_t)BT_ * NH_;             // BT_*NH_
    float* w_scal  = w_dbp + (size_t)BT_ * NH_;            // 2 floats
    int*   w_mode  = (int*)(w_scal + 2);

    float* out0 = (float*)d_out;                       // front_feat_out
    float* out1 = out0 + (size_t)B_ * C_ * T_;         // read_feat
    float* outc = out1 + (size_t)B_ * C_ * T_;         // confidence (B,T)
    float* outl = outc + (size_t)B_ * T_;              // loss scalar

    dim3 blk(256);
    dim3 g_tr(32, 16, 8);        // t-tiles, c-tiles, b
    dim3 g_gemm(BT_ / 128, D_ / 64);

    // 0. mask mode detect + zero loss accumulators
    mode_k<<<1, blk, 0, stream>>>((const unsigned int*)mask, 2048, w_mode, w_scal);
    // 1. front_flat = transpose(front_feat) -> s1
    front_transpose_k<<<g_tr, blk, 0, stream>>>(front_feat, s1);
    // 2. E = LN(front_flat @ fa_w + fa_b) -> s0
    gemm_k<false><<<g_gemm, blk, 0, stream>>>(s1, fa_w, fa_b, nullptr, s0, BT_, D_, C_);
    ln_k<<<BT_, blk, 0, stream>>>(s0, fa_g, fa_lb);
    // 3. PLH = silu(plucker @ pl_w1 + pl_b1) -> s1
    plh_k<<<dim3(BT_, 2), blk, 0, stream>>>(plucker, pl_w1, pl_b1, s1);
    // 4. CTX = PLH @ pl_w2 + pl_b2 + E -> s2
    gemm_k<true><<<g_gemm, blk, 0, stream>>>(s1, pl_w2, pl_b2, s0, s2, BT_, D_, D_);
    // 5. sigma, dustbin heads from CTX
    sigma_k<<<BT_ / 4, blk, 0, stream>>>(s2, sig_w, sig_b, w_sigma);
    db_k<<<BT_ / 4, blk, 0, stream>>>(s2, db_w, db_b, w_db);
    // 6. Q = E @ q_w + q_b -> s1
    gemm_k<false><<<g_gemm, blk, 0, stream>>>(s0, q_w, q_b, nullptr, s1, BT_, D_, D_);
    // 7. SE = LN(sat_tokens @ sa_w + sa_b) -> s2 (CTX dead)
    gemm_k<false><<<g_gemm, blk, 0, stream>>>(sat_tokens, sa_w, sa_b, nullptr, s2, BT_, D_, C_);
    ln_k<<<BT_, blk, 0, stream>>>(s2, sa_g, sa_lb);
    // 8. K = SE @ k_w -> s3 ; V = SE @ v_w -> s0 (E dead)
    gemm_k<false><<<g_gemm, blk, 0, stream>>>(s2, k_w, k_b, nullptr, s3, BT_, D_, D_);
    gemm_k<false><<<g_gemm, blk, 0, stream>>>(s2, v_w, v_b, nullptr, s0, BT_, D_, D_);
    // 9. attention -> read s2 (SE dead), dbp
    attn_k<<<dim3(T_ / 32, NH_, B_), blk, 0, stream>>>(
        s1, s3, s0, w_sigma, w_db, bev_xy, sat_xy, mask, w_mode, s2, w_dbp);
    // 10. RF = read @ out_w + out_b -> s3 (K dead)
    gemm_k<false><<<g_gemm, blk, 0, stream>>>(s2, out_w, out_b, nullptr, s3, BT_, D_, D_);
    // 11. confidence + loss partials
    conf_k<<<BT_ / 256, blk, 0, stream>>>(w_dbp, mask, w_mode, outc, w_scal);
    // 12. final epilogue (outputs 0 and 1)
    final_k<<<g_tr, blk, 0, stream>>>(front_feat, s3, outc, out0, out1);
    // 13. loss scalar
    loss_k<<<1, 1, 0, stream>>>(w_scal, outl);
}

// Round 2
// 429.488 us; speedup vs baseline: 2.1893x; 2.1893x over previous
//
#include <hip/hip_runtime.h>

typedef unsigned short u16;
typedef __attribute__((ext_vector_type(8))) short short8;   // 8 bf16 = 4 VGPR
typedef __attribute__((ext_vector_type(4))) float f32x4;    // MFMA acc

// Problem constants
constexpr int B_  = 8;
constexpr int C_  = 512;
constexpr int T_  = 1024;   // H*W
constexpr int S_  = 1024;
constexpr int D_  = 512;
constexpr int NH_ = 8;
constexpr int BT_ = B_ * T_;   // 8192

__device__ __forceinline__ u16 f2bf(float x) {
    union { float f; unsigned u; } v; v.f = x;
    unsigned r = v.u + 0x7fffu + ((v.u >> 16) & 1u);   // RNE
    return (u16)(r >> 16);
}
__device__ __forceinline__ float bf2f(u16 h) {
    union { unsigned u; float f; } v; v.u = ((unsigned)h) << 16;
    return v.f;
}
__device__ __forceinline__ unsigned pack2(float a, float b) {
    return (unsigned)f2bf(a) | ((unsigned)f2bf(b) << 16);
}

// ---------------------------------------------------------------------------
// mask mode detect (int32 / f32 / bytes), same as round-1 (passed).
__device__ __forceinline__ int is_valid(const void* mask, int mode, int idx) {
    if (mode == 0) return ((const int*)mask)[idx] != 0;
    if (mode == 1) return ((const float*)mask)[idx] != 0.0f;
    return ((const unsigned char*)mask)[idx] != 0;
}

__global__ void mode_k(const unsigned int* __restrict__ m, int nwords,
                       int* __restrict__ mode, float* __restrict__ scal) {
    __shared__ int bad_i, bad_f;
    if (threadIdx.x == 0) { bad_i = 0; bad_f = 0; }
    __syncthreads();
    for (int i = threadIdx.x; i < nwords; i += 256) {
        unsigned v = m[i];
        if (v > 1u) bad_i = 1;
        if (v != 0u && v != 0x3f800000u) bad_f = 1;
    }
    __syncthreads();
    if (threadIdx.x == 0) {
        *mode = (!bad_i) ? 0 : ((!bad_f) ? 1 : 2);
        scal[0] = 0.0f; scal[1] = 0.0f;
    }
}

// ---------------------------------------------------------------------------
// weight transpose+convert: W[512][512] f32 -> Wt[n][k] bf16. z picks weight.
__global__ __launch_bounds__(256) void wt_t_k(const float* a0, const float* a1,
        const float* a2, const float* a3, const float* a4, const float* a5,
        const float* a6, u16* __restrict__ dstbase) {
    const float* srcs[7] = {a0, a1, a2, a3, a4, a5, a6};
    const float* src = srcs[blockIdx.z];
    u16* d = dstbase + (size_t)blockIdx.z * 512 * 512;
    __shared__ float t[32][33];
    int k0 = blockIdx.x * 32, n0 = blockIdx.y * 32;
    int tx = threadIdx.x & 31, ty = threadIdx.x >> 5;
    for (int i = ty; i < 32; i += 8)
        t[i][tx] = src[(size_t)(k0 + i) * 512 + n0 + tx];
    __syncthreads();
    for (int i = ty; i < 32; i += 8)
        d[(size_t)(n0 + i) * 512 + k0 + tx] = f2bf(t[tx][i]);
}

// front_feat (B,C,T) f32 -> front_flat (B*T, C) bf16
__global__ __launch_bounds__(256) void front_transpose_k(const float* __restrict__ in,
                                                         u16* __restrict__ out) {
    __shared__ float tile[32][33];
    int t0 = blockIdx.x * 32, c0 = blockIdx.y * 32, b = blockIdx.z;
    int tx = threadIdx.x & 31, ty = threadIdx.x >> 5;
    const float* ip = in + (size_t)b * C_ * T_;
    for (int i = ty; i < 32; i += 8)
        tile[i][tx] = ip[(size_t)(c0 + i) * T_ + t0 + tx];
    __syncthreads();
    u16* op = out + (size_t)b * T_ * C_;
    for (int i = ty; i < 32; i += 8)
        op[(size_t)(t0 + i) * C_ + c0 + tx] = f2bf(tile[tx][i]);
}

// f32 -> bf16 elementwise (sat_tokens)
__global__ __launch_bounds__(256) void cvt_k(const float* __restrict__ in,
                                             u16* __restrict__ out, int n8) {
    int i = blockIdx.x * 256 + threadIdx.x;
    if (i >= n8) return;
    const float4* p = (const float4*)(in + (size_t)i * 8);
    float4 a = p[0], b = p[1];
    uint4 o;
    o.x = pack2(a.x, a.y); o.y = pack2(a.z, a.w);
    o.z = pack2(b.x, b.y); o.w = pack2(b.z, b.w);
    *(uint4*)(out + (size_t)i * 8) = o;
}

// ---------------------------------------------------------------------------
// bf16 MFMA GEMM: C[M,512] = A[M,512](bf16) @ Wt[512,512]^T + bias.
// Block 64x64, 4 waves (2x2), wave 32x32 = 2x2 fragments of 16x16, K-step 32.
// Fragments load straight from global (16B/lane, L2-resident B panels).
// MODE: 0 = f32 out, 1 = bf16 out, 2 = f32 out + bf16 addend, 3 = Vt bf16 out.
template <int MODE>
__global__ __launch_bounds__(256) void mm_k(const u16* __restrict__ A,
                                            const u16* __restrict__ Bt,
                                            const float* __restrict__ bias,
                                            const u16* __restrict__ addend,
                                            void* __restrict__ Cout) {
    int tid = threadIdx.x, w = tid >> 6, l = tid & 63;
    int wtr = w >> 1, wtc = w & 1;
    int m0 = blockIdx.x * 64, n0 = blockIdx.y * 64;
    int lr = l & 15, g = l >> 4;

    const u16* Ab = A  + (size_t)(m0 + wtr * 32 + lr) * 512 + g * 8;
    const u16* Bb = Bt + (size_t)(n0 + wtc * 32 + lr) * 512 + g * 8;

    f32x4 acc[2][2] = {};
#pragma unroll 4
    for (int k0 = 0; k0 < 512; k0 += 32) {
        short8 a0 = *(const short8*)(Ab + k0);
        short8 a1 = *(const short8*)(Ab + 16 * 512 + k0);
        short8 b0 = *(const short8*)(Bb + k0);
        short8 b1 = *(const short8*)(Bb + 16 * 512 + k0);
        acc[0][0] = __builtin_amdgcn_mfma_f32_16x16x32_bf16(a0, b0, acc[0][0], 0, 0, 0);
        acc[0][1] = __builtin_amdgcn_mfma_f32_16x16x32_bf16(a0, b1, acc[0][1], 0, 0, 0);
        acc[1][0] = __builtin_amdgcn_mfma_f32_16x16x32_bf16(a1, b0, acc[1][0], 0, 0, 0);
        acc[1][1] = __builtin_amdgcn_mfma_f32_16x16x32_bf16(a1, b1, acc[1][1], 0, 0, 0);
    }

    float bs[2] = {bias[n0 + wtc * 32 + lr], bias[n0 + wtc * 32 + 16 + lr]};
#pragma unroll
    for (int m = 0; m < 2; ++m) {
#pragma unroll
        for (int n = 0; n < 2; ++n) {
            int R0  = m0 + wtr * 32 + m * 16 + 4 * g;   // rows R0..R0+3 (j)
            int col = n0 + wtc * 32 + n * 16 + lr;
            if constexpr (MODE == 3) {
                int bb = R0 >> 10, ss = R0 & 1023, hh = col >> 6, dd = col & 63;
                unsigned lo = pack2(acc[m][n][0] + bs[n], acc[m][n][1] + bs[n]);
                unsigned hi = pack2(acc[m][n][2] + bs[n], acc[m][n][3] + bs[n]);
                uint2 pk; pk.x = lo; pk.y = hi;
                u16* dst = (u16*)Cout + ((size_t)(bb * 8 + hh) * 64 + dd) * 1024 + ss;
                *(uint2*)dst = pk;
            } else {
#pragma unroll
                for (int j = 0; j < 4; ++j) {
                    int row = R0 + j;
                    float v = acc[m][n][j] + bs[n];
                    if constexpr (MODE == 0) {
                        ((float*)Cout)[(size_t)row * 512 + col] = v;
                    } else if constexpr (MODE == 2) {
                        v += bf2f(addend[(size_t)row * 512 + col]);
                        ((float*)Cout)[(size_t)row * 512 + col] = v;
                    } else {   // MODE 1
                        ((u16*)Cout)[(size_t)row * 512 + col] = f2bf(v);
                    }
                }
            }
        }
    }
}

// ---------------------------------------------------------------------------
// LayerNorm rows of 512: f32 in -> bf16 out
__global__ __launch_bounds__(256) void ln_bf_k(const float* __restrict__ X,
                                               const float* __restrict__ g,
                                               const float* __restrict__ bv,
                                               u16* __restrict__ out) {
    int row = blockIdx.x, tid = threadIdx.x;
    const float* xr = X + (size_t)row * D_;
    float x0 = xr[tid], x1 = xr[tid + 256];
    float s = x0 + x1, sq = x0 * x0 + x1 * x1;
    __shared__ float rs[4], rq[4];
    for (int o = 32; o; o >>= 1) { s += __shfl_down(s, o); sq += __shfl_down(sq, o); }
    int wid = tid >> 6, lane = tid & 63;
    if (lane == 0) { rs[wid] = s; rq[wid] = sq; }
    __syncthreads();
    if (tid == 0) {
        float ts = 0, tq = 0;
        for (int w = 0; w < 4; ++w) { ts += rs[w]; tq += rq[w]; }
        rs[0] = ts; rq[0] = tq;
    }
    __syncthreads();
    float mean = rs[0] * (1.0f / D_);
    float var  = rq[0] * (1.0f / D_) - mean * mean;
    float r = rsqrtf(var + 1e-5f);
    u16* orow = out + (size_t)row * D_;
    orow[tid]       = f2bf((x0 - mean) * r * g[tid] + bv[tid]);
    orow[tid + 256] = f2bf((x1 - mean) * r * g[tid + 256] + bv[tid + 256]);
}

// plucker hidden: silu(plucker @ pl_w1 + pl_b1) -> bf16
__global__ __launch_bounds__(256) void plh_k(const float* __restrict__ pl,
                                             const float* __restrict__ w1,
                                             const float* __restrict__ b1,
                                             u16* __restrict__ out) {
    int m = blockIdx.x;
    int n = blockIdx.y * 256 + threadIdx.x;
    const float* p = pl + (size_t)m * 6;
    float acc = b1[n];
#pragma unroll
    for (int j = 0; j < 6; ++j) acc += p[j] * w1[j * D_ + n];
    out[(size_t)m * D_ + n] = f2bf(acc / (1.0f + __expf(-acc)));
}

// sigma head (CTX f32)
__global__ __launch_bounds__(256) void sigma_k(const float* __restrict__ ctx,
                                               const float* __restrict__ w,
                                               const float* __restrict__ bb,
                                               float* __restrict__ sig) {
    int wid = threadIdx.x >> 6, lane = threadIdx.x & 63;
    int row = blockIdx.x * 4 + wid;
    const float* xr = ctx + (size_t)row * D_;
    float acc = 0;
#pragma unroll
    for (int i = 0; i < 8; ++i) { int c = i * 64 + lane; acc += xr[c] * w[c]; }
    for (int o = 32; o; o >>= 1) acc += __shfl_down(acc, o);
    if (lane == 0) {
        float z = acc + bb[0];
        sig[row] = 0.03f + 0.32f / (1.0f + __expf(-z));
    }
}

// dustbin head (CTX f32)
__global__ __launch_bounds__(256) void db_k(const float* __restrict__ ctx,
                                            const float* __restrict__ w,
                                            const float* __restrict__ bb,
                                            float* __restrict__ dbo) {
    int wid = threadIdx.x >> 6, lane = threadIdx.x & 63;
    int row = blockIdx.x * 4 + wid;
    const float* xr = ctx + (size_t)row * D_;
    float p_[8] = {};
#pragma unroll
    for (int i = 0; i < 8; ++i) {
        int c = i * 64 + lane;
        float x = xr[c];
        const float* wr = w + (size_t)c * NH_;
#pragma unroll
        for (int h = 0; h < 8; ++h) p_[h] += x * wr[h];
    }
#pragma unroll
    for (int h = 0; h < 8; ++h) {
        float v = p_[h];
        for (int o = 32; o; o >>= 1) v += __shfl_down(v, o);
        if (lane == 0) dbo[(size_t)row * NH_ + h] = v + bb[h];
    }
}

// ---------------------------------------------------------------------------
// MFMA flash attention. Wave = 16 q-tokens, block = 4 waves (64 t).
// Swapped QK^T: P[s][t] = mfma(Kfrag, Qfrag); PV: O[d][t] = mfma(Vtfrag, Pfrag).
// Both have col = t = lane&15 -> softmax state fully per-lane.
__global__ __launch_bounds__(256) void attn_k(
    const u16* __restrict__ Q, const u16* __restrict__ K,
    const u16* __restrict__ Vt, const float* __restrict__ sig,
    const float* __restrict__ dbl, const float* __restrict__ bev,
    const float* __restrict__ sxy, const void* __restrict__ mask,
    const int* __restrict__ mode, u16* __restrict__ OUT,
    float* __restrict__ dbp) {
    int h = blockIdx.y, b = blockIdx.z;
    int tid = threadIdx.x, w = tid >> 6, l = tid & 63;
    int lr = l & 15, g = l >> 4;

    __shared__ u16 P_lds[4][640];   // per wave: 16 rows x 40 bf16 (80B, 16B-aligned)
    char* pbase = (char*)&P_lds[w][0];

    int trow = b * T_ + blockIdx.x * 64 + w * 16 + lr;
    float s_ = sig[trow];
    float grow = -8.0f / fmaxf(s_ * s_, 1e-6f);
    float bx = bev[(size_t)trow * 2], by = bev[(size_t)trow * 2 + 1];
    float dbv = dbl[(size_t)trow * NH_ + h];
    int md = *mode;
    bool vld = is_valid(mask, md, trow) != 0;

    const u16* qp = Q + (size_t)trow * 512 + h * 64 + g * 8;
    short8 q0 = *(const short8*)qp;
    short8 q1 = *(const short8*)(qp + 32);

    float m_st = dbv, l_st = 1.0f;
    f32x4 o0 = {}, o1 = {}, o2 = {}, o3 = {};

    const u16* Kb = K + (size_t)b * S_ * 512 + h * 64 + g * 8;
    const u16* Vb = Vt + ((size_t)(b * 8 + h) * 64 + lr) * 1024;
    const float2* xp = (const float2*)(sxy + (size_t)b * S_ * 2);

    for (int c = 0; c < 32; ++c) {
        int s0c = c * 32;
        // K fragments (A-operand rows = s)
        short8 k00 = *(const short8*)(Kb + (size_t)(s0c + lr) * 512);
        short8 k01 = *(const short8*)(Kb + (size_t)(s0c + lr) * 512 + 32);
        short8 k10 = *(const short8*)(Kb + (size_t)(s0c + 16 + lr) * 512);
        short8 k11 = *(const short8*)(Kb + (size_t)(s0c + 16 + lr) * 512 + 32);
        // V^T fragments (A-operand rows = d), contiguous s
        short8 v0 = *(const short8*)(Vb + (size_t)0 * 16384 + s0c + g * 8);
        short8 v1 = *(const short8*)(Vb + (size_t)1 * 16384 + s0c + g * 8);
        short8 v2 = *(const short8*)(Vb + (size_t)2 * 16384 + s0c + g * 8);
        short8 v3 = *(const short8*)(Vb + (size_t)3 * 16384 + s0c + g * 8);
        // sat_xy for this lane's 8 s-values
        float sxv[8], syv[8];
#pragma unroll
        for (int r = 0; r < 8; ++r) {
            int sidx = s0c + (r >> 2) * 16 + g * 4 + (r & 3);
            float2 xy = xp[sidx];
            sxv[r] = xy.x; syv[r] = xy.y;
        }
        f32x4 z = {};
        f32x4 p0 = __builtin_amdgcn_mfma_f32_16x16x32_bf16(k00, q0, z, 0, 0, 0);
        p0 = __builtin_amdgcn_mfma_f32_16x16x32_bf16(k01, q1, p0, 0, 0, 0);
        f32x4 p1 = __builtin_amdgcn_mfma_f32_16x16x32_bf16(k10, q0, z, 0, 0, 0);
        p1 = __builtin_amdgcn_mfma_f32_16x16x32_bf16(k11, q1, p1, 0, 0, 0);

        // logits + online softmax (state per-lane, col t = lane&15)
        float pe[8];
        float cmax = -3.0e38f;
#pragma unroll
        for (int r = 0; r < 8; ++r) {
            float pv = (r < 4) ? p0[r & 3] : p1[r & 3];
            float dx = bx - sxv[r], dy = by - syv[r];
            float lg = fmaf(pv, 0.0125f, grow * (dx * dx + dy * dy));
            lg = vld ? lg : -10000.0f;
            pe[r] = lg;
            cmax = fmaxf(cmax, lg);
        }
        cmax = fmaxf(cmax, __shfl_xor(cmax, 16));
        cmax = fmaxf(cmax, __shfl_xor(cmax, 32));
        float m_new = fmaxf(m_st, cmax);
        float scl = __expf(m_st - m_new);
        float ps = 0.0f;
#pragma unroll
        for (int r = 0; r < 8; ++r) { pe[r] = __expf(pe[r] - m_new); ps += pe[r]; }
        ps += __shfl_xor(ps, 16);
        ps += __shfl_xor(ps, 32);
        l_st = l_st * scl + ps;
        m_st = m_new;
        o0 *= scl; o1 *= scl; o2 *= scl; o3 *= scl;

        // P -> LDS (bf16, [t][s] stride 40) -> read back as B-fragment
        uint2 w0; w0.x = pack2(pe[0], pe[1]); w0.y = pack2(pe[2], pe[3]);
        uint2 w1; w1.x = pack2(pe[4], pe[5]); w1.y = pack2(pe[6], pe[7]);
        *(uint2*)(pbase + lr * 80 + g * 8)      = w0;
        *(uint2*)(pbase + lr * 80 + 32 + g * 8) = w1;
        union { uint4 u; short8 s8; } pf;
        pf.u = *(uint4*)(pbase + lr * 80 + g * 16);

        o0 = __builtin_amdgcn_mfma_f32_16x16x32_bf16(v0, pf.s8, o0, 0, 0, 0);
        o1 = __builtin_amdgcn_mfma_f32_16x16x32_bf16(v1, pf.s8, o1, 0, 0, 0);
        o2 = __builtin_amdgcn_mfma_f32_16x16x32_bf16(v2, pf.s8, o2, 0, 0, 0);
        o3 = __builtin_amdgcn_mfma_f32_16x16x32_bf16(v3, pf.s8, o3, 0, 0, 0);
    }

    float inv = 1.0f / l_st;
    u16* ob = OUT + (size_t)trow * 512 + h * 64;
    {
        uint2 pk;
        pk.x = pack2(o0[0] * inv, o0[1] * inv); pk.y = pack2(o0[2] * inv, o0[3] * inv);
        *(uint2*)(ob + 0 * 16 + 4 * g) = pk;
        pk.x = pack2(o1[0] * inv, o1[1] * inv); pk.y = pack2(o1[2] * inv, o1[3] * inv);
        *(uint2*)(ob + 1 * 16 + 4 * g) = pk;
        pk.x = pack2(o2[0] * inv, o2[1] * inv); pk.y = pack2(o2[2] * inv, o2[3] * inv);
        *(uint2*)(ob + 2 * 16 + 4 * g) = pk;
        pk.x = pack2(o3[0] * inv, o3[1] * inv); pk.y = pack2(o3[2] * inv, o3[3] * inv);
        *(uint2*)(ob + 3 * 16 + 4 * g) = pk;
    }
    if (g == 0) dbp[(size_t)trow * NH_ + h] = __expf(dbv - m_st) * inv;
}

// ---------------------------------------------------------------------------
// confidence + invalid-loss partials
__global__ __launch_bounds__(256) void conf_k(const float* __restrict__ dbp,
                                              const void* __restrict__ mask,
                                              const int* __restrict__ mode,
                                              float* __restrict__ confout,
                                              float* __restrict__ scal) {
    int row = blockIdx.x * 256 + threadIdx.x;
    const float* dr = dbp + (size_t)row * NH_;
    float s = 0;
#pragma unroll
    for (int h = 0; h < 8; ++h) s += dr[h];
    float cf = 1.0f - s * (1.0f / NH_);
    confout[row] = cf;
    int md = *mode;
    float inv = is_valid(mask, md, row) ? 0.0f : 1.0f;
    float a = cf * inv, bs = inv;
    __shared__ float ra[4], rb[4];
    for (int o = 32; o; o >>= 1) { a += __shfl_down(a, o); bs += __shfl_down(bs, o); }
    int wid = threadIdx.x >> 6, lane = threadIdx.x & 63;
    if (lane == 0) { ra[wid] = a; rb[wid] = bs; }
    __syncthreads();
    if (threadIdx.x == 0) {
        float ta = 0, tb = 0;
        for (int w = 0; w < 4; ++w) { ta += ra[w]; tb += rb[w]; }
        atomicAdd(&scal[0], ta);
        atomicAdd(&scal[1], tb);
    }
}

// epilogue: transpose RF (B,T,C)->(B,C,T); out0 = ff + conf*rf; out1 = rf
__global__ __launch_bounds__(256) void final_k(const float* __restrict__ ff,
                                               const float* __restrict__ RF,
                                               const float* __restrict__ conf,
                                               float* __restrict__ out0,
                                               float* __restrict__ out1) {
    __shared__ float tile[32][33];
    int t0 = blockIdx.x * 32, c0 = blockIdx.y * 32, b = blockIdx.z;
    int tx = threadIdx.x & 31, ty = threadIdx.x >> 5;
    for (int j = ty; j < 32; j += 8)
        tile[j][tx] = RF[((size_t)b * T_ + t0 + j) * C_ + c0 + tx];
    __syncthreads();
    size_t base = (size_t)b * C_ * T_;
    float cf = conf[b * T_ + t0 + tx];
    for (int i = ty; i < 32; i += 8) {
        size_t idx = base + (size_t)(c0 + i) * T_ + t0 + tx;
        float rf = tile[tx][i];
        out1[idx] = rf;
        out0[idx] = ff[idx] + cf * rf;
    }
}

__global__ void loss_k(const float* __restrict__ scal, float* __restrict__ out) {
    out[0] = scal[0] / fmaxf(scal[1], 1.0f) * 0.05f;
}

// ---------------------------------------------------------------------------
extern "C" void kernel_launch(void* const* d_in, const int* in_sizes, int n_in,
                              void* d_out, int out_size, void* d_ws, size_t ws_size,
                              hipStream_t stream) {
    const float* front_feat = (const float*)d_in[0];
    const float* sat_tokens = (const float*)d_in[1];
    const float* sat_xy     = (const float*)d_in[2];
    const float* bev_xy     = (const float*)d_in[3];
    const void*  mask       = d_in[4];
    const float* plucker    = (const float*)d_in[5];
    const float* fa_w = (const float*)d_in[6];
    const float* fa_b = (const float*)d_in[7];
    const float* fa_g = (const float*)d_in[8];
    const float* fa_lb = (const float*)d_in[9];
    const float* sa_w = (const float*)d_in[10];
    const float* sa_b = (const float*)d_in[11];
    const float* sa_g = (const float*)d_in[12];
    const float* sa_lb = (const float*)d_in[13];
    const float* q_w = (const float*)d_in[14];
    const float* q_b = (const float*)d_in[15];
    const float* k_w = (const float*)d_in[16];
    const float* k_b = (const float*)d_in[17];
    const float* v_w = (const float*)d_in[18];
    const float* v_b = (const float*)d_in[19];
    const float* pl_w1 = (const float*)d_in[20];
    const float* pl_b1 = (const float*)d_in[21];
    const float* pl_w2 = (const float*)d_in[22];
    const float* pl_b2 = (const float*)d_in[23];
    const float* sig_w = (const float*)d_in[24];
    const float* sig_b = (const float*)d_in[25];
    const float* db_w = (const float*)d_in[26];
    const float* db_b = (const float*)d_in[27];
    const float* out_w = (const float*)d_in[28];
    const float* out_b = (const float*)d_in[29];

    char* w8 = (char*)d_ws;
    float* F0 = (float*)w8;                                   // 16 MB f32 scratch
    u16* H0 = (u16*)(w8 + 16777216ull);                       // 8 MB bf16 slots
    u16* H1 = (u16*)(w8 + 16777216ull + 8388608ull * 1);
    u16* H2 = (u16*)(w8 + 16777216ull + 8388608ull * 2);
    u16* H3 = (u16*)(w8 + 16777216ull + 8388608ull * 3);
    u16* H4 = (u16*)(w8 + 16777216ull + 8388608ull * 4);
    u16* WT = (u16*)(w8 + 16777216ull + 8388608ull * 5);      // 7 x 0.5 MB
    char* sm = w8 + 16777216ull + 8388608ull * 5 + 3670016ull;
    float* w_sigma = (float*)sm;                              // BT
    float* w_db    = w_sigma + BT_;                           // BT*8
    float* w_dbp   = w_db + (size_t)BT_ * NH_;                // BT*8
    float* w_scal  = w_dbp + (size_t)BT_ * NH_;
    int*   w_mode  = (int*)(w_scal + 2);

    u16* Wfa = WT;               u16* Wpl2 = WT + 262144ull * 1;
    u16* Wq  = WT + 262144ull * 2; u16* Wsa = WT + 262144ull * 3;
    u16* Wk  = WT + 262144ull * 4; u16* Wv  = WT + 262144ull * 5;
    u16* Wo  = WT + 262144ull * 6;

    float* out0 = (float*)d_out;
    float* out1 = out0 + (size_t)B_ * C_ * T_;
    float* outc = out1 + (size_t)B_ * C_ * T_;
    float* outl = outc + (size_t)B_ * T_;

    dim3 blk(256);
    dim3 g_tr(32, 16, 8);
    dim3 g_mm(BT_ / 64, D_ / 64);

    mode_k<<<1, blk, 0, stream>>>((const unsigned int*)mask, 2048, w_mode, w_scal);
    wt_t_k<<<dim3(16, 16, 7), blk, 0, stream>>>(fa_w, pl_w2, q_w, sa_w, k_w, v_w, out_w, WT);
    front_transpose_k<<<g_tr, blk, 0, stream>>>(front_feat, H0);
    // E = LN(front_flat @ fa_w + fa_b)
    mm_k<0><<<g_mm, blk, 0, stream>>>(H0, Wfa, fa_b, nullptr, F0);
    ln_bf_k<<<BT_, blk, 0, stream>>>(F0, fa_g, fa_lb, H1);
    // SAT -> bf16
    cvt_k<<<(BT_ * D_ / 8 + 255) / 256, blk, 0, stream>>>(sat_tokens, H0, BT_ * D_ / 8);
    // PLH
    plh_k<<<dim3(BT_, 2), blk, 0, stream>>>(plucker, pl_w1, pl_b1, H2);
    // CTX = PLH @ pl_w2 + pl_b2 + E
    mm_k<2><<<g_mm, blk, 0, stream>>>(H2, Wpl2, pl_b2, H1, F0);
    sigma_k<<<BT_ / 4, blk, 0, stream>>>(F0, sig_w, sig_b, w_sigma);
    db_k<<<BT_ / 4, blk, 0, stream>>>(F0, db_w, db_b, w_db);
    // Q (bf16)
    mm_k<1><<<g_mm, blk, 0, stream>>>(H1, Wq, q_b, nullptr, H2);
    // SE = LN(sat @ sa_w + sa_b)
    mm_k<0><<<g_mm, blk, 0, stream>>>(H0, Wsa, sa_b, nullptr, F0);
    ln_bf_k<<<BT_, blk, 0, stream>>>(F0, sa_g, sa_lb, H3);
    // K (bf16), Vt (bf16 transposed per-head)
    mm_k<1><<<g_mm, blk, 0, stream>>>(H3, Wk, k_b, nullptr, H1);
    mm_k<3><<<g_mm, blk, 0, stream>>>(H3, Wv, v_b, nullptr, H4);
    // attention
    attn_k<<<dim3(T_ / 64, NH_, B_), blk, 0, stream>>>(
        H2, H1, H4, w_sigma, w_db, bev_xy, sat_xy, mask, w_mode, H0, w_dbp);
    // RF = read @ out_w + out_b (f32)
    mm_k<0><<<g_mm, blk, 0, stream>>>(H0, Wo, out_b, nullptr, F0);
    conf_k<<<BT_ / 256, blk, 0, stream>>>(w_dbp, mask, w_mode, outc, w_scal);
    final_k<<<g_tr, blk, 0, stream>>>(front_feat, F0, outc, out0, out1);
    loss_k<<<1, 1, 0, stream>>>(w_scal, outl);
}

// Round 3
// 249.752 us; speedup vs baseline: 3.7648x; 1.7197x over previous
//
#include <hip/hip_runtime.h>

typedef unsigned short u16;
typedef __attribute__((ext_vector_type(8))) short short8;   // 8 bf16 = 4 VGPR
typedef __attribute__((ext_vector_type(4))) float f32x4;    // MFMA acc

// Problem constants
constexpr int B_  = 8;
constexpr int C_  = 512;
constexpr int T_  = 1024;   // H*W
constexpr int S_  = 1024;
constexpr int D_  = 512;
constexpr int NH_ = 8;
constexpr int BT_ = B_ * T_;   // 8192

__device__ __forceinline__ u16 f2bf(float x) {
    union { float f; unsigned u; } v; v.f = x;
    unsigned r = v.u + 0x7fffu + ((v.u >> 16) & 1u);   // RNE
    return (u16)(r >> 16);
}
__device__ __forceinline__ float bf2f(u16 h) {
    union { unsigned u; float f; } v; v.u = ((unsigned)h) << 16;
    return v.f;
}
__device__ __forceinline__ unsigned pack2(float a, float b) {
    return (unsigned)f2bf(a) | ((unsigned)f2bf(b) << 16);
}

// async global->LDS 16B. lds ptr computed per-lane as wavebase + lane*16 so
// both "firstlane base + lane*16" and "per-lane linear" semantics coincide.
typedef __attribute__((address_space(3))) unsigned int lds_u32;
typedef const __attribute__((address_space(1))) unsigned int glob_u32;
__device__ __forceinline__ void g2l16(void* l, const void* g) {
    __builtin_amdgcn_global_load_lds((glob_u32*)g, (lds_u32*)l, 16, 0, 0);
}

// ---------------------------------------------------------------------------
// mask mode detect (int32 / f32 / bytes)
__device__ __forceinline__ int is_valid(const void* mask, int mode, int idx) {
    if (mode == 0) return ((const int*)mask)[idx] != 0;
    if (mode == 1) return ((const float*)mask)[idx] != 0.0f;
    return ((const unsigned char*)mask)[idx] != 0;
}

__global__ void mode_k(const unsigned int* __restrict__ m, int nwords,
                       int* __restrict__ mode, float* __restrict__ scal) {
    __shared__ int bad_i, bad_f;
    if (threadIdx.x == 0) { bad_i = 0; bad_f = 0; }
    __syncthreads();
    for (int i = threadIdx.x; i < nwords; i += 256) {
        unsigned v = m[i];
        if (v > 1u) bad_i = 1;
        if (v != 0u && v != 0x3f800000u) bad_f = 1;
    }
    __syncthreads();
    if (threadIdx.x == 0) {
        *mode = (!bad_i) ? 0 : ((!bad_f) ? 1 : 2);
        scal[0] = 0.0f; scal[1] = 0.0f;
    }
}

// ---------------------------------------------------------------------------
// weight transpose+convert: W[512][512] f32 -> Wt[n][k] bf16. z picks weight.
__global__ __launch_bounds__(256) void wt_t_k(const float* a0, const float* a1,
        const float* a2, const float* a3, const float* a4, const float* a5,
        const float* a6, u16* __restrict__ dstbase) {
    const float* srcs[7] = {a0, a1, a2, a3, a4, a5, a6};
    const float* src = srcs[blockIdx.z];
    u16* d = dstbase + (size_t)blockIdx.z * 512 * 512;
    __shared__ float t[32][33];
    int k0 = blockIdx.x * 32, n0 = blockIdx.y * 32;
    int tx = threadIdx.x & 31, ty = threadIdx.x >> 5;
    for (int i = ty; i < 32; i += 8)
        t[i][tx] = src[(size_t)(k0 + i) * 512 + n0 + tx];
    __syncthreads();
    for (int i = ty; i < 32; i += 8)
        d[(size_t)(n0 + i) * 512 + k0 + tx] = f2bf(t[tx][i]);
}

// front_feat (B,C,T) f32 -> front_flat (B*T, C) bf16
__global__ __launch_bounds__(256) void front_transpose_k(const float* __restrict__ in,
                                                         u16* __restrict__ out) {
    __shared__ float tile[32][33];
    int t0 = blockIdx.x * 32, c0 = blockIdx.y * 32, b = blockIdx.z;
    int tx = threadIdx.x & 31, ty = threadIdx.x >> 5;
    const float* ip = in + (size_t)b * C_ * T_;
    for (int i = ty; i < 32; i += 8)
        tile[i][tx] = ip[(size_t)(c0 + i) * T_ + t0 + tx];
    __syncthreads();
    u16* op = out + (size_t)b * T_ * C_;
    for (int i = ty; i < 32; i += 8)
        op[(size_t)(t0 + i) * C_ + c0 + tx] = f2bf(tile[tx][i]);
}

// f32 -> bf16 elementwise
__global__ __launch_bounds__(256) void cvt_k(const float* __restrict__ in,
                                             u16* __restrict__ out, int n8) {
    int i = blockIdx.x * 256 + threadIdx.x;
    if (i >= n8) return;
    const float4* p = (const float4*)(in + (size_t)i * 8);
    float4 a = p[0], b = p[1];
    uint4 o;
    o.x = pack2(a.x, a.y); o.y = pack2(a.z, a.w);
    o.z = pack2(b.x, b.y); o.w = pack2(b.z, b.w);
    *(uint4*)(out + (size_t)i * 8) = o;
}

// ---------------------------------------------------------------------------
// bf16 MFMA GEMM, LDS-staged double-buffered 2-phase.
// C[M=8192,N=512] = A[M,512] @ Wt[n][k]^T + bias. Tile 128x64, BK=64, 4 waves.
// LDS layout: k-granule slabs — A: slab gk (0..7) holds 128 rows x 16B;
// B: slab gk holds 64 rows x 16B. Frag reads are 256B-contiguous per 16-lane
// group -> conflict-free. Staged with global_load_lds width 16.
// MODE: 0 f32 out; 1 bf16 out; 2 f32 out + bf16 addend; 3 Vt bf16; 4 bf16*0.0125
template <int MODE>
__global__ __launch_bounds__(256) void mm_k(const u16* __restrict__ A,
                                            const u16* __restrict__ Bt,
                                            const float* __restrict__ bias,
                                            const u16* __restrict__ addend,
                                            void* __restrict__ Cout) {
    __shared__ u16 As[2][8192];   // 16 KB each
    __shared__ u16 Bs[2][4096];   // 8 KB each
    int tid = threadIdx.x, w = tid >> 6, l = tid & 63;
    int lr = l & 15, g = l >> 4;
    int L = blockIdx.x;
    int W = (L & 7) * 64 + (L >> 3);          // XCD swizzle (512 % 8 == 0)
    int m0 = (W >> 3) * 128, n0 = (W & 7) * 64;
    int wr = w >> 1, wc = w & 1;

    f32x4 acc[4][2] = {};

    auto stage = [&](int buf, int k0) {
#pragma unroll
        for (int j = 0; j < 4; ++j) {        // A: 1024 granules
            int i = tid + 256 * j;
            int gg = i >> 7, row = i & 127;
            g2l16((char*)As[buf] + (size_t)i * 16,
                  A + (size_t)(m0 + row) * 512 + k0 + gg * 8);
        }
#pragma unroll
        for (int j = 0; j < 2; ++j) {        // B: 512 granules
            int i = tid + 256 * j;
            int gg = i >> 6, n = i & 63;
            g2l16((char*)Bs[buf] + (size_t)i * 16,
                  Bt + (size_t)(n0 + n) * 512 + k0 + gg * 8);
        }
    };

    stage(0, 0);
    __syncthreads();
    int cur = 0;
    for (int t = 0; t < 8; ++t) {
        if (t < 7) stage(cur ^ 1, (t + 1) * 64);
        const char* Ab = (const char*)As[cur];
        const char* Bb = (const char*)Bs[cur];
#pragma unroll
        for (int kk = 0; kk < 2; ++kk) {
            short8 af[4], bf[2];
#pragma unroll
            for (int m = 0; m < 4; ++m)
                af[m] = *(const short8*)(Ab + (kk * 4 + g) * 2048 +
                                         (wr * 64 + m * 16 + lr) * 16);
#pragma unroll
            for (int n = 0; n < 2; ++n)
                bf[n] = *(const short8*)(Bb + (kk * 4 + g) * 1024 +
                                         (wc * 32 + n * 16 + lr) * 16);
#pragma unroll
            for (int m = 0; m < 4; ++m)
#pragma unroll
                for (int n = 0; n < 2; ++n)
                    acc[m][n] = __builtin_amdgcn_mfma_f32_16x16x32_bf16(
                        af[m], bf[n], acc[m][n], 0, 0, 0);
        }
        __syncthreads();
        cur ^= 1;
    }

    float bs[2] = {bias[n0 + wc * 32 + lr], bias[n0 + wc * 32 + 16 + lr]};
#pragma unroll
    for (int m = 0; m < 4; ++m) {
#pragma unroll
        for (int n = 0; n < 2; ++n) {
            int R0  = m0 + wr * 64 + m * 16 + 4 * g;
            int col = n0 + wc * 32 + n * 16 + lr;
            if constexpr (MODE == 3) {
                int bb = R0 >> 10, ss = R0 & 1023, hh = col >> 6, dd = col & 63;
                uint2 pk;
                pk.x = pack2(acc[m][n][0] + bs[n], acc[m][n][1] + bs[n]);
                pk.y = pack2(acc[m][n][2] + bs[n], acc[m][n][3] + bs[n]);
                u16* dst = (u16*)Cout + ((size_t)(bb * 8 + hh) * 64 + dd) * 1024 + ss;
                *(uint2*)dst = pk;
            } else {
#pragma unroll
                for (int j = 0; j < 4; ++j) {
                    int row = R0 + j;
                    float v = acc[m][n][j] + bs[n];
                    if constexpr (MODE == 0) {
                        ((float*)Cout)[(size_t)row * 512 + col] = v;
                    } else if constexpr (MODE == 2) {
                        v += bf2f(addend[(size_t)row * 512 + col]);
                        ((float*)Cout)[(size_t)row * 512 + col] = v;
                    } else if constexpr (MODE == 4) {
                        ((u16*)Cout)[(size_t)row * 512 + col] = f2bf(v * 0.0125f);
                    } else {   // MODE 1
                        ((u16*)Cout)[(size_t)row * 512 + col] = f2bf(v);
                    }
                }
            }
        }
    }
}

// ---------------------------------------------------------------------------
// LayerNorm rows of 512: f32 in -> bf16 out
__global__ __launch_bounds__(256) void ln_bf_k(const float* __restrict__ X,
                                               const float* __restrict__ g,
                                               const float* __restrict__ bv,
                                               u16* __restrict__ out) {
    int row = blockIdx.x, tid = threadIdx.x;
    const float* xr = X + (size_t)row * D_;
    float x0 = xr[tid], x1 = xr[tid + 256];
    float s = x0 + x1, sq = x0 * x0 + x1 * x1;
    __shared__ float rs[4], rq[4];
    for (int o = 32; o; o >>= 1) { s += __shfl_down(s, o); sq += __shfl_down(sq, o); }
    int wid = tid >> 6, lane = tid & 63;
    if (lane == 0) { rs[wid] = s; rq[wid] = sq; }
    __syncthreads();
    if (tid == 0) {
        float ts = 0, tq = 0;
        for (int w = 0; w < 4; ++w) { ts += rs[w]; tq += rq[w]; }
        rs[0] = ts; rq[0] = tq;
    }
    __syncthreads();
    float mean = rs[0] * (1.0f / D_);
    float var  = rq[0] * (1.0f / D_) - mean * mean;
    float r = rsqrtf(var + 1e-5f);
    u16* orow = out + (size_t)row * D_;
    orow[tid]       = f2bf((x0 - mean) * r * g[tid] + bv[tid]);
    orow[tid + 256] = f2bf((x1 - mean) * r * g[tid + 256] + bv[tid + 256]);
}

// plucker hidden: silu(plucker @ pl_w1 + pl_b1) -> bf16
__global__ __launch_bounds__(256) void plh_k(const float* __restrict__ pl,
                                             const float* __restrict__ w1,
                                             const float* __restrict__ b1,
                                             u16* __restrict__ out) {
    int m = blockIdx.x;
    int n = blockIdx.y * 256 + threadIdx.x;
    const float* p = pl + (size_t)m * 6;
    float acc = b1[n];
#pragma unroll
    for (int j = 0; j < 6; ++j) acc += p[j] * w1[j * D_ + n];
    out[(size_t)m * D_ + n] = f2bf(acc / (1.0f + __expf(-acc)));
}

// fused sigma + dustbin heads (one CTX pass). One wave per row.
__global__ __launch_bounds__(256) void head_k(const float* __restrict__ ctx,
        const float* __restrict__ sw, const float* __restrict__ sbb,
        const float* __restrict__ dw, const float* __restrict__ dbb,
        float* __restrict__ sig, float* __restrict__ dbo) {
    int w = threadIdx.x >> 6, lane = threadIdx.x & 63;
    int row = blockIdx.x * 4 + w;
    const float* xr = ctx + (size_t)row * D_;
    float4 xa = *(const float4*)(xr + lane * 8);
    float4 xb = *(const float4*)(xr + lane * 8 + 4);
    float4 wa = *(const float4*)(sw + lane * 8);
    float4 wb = *(const float4*)(sw + lane * 8 + 4);
    float sacc = xa.x * wa.x + xa.y * wa.y + xa.z * wa.z + xa.w * wa.w +
                 xb.x * wb.x + xb.y * wb.y + xb.z * wb.z + xb.w * wb.w;
    float xs[8] = {xa.x, xa.y, xa.z, xa.w, xb.x, xb.y, xb.z, xb.w};
    float d_[8] = {};
    const float* dr = dw + (size_t)lane * 8 * NH_;
#pragma unroll
    for (int i = 0; i < 8; ++i)
#pragma unroll
        for (int hh = 0; hh < 8; ++hh) d_[hh] += xs[i] * dr[i * NH_ + hh];
    for (int o = 32; o; o >>= 1) {
        sacc += __shfl_down(sacc, o);
#pragma unroll
        for (int hh = 0; hh < 8; ++hh) d_[hh] += __shfl_down(d_[hh], o);
    }
    if (lane == 0) {
        float z = sacc + sbb[0];
        sig[row] = 0.03f + 0.32f / (1.0f + __expf(-z));
        float* dd = dbo + (size_t)row * NH_;
#pragma unroll
        for (int hh = 0; hh < 8; ++hh) dd[hh] = d_[hh] + dbb[hh];
    }
}

// ---------------------------------------------------------------------------
// Staged MFMA flash attention. Block = (b,h,64 t), 4 waves x 16 t.
// K/V chunks (32 s) staged cooperatively via global_load_lds into slab
// layouts (conflict-free frag reads), double-buffered 2-phase.
// Swapped QK^T: P[s][t] = mfma(K,Q); PV: O[d][t] = mfma(Vt,P); col=t=lane&15
// -> softmax state per-lane. Geometry via LDS tables (-2x,-2y,|s|^2).
// Q pre-scaled by COMPAT; mask folded by zeroing Q + grow=0 + A=-1e4.
__global__ __launch_bounds__(256) void attn_k(
    const u16* __restrict__ Q, const u16* __restrict__ K,
    const u16* __restrict__ Vt, const float* __restrict__ sig,
    const float* __restrict__ dbl, const float* __restrict__ bev,
    const float* __restrict__ sxy, const void* __restrict__ mask,
    const int* __restrict__ mode, u16* __restrict__ OUT,
    float* __restrict__ dbp) {
    int L = blockIdx.x;
    int W = (L & 7) * 128 + (L >> 3);   // XCD swizzle: XCD x owns batch x
    int tt0 = W & 15, h = (W >> 4) & 7, b = W >> 7;
    int tid = threadIdx.x, w = tid >> 6, l = tid & 63;
    int lr = l & 15, g = l >> 4;

    __shared__ u16 Kbuf[2][2048];      // 4 KB: slab gd(0..7) x 32 s x 16B
    __shared__ u16 Vbuf[2][2048];      // 4 KB: slab gs(0..3) x 64 d x 16B
    __shared__ float2 SXY[1024];       // (-2x, -2y)
    __shared__ float  SZ[1024];        // x^2+y^2
    __shared__ u16 P_lds[4][640];      // per-wave P roundtrip
    char* pbase = (char*)&P_lds[w][0];

    const float2* xp = (const float2*)(sxy + (size_t)b * S_ * 2);
#pragma unroll
    for (int j = 0; j < 4; ++j) {
        int idx = tid + 256 * j;
        float2 v = xp[idx];
        SXY[idx] = make_float2(-2.0f * v.x, -2.0f * v.y);
        SZ[idx] = v.x * v.x + v.y * v.y;
    }

    int trow = b * T_ + tt0 * 64 + w * 16 + lr;
    float s_ = sig[trow];
    float bx = bev[(size_t)trow * 2], by = bev[(size_t)trow * 2 + 1];
    float dbv = dbl[(size_t)trow * NH_ + h];
    int md = *mode;
    bool vld = is_valid(mask, md, trow) != 0;
    float grow  = vld ? (-8.0f / fmaxf(s_ * s_, 1e-6f)) : 0.0f;
    float Abase = vld ? grow * (bx * bx + by * by) : -10000.0f;

    const u16* qp = Q + (size_t)trow * 512 + h * 64 + g * 8;
    short8 q0 = *(const short8*)qp;
    short8 q1 = *(const short8*)(qp + 32);
    if (!vld) { q0 = short8{}; q1 = short8{}; }

    const u16* Kp = K + (size_t)b * S_ * 512 + h * 64;
    const u16* Vp = Vt + (size_t)(b * 8 + h) * 64 * 1024;

    auto stageKV = [&](int buf, int s0) {
        {   // K: 256 granules, 1 issue/thread
            int gd = tid >> 5, s = tid & 31;
            g2l16((char*)Kbuf[buf] + (size_t)tid * 16,
                  Kp + (size_t)(s0 + s) * 512 + gd * 8);
        }
        {   // V: 256 granules
            int gs = tid >> 6, d = tid & 63;
            g2l16((char*)Vbuf[buf] + (size_t)tid * 16,
                  Vp + (size_t)d * 1024 + s0 + gs * 8);
        }
    };

    float m_st = dbv, l_st = 1.0f;
    f32x4 o0 = {}, o1 = {}, o2 = {}, o3 = {};

    stageKV(0, 0);
    __syncthreads();
    int cur = 0;
    for (int c = 0; c < 32; ++c) {
        int s0c = c * 32;
        if (c < 31) stageKV(cur ^ 1, s0c + 32);

        const char* Kc = (const char*)Kbuf[cur];
        const char* Vc = (const char*)Vbuf[cur];
        short8 k00 = *(const short8*)(Kc + (0 + g) * 512 + lr * 16);
        short8 k01 = *(const short8*)(Kc + (4 + g) * 512 + lr * 16);
        short8 k10 = *(const short8*)(Kc + (0 + g) * 512 + (16 + lr) * 16);
        short8 k11 = *(const short8*)(Kc + (4 + g) * 512 + (16 + lr) * 16);
        short8 vf0 = *(const short8*)(Vc + g * 1024 + (0 * 16 + lr) * 16);
        short8 vf1 = *(const short8*)(Vc + g * 1024 + (1 * 16 + lr) * 16);
        short8 vf2 = *(const short8*)(Vc + g * 1024 + (2 * 16 + lr) * 16);
        short8 vf3 = *(const short8*)(Vc + g * 1024 + (3 * 16 + lr) * 16);

        f32x4 z4 = {};
        f32x4 p0 = __builtin_amdgcn_mfma_f32_16x16x32_bf16(k00, q0, z4, 0, 0, 0);
        p0 = __builtin_amdgcn_mfma_f32_16x16x32_bf16(k01, q1, p0, 0, 0, 0);
        f32x4 p1 = __builtin_amdgcn_mfma_f32_16x16x32_bf16(k10, q0, z4, 0, 0, 0);
        p1 = __builtin_amdgcn_mfma_f32_16x16x32_bf16(k11, q1, p1, 0, 0, 0);

        float pe[8];
        float cmax = -3.0e38f;
#pragma unroll
        for (int half = 0; half < 2; ++half) {
            int sl = s0c + half * 16 + 4 * g;
            float4 xy01 = *(const float4*)&SXY[sl];
            float4 xy23 = *(const float4*)&SXY[sl + 2];
            float4 zz   = *(const float4*)&SZ[sl];
            float X[4] = {xy01.x, xy01.z, xy23.x, xy23.z};
            float Y[4] = {xy01.y, xy01.w, xy23.y, xy23.w};
            float Z[4] = {zz.x, zz.y, zz.z, zz.w};
#pragma unroll
            for (int i2 = 0; i2 < 4; ++i2) {
                float pv = half ? p1[i2] : p0[i2];
                float wg = fmaf(bx, X[i2], fmaf(by, Y[i2], Z[i2]));
                float lg = fmaf(grow, wg, pv + Abase);
                pe[half * 4 + i2] = lg;
                cmax = fmaxf(cmax, lg);
            }
        }
        cmax = fmaxf(cmax, __shfl_xor(cmax, 16));
        cmax = fmaxf(cmax, __shfl_xor(cmax, 32));

        if (!__all(cmax <= m_st + 8.0f)) {      // defer-max (T13)
            float m_new = fmaxf(m_st, cmax);
            float scl = __expf(m_st - m_new);
            l_st *= scl;
            o0 *= scl; o1 *= scl; o2 *= scl; o3 *= scl;
            m_st = m_new;
        }
        float ps = 0.0f;
#pragma unroll
        for (int r = 0; r < 8; ++r) { pe[r] = __expf(pe[r] - m_st); ps += pe[r]; }
        ps += __shfl_xor(ps, 16);
        ps += __shfl_xor(ps, 32);
        l_st += ps;

        // P -> LDS (bf16 [t][s], 80B stride) -> B-fragment
        uint2 w0; w0.x = pack2(pe[0], pe[1]); w0.y = pack2(pe[2], pe[3]);
        uint2 w1; w1.x = pack2(pe[4], pe[5]); w1.y = pack2(pe[6], pe[7]);
        *(uint2*)(pbase + lr * 80 + g * 8)      = w0;
        *(uint2*)(pbase + lr * 80 + 32 + g * 8) = w1;
        union { uint4 u; short8 s8; } pf;
        pf.u = *(uint4*)(pbase + lr * 80 + g * 16);

        o0 = __builtin_amdgcn_mfma_f32_16x16x32_bf16(vf0, pf.s8, o0, 0, 0, 0);
        o1 = __builtin_amdgcn_mfma_f32_16x16x32_bf16(vf1, pf.s8, o1, 0, 0, 0);
        o2 = __builtin_amdgcn_mfma_f32_16x16x32_bf16(vf2, pf.s8, o2, 0, 0, 0);
        o3 = __builtin_amdgcn_mfma_f32_16x16x32_bf16(vf3, pf.s8, o3, 0, 0, 0);

        __syncthreads();
        cur ^= 1;
    }

    float inv = 1.0f / l_st;
    u16* ob = OUT + (size_t)trow * 512 + h * 64;
    {
        uint2 pk;
        pk.x = pack2(o0[0] * inv, o0[1] * inv); pk.y = pack2(o0[2] * inv, o0[3] * inv);
        *(uint2*)(ob + 0 * 16 + 4 * g) = pk;
        pk.x = pack2(o1[0] * inv, o1[1] * inv); pk.y = pack2(o1[2] * inv, o1[3] * inv);
        *(uint2*)(ob + 1 * 16 + 4 * g) = pk;
        pk.x = pack2(o2[0] * inv, o2[1] * inv); pk.y = pack2(o2[2] * inv, o2[3] * inv);
        *(uint2*)(ob + 2 * 16 + 4 * g) = pk;
        pk.x = pack2(o3[0] * inv, o3[1] * inv); pk.y = pack2(o3[2] * inv, o3[3] * inv);
        *(uint2*)(ob + 3 * 16 + 4 * g) = pk;
    }
    if (g == 0) dbp[(size_t)trow * NH_ + h] = __expf(dbv - m_st) * inv;
}

// ---------------------------------------------------------------------------
// confidence + invalid-loss partials
__global__ __launch_bounds__(256) void conf_k(const float* __restrict__ dbp,
                                              const void* __restrict__ mask,
                                              const int* __restrict__ mode,
                                              float* __restrict__ confout,
                                              float* __restrict__ scal) {
    int row = blockIdx.x * 256 + threadIdx.x;
    const float* dr = dbp + (size_t)row * NH_;
    float s = 0;
#pragma unroll
    for (int h = 0; h < 8; ++h) s += dr[h];
    float cf = 1.0f - s * (1.0f / NH_);
    confout[row] = cf;
    int md = *mode;
    float inv = is_valid(mask, md, row) ? 0.0f : 1.0f;
    float a = cf * inv, bs = inv;
    __shared__ float ra[4], rb[4];
    for (int o = 32; o; o >>= 1) { a += __shfl_down(a, o); bs += __shfl_down(bs, o); }
    int wid = threadIdx.x >> 6, lane = threadIdx.x & 63;
    if (lane == 0) { ra[wid] = a; rb[wid] = bs; }
    __syncthreads();
    if (threadIdx.x == 0) {
        float ta = 0, tb = 0;
        for (int w = 0; w < 4; ++w) { ta += ra[w]; tb += rb[w]; }
        atomicAdd(&scal[0], ta);
        atomicAdd(&scal[1], tb);
    }
}

// epilogue: transpose RF (B,T,C)->(B,C,T); out0 = ff + conf*rf; out1 = rf
__global__ __launch_bounds__(256) void final_k(const float* __restrict__ ff,
                                               const float* __restrict__ RF,
                                               const float* __restrict__ conf,
                                               float* __restrict__ out0,
                                               float* __restrict__ out1) {
    __shared__ float tile[32][33];
    int t0 = blockIdx.x * 32, c0 = blockIdx.y * 32, b = blockIdx.z;
    int tx = threadIdx.x & 31, ty = threadIdx.x >> 5;
    for (int j = ty; j < 32; j += 8)
        tile[j][tx] = RF[((size_t)b * T_ + t0 + j) * C_ + c0 + tx];
    __syncthreads();
    size_t base = (size_t)b * C_ * T_;
    float cf = conf[b * T_ + t0 + tx];
    for (int i = ty; i < 32; i += 8) {
        size_t idx = base + (size_t)(c0 + i) * T_ + t0 + tx;
        float rf = tile[tx][i];
        out1[idx] = rf;
        out0[idx] = ff[idx] + cf * rf;
    }
}

__global__ void loss_k(const float* __restrict__ scal, float* __restrict__ out) {
    out[0] = scal[0] / fmaxf(scal[1], 1.0f) * 0.05f;
}

// ---------------------------------------------------------------------------
extern "C" void kernel_launch(void* const* d_in, const int* in_sizes, int n_in,
                              void* d_out, int out_size, void* d_ws, size_t ws_size,
                              hipStream_t stream) {
    const float* front_feat = (const float*)d_in[0];
    const float* sat_tokens = (const float*)d_in[1];
    const float* sat_xy     = (const float*)d_in[2];
    const float* bev_xy     = (const float*)d_in[3];
    const void*  mask       = d_in[4];
    const float* plucker    = (const float*)d_in[5];
    const float* fa_w = (const float*)d_in[6];
    const float* fa_b = (const float*)d_in[7];
    const float* fa_g = (const float*)d_in[8];
    const float* fa_lb = (const float*)d_in[9];
    const float* sa_w = (const float*)d_in[10];
    const float* sa_b = (const float*)d_in[11];
    const float* sa_g = (const float*)d_in[12];
    const float* sa_lb = (const float*)d_in[13];
    const float* q_w = (const float*)d_in[14];
    const float* q_b = (const float*)d_in[15];
    const float* k_w = (const float*)d_in[16];
    const float* k_b = (const float*)d_in[17];
    const float* v_w = (const float*)d_in[18];
    const float* v_b = (const float*)d_in[19];
    const float* pl_w1 = (const float*)d_in[20];
    const float* pl_b1 = (const float*)d_in[21];
    const float* pl_w2 = (const float*)d_in[22];
    const float* pl_b2 = (const float*)d_in[23];
    const float* sig_w = (const float*)d_in[24];
    const float* sig_b = (const float*)d_in[25];
    const float* db_w = (const float*)d_in[26];
    const float* db_b = (const float*)d_in[27];
    const float* out_w = (const float*)d_in[28];
    const float* out_b = (const float*)d_in[29];

    char* w8 = (char*)d_ws;
    float* F0 = (float*)w8;                                   // 16 MB f32
    u16* H0 = (u16*)(w8 + 16777216ull);                       // 8 MB bf16 slots
    u16* H1 = (u16*)(w8 + 16777216ull + 8388608ull * 1);
    u16* H2 = (u16*)(w8 + 16777216ull + 8388608ull * 2);
    u16* H3 = (u16*)(w8 + 16777216ull + 8388608ull * 3);
    u16* H4 = (u16*)(w8 + 16777216ull + 8388608ull * 4);
    u16* WT = (u16*)(w8 + 16777216ull + 8388608ull * 5);      // 7 x 0.5 MB
    char* sm = w8 + 16777216ull + 8388608ull * 5 + 3670016ull;
    float* w_sigma = (float*)sm;
    float* w_db    = w_sigma + BT_;
    float* w_dbp   = w_db + (size_t)BT_ * NH_;
    float* w_scal  = w_dbp + (size_t)BT_ * NH_;
    int*   w_mode  = (int*)(w_scal + 2);

    u16* Wfa = WT;                 u16* Wpl2 = WT + 262144ull * 1;
    u16* Wq  = WT + 262144ull * 2; u16* Wsa  = WT + 262144ull * 3;
    u16* Wk  = WT + 262144ull * 4; u16* Wv   = WT + 262144ull * 5;
    u16* Wo  = WT + 262144ull * 6;

    float* out0 = (float*)d_out;
    float* out1 = out0 + (size_t)B_ * C_ * T_;
    float* outc = out1 + (size_t)B_ * C_ * T_;
    float* outl = outc + (size_t)B_ * T_;

    dim3 blk(256);
    dim3 g_tr(32, 16, 8);
    dim3 g_mm(512);

    mode_k<<<1, blk, 0, stream>>>((const unsigned int*)mask, 2048, w_mode, w_scal);
    wt_t_k<<<dim3(16, 16, 7), blk, 0, stream>>>(fa_w, pl_w2, q_w, sa_w, k_w, v_w, out_w, WT);
    front_transpose_k<<<g_tr, blk, 0, stream>>>(front_feat, H0);
    // E = LN(front_flat @ fa_w + fa_b)
    mm_k<0><<<g_mm, blk, 0, stream>>>(H0, Wfa, fa_b, nullptr, F0);
    ln_bf_k<<<BT_, blk, 0, stream>>>(F0, fa_g, fa_lb, H1);
    // SAT -> bf16
    cvt_k<<<(BT_ * D_ / 8 + 255) / 256, blk, 0, stream>>>(sat_tokens, H0, BT_ * D_ / 8);
    // PLH
    plh_k<<<dim3(BT_, 2), blk, 0, stream>>>(plucker, pl_w1, pl_b1, H2);
    // CTX = PLH @ pl_w2 + pl_b2 + E  (f32)
    mm_k<2><<<g_mm, blk, 0, stream>>>(H2, Wpl2, pl_b2, H1, F0);
    // sigma + dustbin heads (fused, one CTX pass)
    head_k<<<BT_ / 4, blk, 0, stream>>>(F0, sig_w, sig_b, db_w, db_b, w_sigma, w_db);
    // Q (bf16, pre-scaled by COMPAT_SCALE/sqrt(HD))
    mm_k<4><<<g_mm, blk, 0, stream>>>(H1, Wq, q_b, nullptr, H2);
    // SE = LN(sat @ sa_w + sa_b)
    mm_k<0><<<g_mm, blk, 0, stream>>>(H0, Wsa, sa_b, nullptr, F0);
    ln_bf_k<<<BT_, blk, 0, stream>>>(F0, sa_g, sa_lb, H3);
    // K (bf16), Vt (bf16 transposed per-head)
    mm_k<1><<<g_mm, blk, 0, stream>>>(H3, Wk, k_b, nullptr, H1);
    mm_k<3><<<g_mm, blk, 0, stream>>>(H3, Wv, v_b, nullptr, H4);
    // attention
    attn_k<<<dim3(1024), blk, 0, stream>>>(
        H2, H1, H4, w_sigma, w_db, bev_xy, sat_xy, mask, w_mode, H0, w_dbp);
    // RF = read @ out_w + out_b (f32)
    mm_k<0><<<g_mm, blk, 0, stream>>>(H0, Wo, out_b, nullptr, F0);
    conf_k<<<BT_ / 256, blk, 0, stream>>>(w_dbp, mask, w_mode, outc, w_scal);
    final_k<<<g_tr, blk, 0, stream>>>(front_feat, F0, outc, out0, out1);
    loss_k<<<1, 1, 0, stream>>>(w_scal, outl);
}

// Round 4
// 239.959 us; speedup vs baseline: 3.9185x; 1.0408x over previous
//
#include <hip/hip_runtime.h>

typedef unsigned short u16;
typedef __attribute__((ext_vector_type(8))) short short8;   // 8 bf16 = 4 VGPR
typedef __attribute__((ext_vector_type(4))) float f32x4;    // MFMA acc

// Problem constants
constexpr int B_  = 8;
constexpr int C_  = 512;
constexpr int T_  = 1024;   // H*W
constexpr int S_  = 1024;
constexpr int D_  = 512;
constexpr int NH_ = 8;
constexpr int BT_ = B_ * T_;   // 8192
constexpr float INVLN2 = 1.44269504088896340736f;
// COMPAT_SCALE/sqrt(HD) * 1/ln2  (exp2-domain logits)
constexpr float QSCALE2 = 0.0125f * INVLN2;

// single-instruction f32x2 -> packed bf16x2 (RNE), T12 recipe
__device__ __forceinline__ unsigned pack2(float lo, float hi) {
    unsigned r;
    asm("v_cvt_pk_bf16_f32 %0, %1, %2" : "=v"(r) : "v"(lo), "v"(hi));
    return r;
}
__device__ __forceinline__ u16 f2bf(float x) {
    return (u16)pack2(x, x);
}
__device__ __forceinline__ float bf2f(u16 h) {
    union { unsigned u; float f; } v; v.u = ((unsigned)h) << 16;
    return v.f;
}
__device__ __forceinline__ float fexp2(float x) {   // 2^x, one v_exp_f32
    float r;
    asm("v_exp_f32 %0, %1" : "=v"(r) : "v"(x));
    return r;
}

// async global->LDS 16B
typedef __attribute__((address_space(3))) unsigned int lds_u32;
typedef const __attribute__((address_space(1))) unsigned int glob_u32;
__device__ __forceinline__ void g2l16(void* l, const void* g) {
    __builtin_amdgcn_global_load_lds((glob_u32*)g, (lds_u32*)l, 16, 0, 0);
}

// ---------------------------------------------------------------------------
// mask mode detect (int32 / f32 / bytes)
__device__ __forceinline__ int is_valid(const void* mask, int mode, int idx) {
    if (mode == 0) return ((const int*)mask)[idx] != 0;
    if (mode == 1) return ((const float*)mask)[idx] != 0.0f;
    return ((const unsigned char*)mask)[idx] != 0;
}

__global__ void mode_k(const unsigned int* __restrict__ m, int nwords,
                       int* __restrict__ mode, float* __restrict__ scal) {
    __shared__ int bad_i, bad_f;
    if (threadIdx.x == 0) { bad_i = 0; bad_f = 0; }
    __syncthreads();
    for (int i = threadIdx.x; i < nwords; i += 256) {
        unsigned v = m[i];
        if (v > 1u) bad_i = 1;
        if (v != 0u && v != 0x3f800000u) bad_f = 1;
    }
    __syncthreads();
    if (threadIdx.x == 0) {
        *mode = (!bad_i) ? 0 : ((!bad_f) ? 1 : 2);
        scal[0] = 0.0f; scal[1] = 0.0f;
    }
}

// ---------------------------------------------------------------------------
// weight transpose+convert: W[512][512] f32 -> Wt[n][k] bf16. z picks weight.
__global__ __launch_bounds__(256) void wt_t_k(const float* a0, const float* a1,
        const float* a2, const float* a3, const float* a4, const float* a5,
        const float* a6, u16* __restrict__ dstbase) {
    const float* srcs[7] = {a0, a1, a2, a3, a4, a5, a6};
    const float* src = srcs[blockIdx.z];
    u16* d = dstbase + (size_t)blockIdx.z * 512 * 512;
    __shared__ float t[32][33];
    int k0 = blockIdx.x * 32, n0 = blockIdx.y * 32;
    int tx = threadIdx.x & 31, ty = threadIdx.x >> 5;
    for (int i = ty; i < 32; i += 8)
        t[i][tx] = src[(size_t)(k0 + i) * 512 + n0 + tx];
    __syncthreads();
    for (int i = ty; i < 32; i += 8)
        d[(size_t)(n0 + i) * 512 + k0 + tx] = f2bf(t[tx][i]);
}

// front_feat (B,C,T) f32 -> front_flat (B*T, C) bf16
__global__ __launch_bounds__(256) void front_transpose_k(const float* __restrict__ in,
                                                         u16* __restrict__ out) {
    __shared__ float tile[32][33];
    int t0 = blockIdx.x * 32, c0 = blockIdx.y * 32, b = blockIdx.z;
    int tx = threadIdx.x & 31, ty = threadIdx.x >> 5;
    const float* ip = in + (size_t)b * C_ * T_;
    for (int i = ty; i < 32; i += 8)
        tile[i][tx] = ip[(size_t)(c0 + i) * T_ + t0 + tx];
    __syncthreads();
    u16* op = out + (size_t)b * T_ * C_;
    for (int i = ty; i < 32; i += 8)
        op[(size_t)(t0 + i) * C_ + c0 + tx] = f2bf(tile[tx][i]);
}

// f32 -> bf16 elementwise
__global__ __launch_bounds__(256) void cvt_k(const float* __restrict__ in,
                                             u16* __restrict__ out, int n8) {
    int i = blockIdx.x * 256 + threadIdx.x;
    if (i >= n8) return;
    const float4* p = (const float4*)(in + (size_t)i * 8);
    float4 a = p[0], b = p[1];
    uint4 o;
    o.x = pack2(a.x, a.y); o.y = pack2(a.z, a.w);
    o.z = pack2(b.x, b.y); o.w = pack2(b.z, b.w);
    *(uint4*)(out + (size_t)i * 8) = o;
}

// ---------------------------------------------------------------------------
// bf16 MFMA GEMM, LDS-staged double-buffered 2-phase. Tile 128x64, BK=64.
// MODE: 0 f32 out; 1 bf16 out; 2 f32 out + bf16 addend; 3 Vt bf16 scatter;
//       4 bf16 * QSCALE2; 5 fused read-feat epilogue (transposed out0/out1).
template <int MODE>
__global__ __launch_bounds__(256) void mm_k(const u16* __restrict__ A,
                                            const u16* __restrict__ Bt,
                                            const float* __restrict__ bias,
                                            const u16* __restrict__ addend,
                                            void* __restrict__ Cout,
                                            const float* __restrict__ ffp,
                                            const float* __restrict__ confp,
                                            float* __restrict__ out1p) {
    __shared__ u16 As[2][8192];   // 16 KB each
    __shared__ u16 Bs[2][4096];   // 8 KB each
    int tid = threadIdx.x, w = tid >> 6, l = tid & 63;
    int lr = l & 15, g = l >> 4;
    int L = blockIdx.x;
    int W = (L & 7) * 64 + (L >> 3);          // XCD swizzle (512 % 8 == 0)
    int m0 = (W >> 3) * 128, n0 = (W & 7) * 64;
    int wr = w >> 1, wc = w & 1;

    f32x4 acc[4][2] = {};

    auto stage = [&](int buf, int k0) {
#pragma unroll
        for (int j = 0; j < 4; ++j) {        // A: 1024 granules
            int i = tid + 256 * j;
            int gg = i >> 7, row = i & 127;
            g2l16((char*)As[buf] + (size_t)i * 16,
                  A + (size_t)(m0 + row) * 512 + k0 + gg * 8);
        }
#pragma unroll
        for (int j = 0; j < 2; ++j) {        // B: 512 granules
            int i = tid + 256 * j;
            int gg = i >> 6, n = i & 63;
            g2l16((char*)Bs[buf] + (size_t)i * 16,
                  Bt + (size_t)(n0 + n) * 512 + k0 + gg * 8);
        }
    };

    stage(0, 0);
    __syncthreads();
    int cur = 0;
    for (int t = 0; t < 8; ++t) {
        if (t < 7) stage(cur ^ 1, (t + 1) * 64);
        const char* Ab = (const char*)As[cur];
        const char* Bb = (const char*)Bs[cur];
#pragma unroll
        for (int kk = 0; kk < 2; ++kk) {
            short8 af[4], bf[2];
#pragma unroll
            for (int m = 0; m < 4; ++m)
                af[m] = *(const short8*)(Ab + (kk * 4 + g) * 2048 +
                                         (wr * 64 + m * 16 + lr) * 16);
#pragma unroll
            for (int n = 0; n < 2; ++n)
                bf[n] = *(const short8*)(Bb + (kk * 4 + g) * 1024 +
                                         (wc * 32 + n * 16 + lr) * 16);
#pragma unroll
            for (int m = 0; m < 4; ++m)
#pragma unroll
                for (int n = 0; n < 2; ++n)
                    acc[m][n] = __builtin_amdgcn_mfma_f32_16x16x32_bf16(
                        af[m], bf[n], acc[m][n], 0, 0, 0);
        }
        __syncthreads();
        cur ^= 1;
    }

    float bs[2] = {bias[n0 + wc * 32 + lr], bias[n0 + wc * 32 + 16 + lr]};
#pragma unroll
    for (int m = 0; m < 4; ++m) {
#pragma unroll
        for (int n = 0; n < 2; ++n) {
            int R0  = m0 + wr * 64 + m * 16 + 4 * g;
            int col = n0 + wc * 32 + n * 16 + lr;
            if constexpr (MODE == 3) {
                int bb = R0 >> 10, ss = R0 & 1023, hh = col >> 6, dd = col & 63;
                uint2 pk;
                pk.x = pack2(acc[m][n][0] + bs[n], acc[m][n][1] + bs[n]);
                pk.y = pack2(acc[m][n][2] + bs[n], acc[m][n][3] + bs[n]);
                u16* dst = (u16*)Cout + ((size_t)(bb * 8 + hh) * 64 + dd) * 1024 + ss;
                *(uint2*)dst = pk;
            } else if constexpr (MODE == 5) {
                int bb = R0 >> 10, t0p = R0 & 1023;
                size_t base = (size_t)bb * C_ * T_ + (size_t)col * T_ + t0p;
                float4 rf;
                rf.x = acc[m][n][0] + bs[n]; rf.y = acc[m][n][1] + bs[n];
                rf.z = acc[m][n][2] + bs[n]; rf.w = acc[m][n][3] + bs[n];
                float4 ffv = *(const float4*)(ffp + base);
                float4 cfv = *(const float4*)(confp + bb * T_ + t0p);
                float4 o0;
                o0.x = ffv.x + cfv.x * rf.x; o0.y = ffv.y + cfv.y * rf.y;
                o0.z = ffv.z + cfv.z * rf.z; o0.w = ffv.w + cfv.w * rf.w;
                *(float4*)(out1p + base) = rf;
                *(float4*)((float*)Cout + base) = o0;
            } else {
#pragma unroll
                for (int j = 0; j < 4; ++j) {
                    int row = R0 + j;
                    float v = acc[m][n][j] + bs[n];
                    if constexpr (MODE == 0) {
                        ((float*)Cout)[(size_t)row * 512 + col] = v;
                    } else if constexpr (MODE == 2) {
                        v += bf2f(addend[(size_t)row * 512 + col]);
                        ((float*)Cout)[(size_t)row * 512 + col] = v;
                    } else if constexpr (MODE == 4) {
                        ((u16*)Cout)[(size_t)row * 512 + col] = f2bf(v * QSCALE2);
                    } else {   // MODE 1
                        ((u16*)Cout)[(size_t)row * 512 + col] = f2bf(v);
                    }
                }
            }
        }
    }
}

// ---------------------------------------------------------------------------
// Dual GEMM: K = SE @ Wk + kb (bf16 row-major), V = SE @ Wv + vb (Vt scatter).
// A staged once; both B panels staged. Same tile geometry as mm_k.
__global__ __launch_bounds__(256) void mm2_k(const u16* __restrict__ A,
                                             const u16* __restrict__ Kt,
                                             const u16* __restrict__ Vt,
                                             const float* __restrict__ kb,
                                             const float* __restrict__ vb,
                                             u16* __restrict__ Kout,
                                             u16* __restrict__ Vout) {
    __shared__ u16 As[2][8192];
    __shared__ u16 Bks[2][4096];
    __shared__ u16 Bvs[2][4096];
    int tid = threadIdx.x, w = tid >> 6, l = tid & 63;
    int lr = l & 15, g = l >> 4;
    int L = blockIdx.x;
    int W = (L & 7) * 64 + (L >> 3);
    int m0 = (W >> 3) * 128, n0 = (W & 7) * 64;
    int wr = w >> 1, wc = w & 1;

    f32x4 ak[4][2] = {}, av[4][2] = {};

    auto stage = [&](int buf, int k0) {
#pragma unroll
        for (int j = 0; j < 4; ++j) {
            int i = tid + 256 * j;
            int gg = i >> 7, row = i & 127;
            g2l16((char*)As[buf] + (size_t)i * 16,
                  A + (size_t)(m0 + row) * 512 + k0 + gg * 8);
        }
#pragma unroll
        for (int j = 0; j < 2; ++j) {
            int i = tid + 256 * j;
            int gg = i >> 6, n = i & 63;
            g2l16((char*)Bks[buf] + (size_t)i * 16,
                  Kt + (size_t)(n0 + n) * 512 + k0 + gg * 8);
            g2l16((char*)Bvs[buf] + (size_t)i * 16,
                  Vt + (size_t)(n0 + n) * 512 + k0 + gg * 8);
        }
    };

    stage(0, 0);
    __syncthreads();
    int cur = 0;
    for (int t = 0; t < 8; ++t) {
        if (t < 7) stage(cur ^ 1, (t + 1) * 64);
        const char* Ab  = (const char*)As[cur];
        const char* Bkb = (const char*)Bks[cur];
        const char* Bvb = (const char*)Bvs[cur];
#pragma unroll
        for (int kk = 0; kk < 2; ++kk) {
            short8 af[4], bk[2], bv[2];
#pragma unroll
            for (int m = 0; m < 4; ++m)
                af[m] = *(const short8*)(Ab + (kk * 4 + g) * 2048 +
                                         (wr * 64 + m * 16 + lr) * 16);
#pragma unroll
            for (int n = 0; n < 2; ++n) {
                bk[n] = *(const short8*)(Bkb + (kk * 4 + g) * 1024 +
                                         (wc * 32 + n * 16 + lr) * 16);
                bv[n] = *(const short8*)(Bvb + (kk * 4 + g) * 1024 +
                                         (wc * 32 + n * 16 + lr) * 16);
            }
#pragma unroll
            for (int m = 0; m < 4; ++m)
#pragma unroll
                for (int n = 0; n < 2; ++n) {
                    ak[m][n] = __builtin_amdgcn_mfma_f32_16x16x32_bf16(
                        af[m], bk[n], ak[m][n], 0, 0, 0);
                    av[m][n] = __builtin_amdgcn_mfma_f32_16x16x32_bf16(
                        af[m], bv[n], av[m][n], 0, 0, 0);
                }
        }
        __syncthreads();
        cur ^= 1;
    }

    float kbs[2] = {kb[n0 + wc * 32 + lr], kb[n0 + wc * 32 + 16 + lr]};
    float vbs[2] = {vb[n0 + wc * 32 + lr], vb[n0 + wc * 32 + 16 + lr]};
#pragma unroll
    for (int m = 0; m < 4; ++m) {
#pragma unroll
        for (int n = 0; n < 2; ++n) {
            int R0  = m0 + wr * 64 + m * 16 + 4 * g;
            int col = n0 + wc * 32 + n * 16 + lr;
            // K row-major bf16
#pragma unroll
            for (int j = 0; j < 4; ++j)
                Kout[(size_t)(R0 + j) * 512 + col] = f2bf(ak[m][n][j] + kbs[n]);
            // V transposed scatter
            int bb = R0 >> 10, ss = R0 & 1023, hh = col >> 6, dd = col & 63;
            uint2 pk;
            pk.x = pack2(av[m][n][0] + vbs[n], av[m][n][1] + vbs[n]);
            pk.y = pack2(av[m][n][2] + vbs[n], av[m][n][3] + vbs[n]);
            u16* dst = Vout + ((size_t)(bb * 8 + hh) * 64 + dd) * 1024 + ss;
            *(uint2*)dst = pk;
        }
    }
}

// ---------------------------------------------------------------------------
// LayerNorm rows of 512: f32 in -> bf16 out
__global__ __launch_bounds__(256) void ln_bf_k(const float* __restrict__ X,
                                               const float* __restrict__ g,
                                               const float* __restrict__ bv,
                                               u16* __restrict__ out) {
    int row = blockIdx.x, tid = threadIdx.x;
    const float* xr = X + (size_t)row * D_;
    float x0 = xr[tid], x1 = xr[tid + 256];
    float s = x0 + x1, sq = x0 * x0 + x1 * x1;
    __shared__ float rs[4], rq[4];
    for (int o = 32; o; o >>= 1) { s += __shfl_down(s, o); sq += __shfl_down(sq, o); }
    int wid = tid >> 6, lane = tid & 63;
    if (lane == 0) { rs[wid] = s; rq[wid] = sq; }
    __syncthreads();
    if (tid == 0) {
        float ts = 0, tq = 0;
        for (int w = 0; w < 4; ++w) { ts += rs[w]; tq += rq[w]; }
        rs[0] = ts; rq[0] = tq;
    }
    __syncthreads();
    float mean = rs[0] * (1.0f / D_);
    float var  = rq[0] * (1.0f / D_) - mean * mean;
    float r = rsqrtf(var + 1e-5f);
    u16* orow = out + (size_t)row * D_;
    orow[tid]       = f2bf((x0 - mean) * r * g[tid] + bv[tid]);
    orow[tid + 256] = f2bf((x1 - mean) * r * g[tid + 256] + bv[tid + 256]);
}

// plucker hidden: silu(plucker @ pl_w1 + pl_b1) -> bf16
__global__ __launch_bounds__(256) void plh_k(const float* __restrict__ pl,
                                             const float* __restrict__ w1,
                                             const float* __restrict__ b1,
                                             u16* __restrict__ out) {
    int m = blockIdx.x;
    int n = blockIdx.y * 256 + threadIdx.x;
    const float* p = pl + (size_t)m * 6;
    float acc = b1[n];
#pragma unroll
    for (int j = 0; j < 6; ++j) acc += p[j] * w1[j * D_ + n];
    out[(size_t)m * D_ + n] = f2bf(acc / (1.0f + __expf(-acc)));
}

// fused sigma + dustbin heads (one CTX pass). One wave per row.
__global__ __launch_bounds__(256) void head_k(const float* __restrict__ ctx,
        const float* __restrict__ sw, const float* __restrict__ sbb,
        const float* __restrict__ dw, const float* __restrict__ dbb,
        float* __restrict__ sig, float* __restrict__ dbo) {
    int w = threadIdx.x >> 6, lane = threadIdx.x & 63;
    int row = blockIdx.x * 4 + w;
    const float* xr = ctx + (size_t)row * D_;
    float4 xa = *(const float4*)(xr + lane * 8);
    float4 xb = *(const float4*)(xr + lane * 8 + 4);
    float4 wa = *(const float4*)(sw + lane * 8);
    float4 wb = *(const float4*)(sw + lane * 8 + 4);
    float sacc = xa.x * wa.x + xa.y * wa.y + xa.z * wa.z + xa.w * wa.w +
                 xb.x * wb.x + xb.y * wb.y + xb.z * wb.z + xb.w * wb.w;
    float xs[8] = {xa.x, xa.y, xa.z, xa.w, xb.x, xb.y, xb.z, xb.w};
    float d_[8] = {};
    const float* dr = dw + (size_t)lane * 8 * NH_;
#pragma unroll
    for (int i = 0; i < 8; ++i)
#pragma unroll
        for (int hh = 0; hh < 8; ++hh) d_[hh] += xs[i] * dr[i * NH_ + hh];
    for (int o = 32; o; o >>= 1) {
        sacc += __shfl_down(sacc, o);
#pragma unroll
        for (int hh = 0; hh < 8; ++hh) d_[hh] += __shfl_down(d_[hh], o);
    }
    if (lane == 0) {
        float z = sacc + sbb[0];
        sig[row] = 0.03f + 0.32f / (1.0f + __expf(-z));
        float* dd = dbo + (size_t)row * NH_;
#pragma unroll
        for (int hh = 0; hh < 8; ++hh) dd[hh] = d_[hh] + dbb[hh];
    }
}

// ---------------------------------------------------------------------------
// Staged MFMA flash attention, KVBLK=64, exp2-domain softmax.
// Block = (b,h,64 t), 4 waves x 16 t. Swapped QK^T: P[s][t]=mfma(K,Q);
// PV: O[d][t]=mfma(Vt,P); col=t=lane&15 -> per-lane softmax state.
// Q pre-scaled by COMPAT*INVLN2; geometry in log2 domain.
__global__ __launch_bounds__(256) void attn_k(
    const u16* __restrict__ Q, const u16* __restrict__ K,
    const u16* __restrict__ Vt, const float* __restrict__ sig,
    const float* __restrict__ dbl, const float* __restrict__ bev,
    const float* __restrict__ sxy, const void* __restrict__ mask,
    const int* __restrict__ mode, u16* __restrict__ OUT,
    float* __restrict__ dbp) {
    int L = blockIdx.x;
    int W = (L & 7) * 128 + (L >> 3);   // XCD swizzle
    int tt0 = W & 15, h = (W >> 4) & 7, b = W >> 7;
    int tid = threadIdx.x, w = tid >> 6, l = tid & 63;
    int lr = l & 15, g = l >> 4;

    __shared__ u16 Kbuf[2][4096];      // 8 KB: slab gd(0..7) x 64 s x 16B
    __shared__ u16 Vbuf[2][4096];      // 8 KB: slab gs(0..7) x 64 d x 16B
    __shared__ float2 SXY[1024];       // (-2x, -2y)
    __shared__ float  SZ[1024];        // x^2+y^2
    __shared__ u16 P_lds[4][1152];     // per-wave P roundtrip, 144B row stride
    char* pbase = (char*)&P_lds[w][0];

    const float2* xp = (const float2*)(sxy + (size_t)b * S_ * 2);
#pragma unroll
    for (int j = 0; j < 4; ++j) {
        int idx = tid + 256 * j;
        float2 v = xp[idx];
        SXY[idx] = make_float2(-2.0f * v.x, -2.0f * v.y);
        SZ[idx] = v.x * v.x + v.y * v.y;
    }

    int trow = b * T_ + tt0 * 64 + w * 16 + lr;
    float s_ = sig[trow];
    float bx = bev[(size_t)trow * 2], by = bev[(size_t)trow * 2 + 1];
    float dbv2 = dbl[(size_t)trow * NH_ + h] * INVLN2;
    int md = *mode;
    bool vld = is_valid(mask, md, trow) != 0;
    // log2-domain geometric factor: -8/ln2 / max(sigma^2,1e-6)
    float grow  = vld ? (-11.5415603271117f / fmaxf(s_ * s_, 1e-6f)) : 0.0f;
    float Abase = vld ? grow * (bx * bx + by * by) : -10000.0f;

    const u16* qp = Q + (size_t)trow * 512 + h * 64 + g * 8;
    short8 q0 = *(const short8*)qp;
    short8 q1 = *(const short8*)(qp + 32);
    if (!vld) { q0 = short8{}; q1 = short8{}; }

    const u16* Kp = K + (size_t)b * S_ * 512 + h * 64;
    const u16* Vp = Vt + (size_t)(b * 8 + h) * 64 * 1024;

    auto stageKV = [&](int buf, int s0) {
#pragma unroll
        for (int j = 0; j < 2; ++j) {   // K: 512 granules (8 gd x 64 s)
            int i = tid + 256 * j;
            int gd = i >> 6, s = i & 63;
            g2l16((char*)Kbuf[buf] + (size_t)i * 16,
                  Kp + (size_t)(s0 + s) * 512 + gd * 8);
        }
#pragma unroll
        for (int j = 0; j < 2; ++j) {   // V: 512 granules (8 gs x 64 d)
            int i = tid + 256 * j;
            int gs = i >> 6, d = i & 63;
            g2l16((char*)Vbuf[buf] + (size_t)i * 16,
                  Vp + (size_t)d * 1024 + s0 + gs * 8);
        }
    };

    float m_st = dbv2, l_st = 1.0f;
    f32x4 o0 = {}, o1 = {}, o2 = {}, o3 = {};

    stageKV(0, 0);
    __syncthreads();
    int cur = 0;
    for (int c = 0; c < 16; ++c) {
        int s0c = c * 64;
        if (c < 15) stageKV(cur ^ 1, s0c + 64);

        const char* Kc = (const char*)Kbuf[cur];
        const char* Vc = (const char*)Vbuf[cur];

        // QK^T: 4 s-subtiles x 2 k-halves
        f32x4 p[4];
        f32x4 z4 = {};
#pragma unroll
        for (int sub = 0; sub < 4; ++sub) {
            short8 kf0 = *(const short8*)(Kc + (0 + g) * 1024 + (sub * 16 + lr) * 16);
            short8 kf1 = *(const short8*)(Kc + (4 + g) * 1024 + (sub * 16 + lr) * 16);
            p[sub] = __builtin_amdgcn_mfma_f32_16x16x32_bf16(kf0, q0, z4, 0, 0, 0);
            p[sub] = __builtin_amdgcn_mfma_f32_16x16x32_bf16(kf1, q1, p[sub], 0, 0, 0);
        }

        // logits (log2 domain) + online softmax; lane holds 16 s-values
        float pe[16];
        float cmax = -3.0e38f;
#pragma unroll
        for (int sub = 0; sub < 4; ++sub) {
            int sl = s0c + sub * 16 + 4 * g;
            float4 xy01 = *(const float4*)&SXY[sl];
            float4 xy23 = *(const float4*)&SXY[sl + 2];
            float4 zz   = *(const float4*)&SZ[sl];
            float X[4] = {xy01.x, xy01.z, xy23.x, xy23.z};
            float Y[4] = {xy01.y, xy01.w, xy23.y, xy23.w};
            float Z[4] = {zz.x, zz.y, zz.z, zz.w};
#pragma unroll
            for (int i2 = 0; i2 < 4; ++i2) {
                float wg = fmaf(bx, X[i2], fmaf(by, Y[i2], Z[i2]));
                float lg = fmaf(grow, wg, p[sub][i2] + Abase);
                pe[sub * 4 + i2] = lg;
                cmax = fmaxf(cmax, lg);
            }
        }
        cmax = fmaxf(cmax, __shfl_xor(cmax, 16));
        cmax = fmaxf(cmax, __shfl_xor(cmax, 32));

        if (!__all(cmax <= m_st + 11.5f)) {      // defer-max (log2 domain)
            float m_new = fmaxf(m_st, cmax);
            float scl = fexp2(m_st - m_new);
            l_st *= scl;
            o0 *= scl; o1 *= scl; o2 *= scl; o3 *= scl;
            m_st = m_new;
        }
        float ps = 0.0f;
#pragma unroll
        for (int r = 0; r < 16; ++r) { pe[r] = fexp2(pe[r] - m_st); ps += pe[r]; }
        ps += __shfl_xor(ps, 16);
        ps += __shfl_xor(ps, 32);
        l_st += ps;

        // P -> LDS bf16 [t=lr][s], row stride 144B -> B-fragments
#pragma unroll
        for (int sub = 0; sub < 4; ++sub) {
            uint2 pk;
            pk.x = pack2(pe[sub * 4 + 0], pe[sub * 4 + 1]);
            pk.y = pack2(pe[sub * 4 + 2], pe[sub * 4 + 3]);
            *(uint2*)(pbase + lr * 144 + sub * 32 + g * 8) = pk;
        }
        union { uint4 u; short8 s8; } pf0, pf1;
        pf0.u = *(uint4*)(pbase + lr * 144 + g * 16);
        pf1.u = *(uint4*)(pbase + lr * 144 + 64 + g * 16);

        // PV: 4 d-frags x 2 k-chunks
        short8 vf;
        vf = *(const short8*)(Vc + (0 + g) * 1024 + (0 * 16 + lr) * 16);
        o0 = __builtin_amdgcn_mfma_f32_16x16x32_bf16(vf, pf0.s8, o0, 0, 0, 0);
        vf = *(const short8*)(Vc + (4 + g) * 1024 + (0 * 16 + lr) * 16);
        o0 = __builtin_amdgcn_mfma_f32_16x16x32_bf16(vf, pf1.s8, o0, 0, 0, 0);
        vf = *(const short8*)(Vc + (0 + g) * 1024 + (1 * 16 + lr) * 16);
        o1 = __builtin_amdgcn_mfma_f32_16x16x32_bf16(vf, pf0.s8, o1, 0, 0, 0);
        vf = *(const short8*)(Vc + (4 + g) * 1024 + (1 * 16 + lr) * 16);
        o1 = __builtin_amdgcn_mfma_f32_16x16x32_bf16(vf, pf1.s8, o1, 0, 0, 0);
        vf = *(const short8*)(Vc + (0 + g) * 1024 + (2 * 16 + lr) * 16);
        o2 = __builtin_amdgcn_mfma_f32_16x16x32_bf16(vf, pf0.s8, o2, 0, 0, 0);
        vf = *(const short8*)(Vc + (4 + g) * 1024 + (2 * 16 + lr) * 16);
        o2 = __builtin_amdgcn_mfma_f32_16x16x32_bf16(vf, pf1.s8, o2, 0, 0, 0);
        vf = *(const short8*)(Vc + (0 + g) * 1024 + (3 * 16 + lr) * 16);
        o3 = __builtin_amdgcn_mfma_f32_16x16x32_bf16(vf, pf0.s8, o3, 0, 0, 0);
        vf = *(const short8*)(Vc + (4 + g) * 1024 + (3 * 16 + lr) * 16);
        o3 = __builtin_amdgcn_mfma_f32_16x16x32_bf16(vf, pf1.s8, o3, 0, 0, 0);

        __syncthreads();
        cur ^= 1;
    }

    float inv = 1.0f / l_st;
    u16* ob = OUT + (size_t)trow * 512 + h * 64;
    {
        uint2 pk;
        pk.x = pack2(o0[0] * inv, o0[1] * inv); pk.y = pack2(o0[2] * inv, o0[3] * inv);
        *(uint2*)(ob + 0 * 16 + 4 * g) = pk;
        pk.x = pack2(o1[0] * inv, o1[1] * inv); pk.y = pack2(o1[2] * inv, o1[3] * inv);
        *(uint2*)(ob + 1 * 16 + 4 * g) = pk;
        pk.x = pack2(o2[0] * inv, o2[1] * inv); pk.y = pack2(o2[2] * inv, o2[3] * inv);
        *(uint2*)(ob + 2 * 16 + 4 * g) = pk;
        pk.x = pack2(o3[0] * inv, o3[1] * inv); pk.y = pack2(o3[2] * inv, o3[3] * inv);
        *(uint2*)(ob + 3 * 16 + 4 * g) = pk;
    }
    if (g == 0) dbp[(size_t)trow * NH_ + h] = fexp2(dbv2 - m_st) * inv;
}

// ---------------------------------------------------------------------------
// confidence + invalid-loss partials
__global__ __launch_bounds__(256) void conf_k(const float* __restrict__ dbp,
                                              const void* __restrict__ mask,
                                              const int* __restrict__ mode,
                                              float* __restrict__ confout,
                                              float* __restrict__ scal) {
    int row = blockIdx.x * 256 + threadIdx.x;
    const float* dr = dbp + (size_t)row * NH_;
    float s = 0;
#pragma unroll
    for (int h = 0; h < 8; ++h) s += dr[h];
    float cf = 1.0f - s * (1.0f / NH_);
    confout[row] = cf;
    int md = *mode;
    float inv = is_valid(mask, md, row) ? 0.0f : 1.0f;
    float a = cf * inv, bs = inv;
    __shared__ float ra[4], rb[4];
    for (int o = 32; o; o >>= 1) { a += __shfl_down(a, o); bs += __shfl_down(bs, o); }
    int wid = threadIdx.x >> 6, lane = threadIdx.x & 63;
    if (lane == 0) { ra[wid] = a; rb[wid] = bs; }
    __syncthreads();
    if (threadIdx.x == 0) {
        float ta = 0, tb = 0;
        for (int w = 0; w < 4; ++w) { ta += ra[w]; tb += rb[w]; }
        atomicAdd(&scal[0], ta);
        atomicAdd(&scal[1], tb);
    }
}

__global__ void loss_k(const float* __restrict__ scal, float* __restrict__ out) {
    out[0] = scal[0] / fmaxf(scal[1], 1.0f) * 0.05f;
}

// ---------------------------------------------------------------------------
extern "C" void kernel_launch(void* const* d_in, const int* in_sizes, int n_in,
                              void* d_out, int out_size, void* d_ws, size_t ws_size,
                              hipStream_t stream) {
    const float* front_feat = (const float*)d_in[0];
    const float* sat_tokens = (const float*)d_in[1];
    const float* sat_xy     = (const float*)d_in[2];
    const float* bev_xy     = (const float*)d_in[3];
    const void*  mask       = d_in[4];
    const float* plucker    = (const float*)d_in[5];
    const float* fa_w = (const float*)d_in[6];
    const float* fa_b = (const float*)d_in[7];
    const float* fa_g = (const float*)d_in[8];
    const float* fa_lb = (const float*)d_in[9];
    const float* sa_w = (const float*)d_in[10];
    const float* sa_b = (const float*)d_in[11];
    const float* sa_g = (const float*)d_in[12];
    const float* sa_lb = (const float*)d_in[13];
    const float* q_w = (const float*)d_in[14];
    const float* q_b = (const float*)d_in[15];
    const float* k_w = (const float*)d_in[16];
    const float* k_b = (const float*)d_in[17];
    const float* v_w = (const float*)d_in[18];
    const float* v_b = (const float*)d_in[19];
    const float* pl_w1 = (const float*)d_in[20];
    const float* pl_b1 = (const float*)d_in[21];
    const float* pl_w2 = (const float*)d_in[22];
    const float* pl_b2 = (const float*)d_in[23];
    const float* sig_w = (const float*)d_in[24];
    const float* sig_b = (const float*)d_in[25];
    const float* db_w = (const float*)d_in[26];
    const float* db_b = (const float*)d_in[27];
    const float* out_w = (const float*)d_in[28];
    const float* out_b = (const float*)d_in[29];

    char* w8 = (char*)d_ws;
    float* F0 = (float*)w8;                                   // 16 MB f32
    u16* H0 = (u16*)(w8 + 16777216ull);                       // 8 MB bf16 slots
    u16* H1 = (u16*)(w8 + 16777216ull + 8388608ull * 1);
    u16* H2 = (u16*)(w8 + 16777216ull + 8388608ull * 2);
    u16* H3 = (u16*)(w8 + 16777216ull + 8388608ull * 3);
    u16* H4 = (u16*)(w8 + 16777216ull + 8388608ull * 4);
    u16* WT = (u16*)(w8 + 16777216ull + 8388608ull * 5);      // 7 x 0.5 MB
    char* sm = w8 + 16777216ull + 8388608ull * 5 + 3670016ull;
    float* w_sigma = (float*)sm;
    float* w_db    = w_sigma + BT_;
    float* w_dbp   = w_db + (size_t)BT_ * NH_;
    float* w_scal  = w_dbp + (size_t)BT_ * NH_;
    int*   w_mode  = (int*)(w_scal + 2);

    u16* Wfa = WT;                 u16* Wpl2 = WT + 262144ull * 1;
    u16* Wq  = WT + 262144ull * 2; u16* Wsa  = WT + 262144ull * 3;
    u16* Wk  = WT + 262144ull * 4; u16* Wv   = WT + 262144ull * 5;
    u16* Wo  = WT + 262144ull * 6;

    float* out0 = (float*)d_out;
    float* out1 = out0 + (size_t)B_ * C_ * T_;
    float* outc = out1 + (size_t)B_ * C_ * T_;
    float* outl = outc + (size_t)B_ * T_;

    dim3 blk(256);
    dim3 g_tr(32, 16, 8);
    dim3 g_mm(512);

    mode_k<<<1, blk, 0, stream>>>((const unsigned int*)mask, 2048, w_mode, w_scal);
    wt_t_k<<<dim3(16, 16, 7), blk, 0, stream>>>(fa_w, pl_w2, q_w, sa_w, k_w, v_w, out_w, WT);
    front_transpose_k<<<g_tr, blk, 0, stream>>>(front_feat, H0);
    // E = LN(front_flat @ fa_w + fa_b)
    mm_k<0><<<g_mm, blk, 0, stream>>>(H0, Wfa, fa_b, nullptr, F0, nullptr, nullptr, nullptr);
    ln_bf_k<<<BT_, blk, 0, stream>>>(F0, fa_g, fa_lb, H1);
    // SAT -> bf16
    cvt_k<<<(BT_ * D_ / 8 + 255) / 256, blk, 0, stream>>>(sat_tokens, H0, BT_ * D_ / 8);
    // PLH
    plh_k<<<dim3(BT_, 2), blk, 0, stream>>>(plucker, pl_w1, pl_b1, H2);
    // CTX = PLH @ pl_w2 + pl_b2 + E  (f32)
    mm_k<2><<<g_mm, blk, 0, stream>>>(H2, Wpl2, pl_b2, H1, F0, nullptr, nullptr, nullptr);
    // sigma + dustbin heads
    head_k<<<BT_ / 4, blk, 0, stream>>>(F0, sig_w, sig_b, db_w, db_b, w_sigma, w_db);
    // Q (bf16, pre-scaled by COMPAT*INVLN2)
    mm_k<4><<<g_mm, blk, 0, stream>>>(H1, Wq, q_b, nullptr, H2, nullptr, nullptr, nullptr);
    // SE = LN(sat @ sa_w + sa_b)
    mm_k<0><<<g_mm, blk, 0, stream>>>(H0, Wsa, sa_b, nullptr, F0, nullptr, nullptr, nullptr);
    ln_bf_k<<<BT_, blk, 0, stream>>>(F0, sa_g, sa_lb, H3);
    // K (bf16) + Vt (bf16 transposed) fused dual-GEMM
    mm2_k<<<g_mm, blk, 0, stream>>>(H3, Wk, Wv, k_b, v_b, H1, H4);
    // attention
    attn_k<<<dim3(1024), blk, 0, stream>>>(
        H2, H1, H4, w_sigma, w_db, bev_xy, sat_xy, mask, w_mode, H0, w_dbp);
    // confidence (needed by fused RF epilogue)
    conf_k<<<BT_ / 256, blk, 0, stream>>>(w_dbp, mask, w_mode, outc, w_scal);
    // RF = read @ out_w + out_b, fused transpose + out0/out1 epilogue
    mm_k<5><<<g_mm, blk, 0, stream>>>(H0, Wo, out_b, nullptr, out0, front_feat, outc, out1);
    loss_k<<<1, 1, 0, stream>>>(w_scal, outl);
}

// Round 5
// 212.073 us; speedup vs baseline: 4.4337x; 1.1315x over previous
//
#include <hip/hip_runtime.h>

typedef unsigned short u16;
typedef __attribute__((ext_vector_type(8))) short short8;   // 8 bf16 = 4 VGPR
typedef __attribute__((ext_vector_type(4))) float f32x4;    // MFMA acc

// Problem constants
constexpr int B_  = 8;
constexpr int C_  = 512;
constexpr int T_  = 1024;   // H*W
constexpr int S_  = 1024;
constexpr int D_  = 512;
constexpr int NH_ = 8;
constexpr int BT_ = B_ * T_;   // 8192
constexpr float INVLN2 = 1.44269504088896340736f;
constexpr float QSCALE2 = 0.0125f * INVLN2;   // COMPAT/sqrt(HD) / ln2

// single-instruction f32x2 -> packed bf16x2 (RNE)
__device__ __forceinline__ unsigned pack2(float lo, float hi) {
    unsigned r;
    asm("v_cvt_pk_bf16_f32 %0, %1, %2" : "=v"(r) : "v"(lo), "v"(hi));
    return r;
}
__device__ __forceinline__ u16 f2bf(float x) {
    return (u16)pack2(x, x);
}
__device__ __forceinline__ float bf2f(u16 h) {
    union { unsigned u; float f; } v; v.u = ((unsigned)h) << 16;
    return v.f;
}
__device__ __forceinline__ float fexp2(float x) {   // 2^x
    float r;
    asm("v_exp_f32 %0, %1" : "=v"(r) : "v"(x));
    return r;
}

// async global->LDS 16B
typedef __attribute__((address_space(3))) unsigned int lds_u32;
typedef const __attribute__((address_space(1))) unsigned int glob_u32;
__device__ __forceinline__ void g2l16(void* l, const void* g) {
    __builtin_amdgcn_global_load_lds((glob_u32*)g, (lds_u32*)l, 16, 0, 0);
}

// ---------------------------------------------------------------------------
// mask mode detect (int32 / f32 / bytes)
__device__ __forceinline__ int is_valid(const void* mask, int mode, int idx) {
    if (mode == 0) return ((const int*)mask)[idx] != 0;
    if (mode == 1) return ((const float*)mask)[idx] != 0.0f;
    return ((const unsigned char*)mask)[idx] != 0;
}

__global__ void mode_k(const unsigned int* __restrict__ m, int nwords,
                       int* __restrict__ mode, float* __restrict__ scal) {
    __shared__ int bad_i, bad_f;
    if (threadIdx.x == 0) { bad_i = 0; bad_f = 0; }
    __syncthreads();
    for (int i = threadIdx.x; i < nwords; i += 256) {
        unsigned v = m[i];
        if (v > 1u) bad_i = 1;
        if (v != 0u && v != 0x3f800000u) bad_f = 1;
    }
    __syncthreads();
    if (threadIdx.x == 0) {
        *mode = (!bad_i) ? 0 : ((!bad_f) ? 1 : 2);
        scal[0] = 0.0f; scal[1] = 0.0f;
    }
}

// ---------------------------------------------------------------------------
// weight transpose+convert: W[512][512] f32 -> Wt[n][k] bf16. z picks weight.
__global__ __launch_bounds__(256) void wt_t_k(const float* a0, const float* a1,
        const float* a2, const float* a3, const float* a4, const float* a5,
        const float* a6, u16* __restrict__ dstbase) {
    const float* srcs[7] = {a0, a1, a2, a3, a4, a5, a6};
    const float* src = srcs[blockIdx.z];
    u16* d = dstbase + (size_t)blockIdx.z * 512 * 512;
    __shared__ float t[32][33];
    int k0 = blockIdx.x * 32, n0 = blockIdx.y * 32;
    int tx = threadIdx.x & 31, ty = threadIdx.x >> 5;
    for (int i = ty; i < 32; i += 8)
        t[i][tx] = src[(size_t)(k0 + i) * 512 + n0 + tx];
    __syncthreads();
    for (int i = ty; i < 32; i += 8)
        d[(size_t)(n0 + i) * 512 + k0 + tx] = f2bf(t[tx][i]);
}

// front_feat (B,C,T) f32 -> front_flat (B*T, C) bf16
__global__ __launch_bounds__(256) void front_transpose_k(const float* __restrict__ in,
                                                         u16* __restrict__ out) {
    __shared__ float tile[32][33];
    int t0 = blockIdx.x * 32, c0 = blockIdx.y * 32, b = blockIdx.z;
    int tx = threadIdx.x & 31, ty = threadIdx.x >> 5;
    const float* ip = in + (size_t)b * C_ * T_;
    for (int i = ty; i < 32; i += 8)
        tile[i][tx] = ip[(size_t)(c0 + i) * T_ + t0 + tx];
    __syncthreads();
    u16* op = out + (size_t)b * T_ * C_;
    for (int i = ty; i < 32; i += 8)
        op[(size_t)(t0 + i) * C_ + c0 + tx] = f2bf(tile[tx][i]);
}

// f32 -> bf16 elementwise
__global__ __launch_bounds__(256) void cvt_k(const float* __restrict__ in,
                                             u16* __restrict__ out, int n8) {
    int i = blockIdx.x * 256 + threadIdx.x;
    if (i >= n8) return;
    const float4* p = (const float4*)(in + (size_t)i * 8);
    float4 a = p[0], b = p[1];
    uint4 o;
    o.x = pack2(a.x, a.y); o.y = pack2(a.z, a.w);
    o.z = pack2(b.x, b.y); o.w = pack2(b.z, b.w);
    *(uint4*)(out + (size_t)i * 8) = o;
}

// ---------------------------------------------------------------------------
// bf16 MFMA GEMM, LDS-staged double-buffered 2-phase. Tile 128x64, BK=64.
// MODE: 1 bf16 out; 2 bf16 out + bf16 addend; 3 Vt bf16 scatter;
//       4 bf16 * QSCALE2; 5 fused read-feat epilogue (transposed out0/out1).
template <int MODE>
__global__ __launch_bounds__(256) void mm_k(const u16* __restrict__ A,
                                            const u16* __restrict__ Bt,
                                            const float* __restrict__ bias,
                                            const u16* __restrict__ addend,
                                            void* __restrict__ Cout,
                                            const float* __restrict__ ffp,
                                            const float* __restrict__ confp,
                                            float* __restrict__ out1p) {
    __shared__ u16 As[2][8192];   // 16 KB each
    __shared__ u16 Bs[2][4096];   // 8 KB each
    int tid = threadIdx.x, w = tid >> 6, l = tid & 63;
    int lr = l & 15, g = l >> 4;
    int L = blockIdx.x;
    int W = (L & 7) * 64 + (L >> 3);          // XCD swizzle (512 % 8 == 0)
    int m0 = (W >> 3) * 128, n0 = (W & 7) * 64;
    int wr = w >> 1, wc = w & 1;

    f32x4 acc[4][2] = {};

    auto stage = [&](int buf, int k0) {
#pragma unroll
        for (int j = 0; j < 4; ++j) {        // A: 1024 granules
            int i = tid + 256 * j;
            int gg = i >> 7, row = i & 127;
            g2l16((char*)As[buf] + (size_t)i * 16,
                  A + (size_t)(m0 + row) * 512 + k0 + gg * 8);
        }
#pragma unroll
        for (int j = 0; j < 2; ++j) {        // B: 512 granules
            int i = tid + 256 * j;
            int gg = i >> 6, n = i & 63;
            g2l16((char*)Bs[buf] + (size_t)i * 16,
                  Bt + (size_t)(n0 + n) * 512 + k0 + gg * 8);
        }
    };

    stage(0, 0);
    __syncthreads();
    int cur = 0;
    for (int t = 0; t < 8; ++t) {
        if (t < 7) stage(cur ^ 1, (t + 1) * 64);
        const char* Ab = (const char*)As[cur];
        const char* Bb = (const char*)Bs[cur];
#pragma unroll
        for (int kk = 0; kk < 2; ++kk) {
            short8 af[4], bf[2];
#pragma unroll
            for (int m = 0; m < 4; ++m)
                af[m] = *(const short8*)(Ab + (kk * 4 + g) * 2048 +
                                         (wr * 64 + m * 16 + lr) * 16);
#pragma unroll
            for (int n = 0; n < 2; ++n)
                bf[n] = *(const short8*)(Bb + (kk * 4 + g) * 1024 +
                                         (wc * 32 + n * 16 + lr) * 16);
            __builtin_amdgcn_s_setprio(1);
#pragma unroll
            for (int m = 0; m < 4; ++m)
#pragma unroll
                for (int n = 0; n < 2; ++n)
                    acc[m][n] = __builtin_amdgcn_mfma_f32_16x16x32_bf16(
                        af[m], bf[n], acc[m][n], 0, 0, 0);
            __builtin_amdgcn_s_setprio(0);
        }
        __syncthreads();
        cur ^= 1;
    }

    float bs[2] = {bias[n0 + wc * 32 + lr], bias[n0 + wc * 32 + 16 + lr]};
#pragma unroll
    for (int m = 0; m < 4; ++m) {
#pragma unroll
        for (int n = 0; n < 2; ++n) {
            int R0  = m0 + wr * 64 + m * 16 + 4 * g;
            int col = n0 + wc * 32 + n * 16 + lr;
            if constexpr (MODE == 3) {
                int bb = R0 >> 10, ss = R0 & 1023, hh = col >> 6, dd = col & 63;
                uint2 pk;
                pk.x = pack2(acc[m][n][0] + bs[n], acc[m][n][1] + bs[n]);
                pk.y = pack2(acc[m][n][2] + bs[n], acc[m][n][3] + bs[n]);
                u16* dst = (u16*)Cout + ((size_t)(bb * 8 + hh) * 64 + dd) * 1024 + ss;
                *(uint2*)dst = pk;
            } else if constexpr (MODE == 5) {
                int bb = R0 >> 10, t0p = R0 & 1023;
                size_t base = (size_t)bb * C_ * T_ + (size_t)col * T_ + t0p;
                float4 rf;
                rf.x = acc[m][n][0] + bs[n]; rf.y = acc[m][n][1] + bs[n];
                rf.z = acc[m][n][2] + bs[n]; rf.w = acc[m][n][3] + bs[n];
                float4 ffv = *(const float4*)(ffp + base);
                float4 cfv = *(const float4*)(confp + bb * T_ + t0p);
                float4 o0;
                o0.x = ffv.x + cfv.x * rf.x; o0.y = ffv.y + cfv.y * rf.y;
                o0.z = ffv.z + cfv.z * rf.z; o0.w = ffv.w + cfv.w * rf.w;
                *(float4*)(out1p + base) = rf;
                *(float4*)((float*)Cout + base) = o0;
            } else {
#pragma unroll
                for (int j = 0; j < 4; ++j) {
                    int row = R0 + j;
                    float v = acc[m][n][j] + bs[n];
                    if constexpr (MODE == 2) v += bf2f(addend[(size_t)row * 512 + col]);
                    if constexpr (MODE == 4) v *= QSCALE2;
                    ((u16*)Cout)[(size_t)row * 512 + col] = f2bf(v);
                }
            }
        }
    }
}

// ---------------------------------------------------------------------------
// Dual GEMM: K = SE @ Wk + kb (bf16 row-major), V = SE @ Wv + vb (Vt scatter).
__global__ __launch_bounds__(256) void mm2_k(const u16* __restrict__ A,
                                             const u16* __restrict__ Kt,
                                             const u16* __restrict__ Vt,
                                             const float* __restrict__ kb,
                                             const float* __restrict__ vb,
                                             u16* __restrict__ Kout,
                                             u16* __restrict__ Vout) {
    __shared__ u16 As[2][8192];
    __shared__ u16 Bks[2][4096];
    __shared__ u16 Bvs[2][4096];
    int tid = threadIdx.x, w = tid >> 6, l = tid & 63;
    int lr = l & 15, g = l >> 4;
    int L = blockIdx.x;
    int W = (L & 7) * 64 + (L >> 3);
    int m0 = (W >> 3) * 128, n0 = (W & 7) * 64;
    int wr = w >> 1, wc = w & 1;

    f32x4 ak[4][2] = {}, av[4][2] = {};

    auto stage = [&](int buf, int k0) {
#pragma unroll
        for (int j = 0; j < 4; ++j) {
            int i = tid + 256 * j;
            int gg = i >> 7, row = i & 127;
            g2l16((char*)As[buf] + (size_t)i * 16,
                  A + (size_t)(m0 + row) * 512 + k0 + gg * 8);
        }
#pragma unroll
        for (int j = 0; j < 2; ++j) {
            int i = tid + 256 * j;
            int gg = i >> 6, n = i & 63;
            g2l16((char*)Bks[buf] + (size_t)i * 16,
                  Kt + (size_t)(n0 + n) * 512 + k0 + gg * 8);
            g2l16((char*)Bvs[buf] + (size_t)i * 16,
                  Vt + (size_t)(n0 + n) * 512 + k0 + gg * 8);
        }
    };

    stage(0, 0);
    __syncthreads();
    int cur = 0;
    for (int t = 0; t < 8; ++t) {
        if (t < 7) stage(cur ^ 1, (t + 1) * 64);
        const char* Ab  = (const char*)As[cur];
        const char* Bkb = (const char*)Bks[cur];
        const char* Bvb = (const char*)Bvs[cur];
#pragma unroll
        for (int kk = 0; kk < 2; ++kk) {
            short8 af[4], bk[2], bv[2];
#pragma unroll
            for (int m = 0; m < 4; ++m)
                af[m] = *(const short8*)(Ab + (kk * 4 + g) * 2048 +
                                         (wr * 64 + m * 16 + lr) * 16);
#pragma unroll
            for (int n = 0; n < 2; ++n) {
                bk[n] = *(const short8*)(Bkb + (kk * 4 + g) * 1024 +
                                         (wc * 32 + n * 16 + lr) * 16);
                bv[n] = *(const short8*)(Bvb + (kk * 4 + g) * 1024 +
                                         (wc * 32 + n * 16 + lr) * 16);
            }
            __builtin_amdgcn_s_setprio(1);
#pragma unroll
            for (int m = 0; m < 4; ++m)
#pragma unroll
                for (int n = 0; n < 2; ++n) {
                    ak[m][n] = __builtin_amdgcn_mfma_f32_16x16x32_bf16(
                        af[m], bk[n], ak[m][n], 0, 0, 0);
                    av[m][n] = __builtin_amdgcn_mfma_f32_16x16x32_bf16(
                        af[m], bv[n], av[m][n], 0, 0, 0);
                }
            __builtin_amdgcn_s_setprio(0);
        }
        __syncthreads();
        cur ^= 1;
    }

    float kbs[2] = {kb[n0 + wc * 32 + lr], kb[n0 + wc * 32 + 16 + lr]};
    float vbs[2] = {vb[n0 + wc * 32 + lr], vb[n0 + wc * 32 + 16 + lr]};
#pragma unroll
    for (int m = 0; m < 4; ++m) {
#pragma unroll
        for (int n = 0; n < 2; ++n) {
            int R0  = m0 + wr * 64 + m * 16 + 4 * g;
            int col = n0 + wc * 32 + n * 16 + lr;
#pragma unroll
            for (int j = 0; j < 4; ++j)
                Kout[(size_t)(R0 + j) * 512 + col] = f2bf(ak[m][n][j] + kbs[n]);
            int bb = R0 >> 10, ss = R0 & 1023, hh = col >> 6, dd = col & 63;
            uint2 pk;
            pk.x = pack2(av[m][n][0] + vbs[n], av[m][n][1] + vbs[n]);
            pk.y = pack2(av[m][n][2] + vbs[n], av[m][n][3] + vbs[n]);
            u16* dst = Vout + ((size_t)(bb * 8 + hh) * 64 + dd) * 1024 + ss;
            *(uint2*)dst = pk;
        }
    }
}

// ---------------------------------------------------------------------------
// LayerNorm rows of 512: bf16 in -> bf16 out (each thread owns elems 2t,2t+1)
__global__ __launch_bounds__(256) void ln_bf_k(const u16* __restrict__ X,
                                               const float* __restrict__ gw,
                                               const float* __restrict__ bw,
                                               u16* __restrict__ out) {
    int row = blockIdx.x, tid = threadIdx.x;
    const unsigned* xr = (const unsigned*)(X + (size_t)row * D_);
    unsigned u = xr[tid];
    float x0 = bf2f((u16)(u & 0xffff)), x1 = bf2f((u16)(u >> 16));
    float s = x0 + x1, sq = x0 * x0 + x1 * x1;
    __shared__ float rs[4], rq[4];
    for (int o = 32; o; o >>= 1) { s += __shfl_down(s, o); sq += __shfl_down(sq, o); }
    int wid = tid >> 6, lane = tid & 63;
    if (lane == 0) { rs[wid] = s; rq[wid] = sq; }
    __syncthreads();
    if (tid == 0) {
        float ts = 0, tq = 0;
        for (int w = 0; w < 4; ++w) { ts += rs[w]; tq += rq[w]; }
        rs[0] = ts; rq[0] = tq;
    }
    __syncthreads();
    float mean = rs[0] * (1.0f / D_);
    float var  = rq[0] * (1.0f / D_) - mean * mean;
    float r = rsqrtf(var + 1e-5f);
    float2 g2 = *(const float2*)(gw + 2 * tid);
    float2 b2 = *(const float2*)(bw + 2 * tid);
    float y0 = (x0 - mean) * r * g2.x + b2.x;
    float y1 = (x1 - mean) * r * g2.y + b2.y;
    ((unsigned*)(out + (size_t)row * D_))[tid] = pack2(y0, y1);
}

// plucker hidden: silu(plucker @ pl_w1 + pl_b1) -> bf16
__global__ __launch_bounds__(256) void plh_k(const float* __restrict__ pl,
                                             const float* __restrict__ w1,
                                             const float* __restrict__ b1,
                                             u16* __restrict__ out) {
    int m = blockIdx.x;
    int n = blockIdx.y * 256 + threadIdx.x;
    const float* p = pl + (size_t)m * 6;
    float acc = b1[n];
#pragma unroll
    for (int j = 0; j < 6; ++j) acc += p[j] * w1[j * D_ + n];
    out[(size_t)m * D_ + n] = f2bf(acc / (1.0f + __expf(-acc)));
}

// fused sigma + dustbin heads from bf16 CTX. One wave per row.
__global__ __launch_bounds__(256) void head_k(const u16* __restrict__ ctx,
        const float* __restrict__ sw, const float* __restrict__ sbb,
        const float* __restrict__ dw, const float* __restrict__ dbb,
        float* __restrict__ sig, float* __restrict__ dbo) {
    int w = threadIdx.x >> 6, lane = threadIdx.x & 63;
    int row = blockIdx.x * 4 + w;
    const u16* xr = ctx + (size_t)row * D_;
    short8 xv = *(const short8*)(xr + lane * 8);
    float xs[8];
#pragma unroll
    for (int i = 0; i < 8; ++i) xs[i] = bf2f((u16)xv[i]);
    float4 wa = *(const float4*)(sw + lane * 8);
    float4 wb = *(const float4*)(sw + lane * 8 + 4);
    float sacc = xs[0] * wa.x + xs[1] * wa.y + xs[2] * wa.z + xs[3] * wa.w +
                 xs[4] * wb.x + xs[5] * wb.y + xs[6] * wb.z + xs[7] * wb.w;
    float d_[8] = {};
    const float* dr = dw + (size_t)lane * 8 * NH_;
#pragma unroll
    for (int i = 0; i < 8; ++i)
#pragma unroll
        for (int hh = 0; hh < 8; ++hh) d_[hh] += xs[i] * dr[i * NH_ + hh];
    for (int o = 32; o; o >>= 1) {
        sacc += __shfl_down(sacc, o);
#pragma unroll
        for (int hh = 0; hh < 8; ++hh) d_[hh] += __shfl_down(d_[hh], o);
    }
    if (lane == 0) {
        float z = sacc + sbb[0];
        sig[row] = 0.03f + 0.32f / (1.0f + __expf(-z));
        float* dd = dbo + (size_t)row * NH_;
#pragma unroll
        for (int hh = 0; hh < 8; ++hh) dd[hh] = d_[hh] + dbb[hh];
    }
}

// ---------------------------------------------------------------------------
// Staged MFMA flash attention, KVBLK=64, exp2 softmax, 512-thread blocks.
// Block = (b,h,128 t), 8 waves x 16 t. K/V dbuf + geo tables shared by all.
// Swapped QK^T: P[s][t]=mfma(K,Q); PV: O[d][t]=mfma(Vt,P); col=t=lane&15.
__global__ __launch_bounds__(512) void attn_k(
    const u16* __restrict__ Q, const u16* __restrict__ K,
    const u16* __restrict__ Vt, const float* __restrict__ sig,
    const float* __restrict__ dbl, const float* __restrict__ bev,
    const float* __restrict__ sxy, const void* __restrict__ mask,
    const int* __restrict__ mode, u16* __restrict__ OUT,
    float* __restrict__ dbp) {
    int L = blockIdx.x;
    int W = (L & 7) * 64 + (L >> 3);   // XCD swizzle: XCD x owns batch x
    int b = W >> 6, h = (W >> 3) & 7, tblk = W & 7;
    int tid = threadIdx.x, w = tid >> 6, l = tid & 63;
    int lr = l & 15, g = l >> 4;

    __shared__ u16 Kbuf[2][4096];      // 8 KB each: slab gd(0..7) x 64 s x 16B
    __shared__ u16 Vbuf[2][4096];      // 8 KB each: slab gs(0..7) x 64 d x 16B
    __shared__ float2 SXY[1024];       // (-2x, -2y)
    __shared__ float  SZ[1024];        // x^2+y^2
    __shared__ u16 P_lds[8][1152];     // per-wave P roundtrip, 144B row stride
    char* pbase = (char*)&P_lds[w][0];

    const float2* xp = (const float2*)(sxy + (size_t)b * S_ * 2);
#pragma unroll
    for (int j = 0; j < 2; ++j) {
        int idx = tid + 512 * j;
        float2 v = xp[idx];
        SXY[idx] = make_float2(-2.0f * v.x, -2.0f * v.y);
        SZ[idx] = v.x * v.x + v.y * v.y;
    }

    int trow = b * T_ + tblk * 128 + w * 16 + lr;
    float s_ = sig[trow];
    float bx = bev[(size_t)trow * 2], by = bev[(size_t)trow * 2 + 1];
    float dbv2 = dbl[(size_t)trow * NH_ + h] * INVLN2;
    int md = *mode;
    bool vld = is_valid(mask, md, trow) != 0;
    float grow  = vld ? (-11.5415603271117f / fmaxf(s_ * s_, 1e-6f)) : 0.0f;
    float Abase = vld ? grow * (bx * bx + by * by) : -10000.0f;

    const u16* qp = Q + (size_t)trow * 512 + h * 64 + g * 8;
    short8 q0 = *(const short8*)qp;
    short8 q1 = *(const short8*)(qp + 32);
    if (!vld) { q0 = short8{}; q1 = short8{}; }

    const u16* Kp = K + (size_t)b * S_ * 512 + h * 64;
    const u16* Vp = Vt + (size_t)(b * 8 + h) * 64 * 1024;

    auto stageKV = [&](int buf, int s0) {
        {   // K: 512 granules (8 gd x 64 s), 1 issue/thread
            int gd = tid >> 6, s = tid & 63;
            g2l16((char*)Kbuf[buf] + (size_t)tid * 16,
                  Kp + (size_t)(s0 + s) * 512 + gd * 8);
        }
        {   // V: 512 granules (8 gs x 64 d)
            int gs = tid >> 6, d = tid & 63;
            g2l16((char*)Vbuf[buf] + (size_t)tid * 16,
                  Vp + (size_t)d * 1024 + s0 + gs * 8);
        }
    };

    float m_st = dbv2, l_st = 1.0f;
    f32x4 o0 = {}, o1 = {}, o2 = {}, o3 = {};

    stageKV(0, 0);
    __syncthreads();
    int cur = 0;
    for (int c = 0; c < 16; ++c) {
        int s0c = c * 64;
        if (c < 15) stageKV(cur ^ 1, s0c + 64);

        const char* Kc = (const char*)Kbuf[cur];
        const char* Vc = (const char*)Vbuf[cur];

        // QK^T: 4 s-subtiles x 2 k-halves
        f32x4 p[4];
        f32x4 z4 = {};
        __builtin_amdgcn_s_setprio(1);
#pragma unroll
        for (int sub = 0; sub < 4; ++sub) {
            short8 kf0 = *(const short8*)(Kc + (0 + g) * 1024 + (sub * 16 + lr) * 16);
            short8 kf1 = *(const short8*)(Kc + (4 + g) * 1024 + (sub * 16 + lr) * 16);
            p[sub] = __builtin_amdgcn_mfma_f32_16x16x32_bf16(kf0, q0, z4, 0, 0, 0);
            p[sub] = __builtin_amdgcn_mfma_f32_16x16x32_bf16(kf1, q1, p[sub], 0, 0, 0);
        }
        __builtin_amdgcn_s_setprio(0);

        // logits (log2 domain) + online softmax; lane holds 16 s-values
        float pe[16];
        float cmax = -3.0e38f;
#pragma unroll
        for (int sub = 0; sub < 4; ++sub) {
            int sl = s0c + sub * 16 + 4 * g;
            float4 xy01 = *(const float4*)&SXY[sl];
            float4 xy23 = *(const float4*)&SXY[sl + 2];
            float4 zz   = *(const float4*)&SZ[sl];
            float X[4] = {xy01.x, xy01.z, xy23.x, xy23.z};
            float Y[4] = {xy01.y, xy01.w, xy23.y, xy23.w};
            float Z[4] = {zz.x, zz.y, zz.z, zz.w};
#pragma unroll
            for (int i2 = 0; i2 < 4; ++i2) {
                float wg = fmaf(bx, X[i2], fmaf(by, Y[i2], Z[i2]));
                float lg = fmaf(grow, wg, p[sub][i2] + Abase);
                pe[sub * 4 + i2] = lg;
                cmax = fmaxf(cmax, lg);
            }
        }
        cmax = fmaxf(cmax, __shfl_xor(cmax, 16));
        cmax = fmaxf(cmax, __shfl_xor(cmax, 32));

        if (!__all(cmax <= m_st + 11.5f)) {      // defer-max (log2 domain)
            float m_new = fmaxf(m_st, cmax);
            float scl = fexp2(m_st - m_new);
            l_st *= scl;
            o0 *= scl; o1 *= scl; o2 *= scl; o3 *= scl;
            m_st = m_new;
        }
        float ps = 0.0f;
#pragma unroll
        for (int r = 0; r < 16; ++r) { pe[r] = fexp2(pe[r] - m_st); ps += pe[r]; }
        ps += __shfl_xor(ps, 16);
        ps += __shfl_xor(ps, 32);
        l_st += ps;

        // P -> LDS bf16 [t=lr][s], row stride 144B -> B-fragments
#pragma unroll
        for (int sub = 0; sub < 4; ++sub) {
            uint2 pk;
            pk.x = pack2(pe[sub * 4 + 0], pe[sub * 4 + 1]);
            pk.y = pack2(pe[sub * 4 + 2], pe[sub * 4 + 3]);
            *(uint2*)(pbase + lr * 144 + sub * 32 + g * 8) = pk;
        }
        union { uint4 u; short8 s8; } pf0, pf1;
        pf0.u = *(uint4*)(pbase + lr * 144 + g * 16);
        pf1.u = *(uint4*)(pbase + lr * 144 + 64 + g * 16);

        // PV: 4 d-frags x 2 k-chunks
        __builtin_amdgcn_s_setprio(1);
        short8 vf;
        vf = *(const short8*)(Vc + (0 + g) * 1024 + (0 * 16 + lr) * 16);
        o0 = __builtin_amdgcn_mfma_f32_16x16x32_bf16(vf, pf0.s8, o0, 0, 0, 0);
        vf = *(const short8*)(Vc + (4 + g) * 1024 + (0 * 16 + lr) * 16);
        o0 = __builtin_amdgcn_mfma_f32_16x16x32_bf16(vf, pf1.s8, o0, 0, 0, 0);
        vf = *(const short8*)(Vc + (0 + g) * 1024 + (1 * 16 + lr) * 16);
        o1 = __builtin_amdgcn_mfma_f32_16x16x32_bf16(vf, pf0.s8, o1, 0, 0, 0);
        vf = *(const short8*)(Vc + (4 + g) * 1024 + (1 * 16 + lr) * 16);
        o1 = __builtin_amdgcn_mfma_f32_16x16x32_bf16(vf, pf1.s8, o1, 0, 0, 0);
        vf = *(const short8*)(Vc + (0 + g) * 1024 + (2 * 16 + lr) * 16);
        o2 = __builtin_amdgcn_mfma_f32_16x16x32_bf16(vf, pf0.s8, o2, 0, 0, 0);
        vf = *(const short8*)(Vc + (4 + g) * 1024 + (2 * 16 + lr) * 16);
        o2 = __builtin_amdgcn_mfma_f32_16x16x32_bf16(vf, pf1.s8, o2, 0, 0, 0);
        vf = *(const short8*)(Vc + (0 + g) * 1024 + (3 * 16 + lr) * 16);
        o3 = __builtin_amdgcn_mfma_f32_16x16x32_bf16(vf, pf0.s8, o3, 0, 0, 0);
        vf = *(const short8*)(Vc + (4 + g) * 1024 + (3 * 16 + lr) * 16);
        o3 = __builtin_amdgcn_mfma_f32_16x16x32_bf16(vf, pf1.s8, o3, 0, 0, 0);
        __builtin_amdgcn_s_setprio(0);

        __syncthreads();
        cur ^= 1;
    }

    float inv = 1.0f / l_st;
    u16* ob = OUT + (size_t)trow * 512 + h * 64;
    {
        uint2 pk;
        pk.x = pack2(o0[0] * inv, o0[1] * inv); pk.y = pack2(o0[2] * inv, o0[3] * inv);
        *(uint2*)(ob + 0 * 16 + 4 * g) = pk;
        pk.x = pack2(o1[0] * inv, o1[1] * inv); pk.y = pack2(o1[2] * inv, o1[3] * inv);
        *(uint2*)(ob + 1 * 16 + 4 * g) = pk;
        pk.x = pack2(o2[0] * inv, o2[1] * inv); pk.y = pack2(o2[2] * inv, o2[3] * inv);
        *(uint2*)(ob + 2 * 16 + 4 * g) = pk;
        pk.x = pack2(o3[0] * inv, o3[1] * inv); pk.y = pack2(o3[2] * inv, o3[3] * inv);
        *(uint2*)(ob + 3 * 16 + 4 * g) = pk;
    }
    if (g == 0) dbp[(size_t)trow * NH_ + h] = fexp2(dbv2 - m_st) * inv;
}

// ---------------------------------------------------------------------------
// confidence + invalid-loss partials
__global__ __launch_bounds__(256) void conf_k(const float* __restrict__ dbp,
                                              const void* __restrict__ mask,
                                              const int* __restrict__ mode,
                                              float* __restrict__ confout,
                                              float* __restrict__ scal) {
    int row = blockIdx.x * 256 + threadIdx.x;
    const float* dr = dbp + (size_t)row * NH_;
    float s = 0;
#pragma unroll
    for (int h = 0; h < 8; ++h) s += dr[h];
    float cf = 1.0f - s * (1.0f / NH_);
    confout[row] = cf;
    int md = *mode;
    float inv = is_valid(mask, md, row) ? 0.0f : 1.0f;
    float a = cf * inv, bs = inv;
    __shared__ float ra[4], rb[4];
    for (int o = 32; o; o >>= 1) { a += __shfl_down(a, o); bs += __shfl_down(bs, o); }
    int wid = threadIdx.x >> 6, lane = threadIdx.x & 63;
    if (lane == 0) { ra[wid] = a; rb[wid] = bs; }
    __syncthreads();
    if (threadIdx.x == 0) {
        float ta = 0, tb = 0;
        for (int w = 0; w < 4; ++w) { ta += ra[w]; tb += rb[w]; }
        atomicAdd(&scal[0], ta);
        atomicAdd(&scal[1], tb);
    }
}

__global__ void loss_k(const float* __restrict__ scal, float* __restrict__ out) {
    out[0] = scal[0] / fmaxf(scal[1], 1.0f) * 0.05f;
}

// ---------------------------------------------------------------------------
extern "C" void kernel_launch(void* const* d_in, const int* in_sizes, int n_in,
                              void* d_out, int out_size, void* d_ws, size_t ws_size,
                              hipStream_t stream) {
    const float* front_feat = (const float*)d_in[0];
    const float* sat_tokens = (const float*)d_in[1];
    const float* sat_xy     = (const float*)d_in[2];
    const float* bev_xy     = (const float*)d_in[3];
    const void*  mask       = d_in[4];
    const float* plucker    = (const float*)d_in[5];
    const float* fa_w = (const float*)d_in[6];
    const float* fa_b = (const float*)d_in[7];
    const float* fa_g = (const float*)d_in[8];
    const float* fa_lb = (const float*)d_in[9];
    const float* sa_w = (const float*)d_in[10];
    const float* sa_b = (const float*)d_in[11];
    const float* sa_g = (const float*)d_in[12];
    const float* sa_lb = (const float*)d_in[13];
    const float* q_w = (const float*)d_in[14];
    const float* q_b = (const float*)d_in[15];
    const float* k_w = (const float*)d_in[16];
    const float* k_b = (const float*)d_in[17];
    const float* v_w = (const float*)d_in[18];
    const float* v_b = (const float*)d_in[19];
    const float* pl_w1 = (const float*)d_in[20];
    const float* pl_b1 = (const float*)d_in[21];
    const float* pl_w2 = (const float*)d_in[22];
    const float* pl_b2 = (const float*)d_in[23];
    const float* sig_w = (const float*)d_in[24];
    const float* sig_b = (const float*)d_in[25];
    const float* db_w = (const float*)d_in[26];
    const float* db_b = (const float*)d_in[27];
    const float* out_w = (const float*)d_in[28];
    const float* out_b = (const float*)d_in[29];

    char* w8 = (char*)d_ws;
    u16* H0 = (u16*)(w8);                        // 8 MB bf16 slots
    u16* H1 = (u16*)(w8 + 8388608ull * 1);
    u16* H2 = (u16*)(w8 + 8388608ull * 2);
    u16* H3 = (u16*)(w8 + 8388608ull * 3);
    u16* H4 = (u16*)(w8 + 8388608ull * 4);
    u16* H5 = (u16*)(w8 + 8388608ull * 5);
    u16* H6 = (u16*)(w8 + 8388608ull * 6);
    u16* WT = (u16*)(w8 + 8388608ull * 7);       // 7 x 0.5 MB
    char* sm = w8 + 8388608ull * 7 + 3670016ull;
    float* w_sigma = (float*)sm;
    float* w_db    = w_sigma + BT_;
    float* w_dbp   = w_db + (size_t)BT_ * NH_;
    float* w_scal  = w_dbp + (size_t)BT_ * NH_;
    int*   w_mode  = (int*)(w_scal + 2);

    u16* Wfa = WT;                 u16* Wpl2 = WT + 262144ull * 1;
    u16* Wq  = WT + 262144ull * 2; u16* Wsa  = WT + 262144ull * 3;
    u16* Wk  = WT + 262144ull * 4; u16* Wv   = WT + 262144ull * 5;
    u16* Wo  = WT + 262144ull * 6;

    float* out0 = (float*)d_out;
    float* out1 = out0 + (size_t)B_ * C_ * T_;
    float* outc = out1 + (size_t)B_ * C_ * T_;
    float* outl = outc + (size_t)B_ * T_;

    dim3 blk(256);
    dim3 g_tr(32, 16, 8);
    dim3 g_mm(512);

    mode_k<<<1, blk, 0, stream>>>((const unsigned int*)mask, 2048, w_mode, w_scal);
    wt_t_k<<<dim3(16, 16, 7), blk, 0, stream>>>(fa_w, pl_w2, q_w, sa_w, k_w, v_w, out_w, WT);
    front_transpose_k<<<g_tr, blk, 0, stream>>>(front_feat, H0);
    // E_pre = front_flat @ fa_w + fa_b (bf16)
    mm_k<1><<<g_mm, blk, 0, stream>>>(H0, Wfa, fa_b, nullptr, H5, nullptr, nullptr, nullptr);
    ln_bf_k<<<BT_, blk, 0, stream>>>(H5, fa_g, fa_lb, H1);
    // PLH
    plh_k<<<dim3(BT_, 2), blk, 0, stream>>>(plucker, pl_w1, pl_b1, H2);
    // CTX = PLH @ pl_w2 + pl_b2 + E (bf16)
    mm_k<2><<<g_mm, blk, 0, stream>>>(H2, Wpl2, pl_b2, H1, H6, nullptr, nullptr, nullptr);
    // sigma + dustbin heads
    head_k<<<BT_ / 4, blk, 0, stream>>>(H6, sig_w, sig_b, db_w, db_b, w_sigma, w_db);
    // Q (bf16, pre-scaled by COMPAT*INVLN2)
    mm_k<4><<<g_mm, blk, 0, stream>>>(H1, Wq, q_b, nullptr, H2, nullptr, nullptr, nullptr);
    // SAT -> bf16
    cvt_k<<<(BT_ * D_ / 8 + 255) / 256, blk, 0, stream>>>(sat_tokens, H5, BT_ * D_ / 8);
    // SE_pre = sat @ sa_w + sa_b (bf16)
    mm_k<1><<<g_mm, blk, 0, stream>>>(H5, Wsa, sa_b, nullptr, H6, nullptr, nullptr, nullptr);
    ln_bf_k<<<BT_, blk, 0, stream>>>(H6, sa_g, sa_lb, H3);
    // K (bf16) + Vt (bf16 transposed) fused dual-GEMM
    mm2_k<<<g_mm, blk, 0, stream>>>(H3, Wk, Wv, k_b, v_b, H1, H4);
    // attention (512-thread blocks, 2/CU)
    attn_k<<<dim3(512), dim3(512), 0, stream>>>(
        H2, H1, H4, w_sigma, w_db, bev_xy, sat_xy, mask, w_mode, H0, w_dbp);
    // confidence (needed by fused RF epilogue)
    conf_k<<<BT_ / 256, blk, 0, stream>>>(w_dbp, mask, w_mode, outc, w_scal);
    // RF = read @ out_w + out_b, fused transpose + out0/out1 epilogue
    mm_k<5><<<g_mm, blk, 0, stream>>>(H0, Wo, out_b, nullptr, out0, front_feat, outc, out1);
    loss_k<<<1, 1, 0, stream>>>(w_scal, outl);
}

// Round 6
// 194.676 us; speedup vs baseline: 4.8300x; 1.0894x over previous
//
#include <hip/hip_runtime.h>

typedef unsigned short u16;
typedef __attribute__((ext_vector_type(8))) short short8;   // 8 bf16 = 4 VGPR
typedef __attribute__((ext_vector_type(4))) float f32x4;    // MFMA acc

// Problem constants
constexpr int B_  = 8;
constexpr int C_  = 512;
constexpr int T_  = 1024;   // H*W
constexpr int S_  = 1024;
constexpr int D_  = 512;
constexpr int NH_ = 8;
constexpr int BT_ = B_ * T_;   // 8192
constexpr float INVLN2 = 1.44269504088896340736f;
constexpr float QSCALE2 = 0.0125f * INVLN2;   // COMPAT/sqrt(HD) / ln2

// single-instruction f32x2 -> packed bf16x2 (RNE)
__device__ __forceinline__ unsigned pack2(float lo, float hi) {
    unsigned r;
    asm("v_cvt_pk_bf16_f32 %0, %1, %2" : "=v"(r) : "v"(lo), "v"(hi));
    return r;
}
__device__ __forceinline__ u16 f2bf(float x) {
    return (u16)pack2(x, x);
}
__device__ __forceinline__ float bf2f(u16 h) {
    union { unsigned u; float f; } v; v.u = ((unsigned)h) << 16;
    return v.f;
}
__device__ __forceinline__ float fexp2(float x) {   // 2^x
    float r;
    asm("v_exp_f32 %0, %1" : "=v"(r) : "v"(x));
    return r;
}

// async global->LDS 16B
typedef __attribute__((address_space(3))) unsigned int lds_u32;
typedef const __attribute__((address_space(1))) unsigned int glob_u32;
__device__ __forceinline__ void g2l16(void* l, const void* g) {
    __builtin_amdgcn_global_load_lds((glob_u32*)g, (lds_u32*)l, 16, 0, 0);
}

// ---------------------------------------------------------------------------
// mask mode detect (int32 / f32 / bytes)
__device__ __forceinline__ int is_valid(const void* mask, int mode, int idx) {
    if (mode == 0) return ((const int*)mask)[idx] != 0;
    if (mode == 1) return ((const float*)mask)[idx] != 0.0f;
    return ((const unsigned char*)mask)[idx] != 0;
}

// ---------------------------------------------------------------------------
// prep_k: merged mode-detect + 7x weight transpose/convert + front transpose
// + sat f32->bf16 + plucker MLP hidden. One launch, block ranges.
__global__ __launch_bounds__(256) void prep_k(
    const float* __restrict__ ff, const float* __restrict__ sat,
    const float* __restrict__ pl,
    const float* a0, const float* a1, const float* a2, const float* a3,
    const float* a4, const float* a5, const float* a6, u16* __restrict__ WT,
    u16* __restrict__ ffb, u16* __restrict__ satb,
    const float* __restrict__ plw1, const float* __restrict__ plb1,
    u16* __restrict__ plh,
    const unsigned* __restrict__ maskw, int* __restrict__ mode,
    float* __restrict__ scal) {
    __shared__ float tile[32][33];
    int blk = blockIdx.x, tid = threadIdx.x;
    if (blk < 4096) {                       // front_feat (B,C,T) -> (B*T,C) bf16
        int t0 = (blk & 31) * 32, c0 = ((blk >> 5) & 15) * 32, b = blk >> 9;
        int tx = tid & 31, ty = tid >> 5;
        const float* ip = ff + (size_t)b * C_ * T_;
        for (int i = ty; i < 32; i += 8)
            tile[i][tx] = ip[(size_t)(c0 + i) * T_ + t0 + tx];
        __syncthreads();
        u16* op = ffb + (size_t)b * T_ * C_;
        for (int i = ty; i < 32; i += 8)
            op[(size_t)(t0 + i) * C_ + c0 + tx] = f2bf(tile[tx][i]);
    } else if (blk < 5888) {                // weight W[k][n] -> Wt[n][k] bf16
        int idx = blk - 4096;
        const float* srcs[7] = {a0, a1, a2, a3, a4, a5, a6};
        int z = idx >> 8;
        const float* src = srcs[z];
        u16* d = WT + (size_t)z * 512 * 512;
        int k0 = (idx & 15) * 32, n0 = ((idx >> 4) & 15) * 32;
        int tx = tid & 31, ty = tid >> 5;
        for (int i = ty; i < 32; i += 8)
            tile[i][tx] = src[(size_t)(k0 + i) * 512 + n0 + tx];
        __syncthreads();
        for (int i = ty; i < 32; i += 8)
            d[(size_t)(n0 + i) * 512 + k0 + tx] = f2bf(tile[tx][i]);
    } else if (blk < 7936) {                // sat f32 -> bf16 (x8 per thread)
        int i = (blk - 5888) * 256 + tid;
        const float4* p = (const float4*)(sat + (size_t)i * 8);
        float4 a = p[0], b = p[1];
        uint4 o;
        o.x = pack2(a.x, a.y); o.y = pack2(a.z, a.w);
        o.z = pack2(b.x, b.y); o.w = pack2(b.z, b.w);
        *(uint4*)(satb + (size_t)i * 8) = o;
    } else if (blk < 9984) {                // plucker hidden: silu MLP (K=6)
        int m = (blk - 7936) * 4 + (tid >> 6);
        int lane = tid & 63;
        float p6[6];
#pragma unroll
        for (int j = 0; j < 6; ++j) p6[j] = pl[(size_t)m * 6 + j];
        int n0 = lane * 8;
        float acc[8];
#pragma unroll
        for (int e = 0; e < 8; ++e) acc[e] = plb1[n0 + e];
#pragma unroll
        for (int j = 0; j < 6; ++j) {
            float4 wv0 = *(const float4*)(plw1 + j * D_ + n0);
            float4 wv1 = *(const float4*)(plw1 + j * D_ + n0 + 4);
            acc[0] += p6[j] * wv0.x; acc[1] += p6[j] * wv0.y;
            acc[2] += p6[j] * wv0.z; acc[3] += p6[j] * wv0.w;
            acc[4] += p6[j] * wv1.x; acc[5] += p6[j] * wv1.y;
            acc[6] += p6[j] * wv1.z; acc[7] += p6[j] * wv1.w;
        }
        uint4 o;
        float s0 = acc[0] / (1.0f + __expf(-acc[0]));
        float s1 = acc[1] / (1.0f + __expf(-acc[1]));
        float s2 = acc[2] / (1.0f + __expf(-acc[2]));
        float s3 = acc[3] / (1.0f + __expf(-acc[3]));
        float s4 = acc[4] / (1.0f + __expf(-acc[4]));
        float s5 = acc[5] / (1.0f + __expf(-acc[5]));
        float s6 = acc[6] / (1.0f + __expf(-acc[6]));
        float s7 = acc[7] / (1.0f + __expf(-acc[7]));
        o.x = pack2(s0, s1); o.y = pack2(s2, s3);
        o.z = pack2(s4, s5); o.w = pack2(s6, s7);
        *(uint4*)(plh + (size_t)m * D_ + n0) = o;
    } else {                                // mode detect + zero accumulators
        __shared__ int bad_i, bad_f;
        if (tid == 0) { bad_i = 0; bad_f = 0; }
        __syncthreads();
        for (int i = tid; i < 2048; i += 256) {
            unsigned v = maskw[i];
            if (v > 1u) bad_i = 1;
            if (v != 0u && v != 0x3f800000u) bad_f = 1;
        }
        __syncthreads();
        if (tid == 0) {
            *mode = (!bad_i) ? 0 : ((!bad_f) ? 1 : 2);
            scal[0] = 0.0f; scal[1] = 0.0f;
        }
    }
}

// ---------------------------------------------------------------------------
// Dual independent bf16 GEMMs in one launch (E-pre and SAT-pre).
// Tile 128x64, BK=64, global_load_lds staged, double-buffered. bf16 out.
__global__ __launch_bounds__(256) void mm_pre_k(
    const u16* __restrict__ A0, const u16* __restrict__ B0,
    const float* __restrict__ bias0, u16* __restrict__ C0,
    const u16* __restrict__ A1, const u16* __restrict__ B1,
    const float* __restrict__ bias1, u16* __restrict__ C1) {
    __shared__ u16 As[2][8192];   // 16 KB each
    __shared__ u16 Bs[2][4096];   // 8 KB each
    int idx = blockIdx.x;
    int sel = idx >> 9;
    const u16* A = sel ? A1 : A0;
    const u16* Bt = sel ? B1 : B0;
    const float* bias = sel ? bias1 : bias0;
    u16* Cout = sel ? C1 : C0;
    int L = idx & 511;
    int tid = threadIdx.x, w = tid >> 6, l = tid & 63;
    int lr = l & 15, g = l >> 4;
    int W = (L & 7) * 64 + (L >> 3);
    int m0 = (W >> 3) * 128, n0 = (W & 7) * 64;
    int wr = w >> 1, wc = w & 1;

    f32x4 acc[4][2] = {};

    auto stage = [&](int buf, int k0) {
#pragma unroll
        for (int j = 0; j < 4; ++j) {
            int i = tid + 256 * j;
            int gg = i >> 7, row = i & 127;
            g2l16((char*)As[buf] + (size_t)i * 16,
                  A + (size_t)(m0 + row) * 512 + k0 + gg * 8);
        }
#pragma unroll
        for (int j = 0; j < 2; ++j) {
            int i = tid + 256 * j;
            int gg = i >> 6, n = i & 63;
            g2l16((char*)Bs[buf] + (size_t)i * 16,
                  Bt + (size_t)(n0 + n) * 512 + k0 + gg * 8);
        }
    };

    stage(0, 0);
    __syncthreads();
    int cur = 0;
    for (int t = 0; t < 8; ++t) {
        if (t < 7) stage(cur ^ 1, (t + 1) * 64);
        const char* Ab = (const char*)As[cur];
        const char* Bb = (const char*)Bs[cur];
#pragma unroll
        for (int kk = 0; kk < 2; ++kk) {
            short8 af[4], bf[2];
#pragma unroll
            for (int m = 0; m < 4; ++m)
                af[m] = *(const short8*)(Ab + (kk * 4 + g) * 2048 +
                                         (wr * 64 + m * 16 + lr) * 16);
#pragma unroll
            for (int n = 0; n < 2; ++n)
                bf[n] = *(const short8*)(Bb + (kk * 4 + g) * 1024 +
                                         (wc * 32 + n * 16 + lr) * 16);
            __builtin_amdgcn_s_setprio(1);
#pragma unroll
            for (int m = 0; m < 4; ++m)
#pragma unroll
                for (int n = 0; n < 2; ++n)
                    acc[m][n] = __builtin_amdgcn_mfma_f32_16x16x32_bf16(
                        af[m], bf[n], acc[m][n], 0, 0, 0);
            __builtin_amdgcn_s_setprio(0);
        }
        __syncthreads();
        cur ^= 1;
    }

    float bs[2] = {bias[n0 + wc * 32 + lr], bias[n0 + wc * 32 + 16 + lr]};
#pragma unroll
    for (int m = 0; m < 4; ++m)
#pragma unroll
        for (int n = 0; n < 2; ++n) {
            int R0  = m0 + wr * 64 + m * 16 + 4 * g;
            int col = n0 + wc * 32 + n * 16 + lr;
#pragma unroll
            for (int j = 0; j < 4; ++j)
                Cout[(size_t)(R0 + j) * 512 + col] = f2bf(acc[m][n][j] + bs[n]);
        }
}

// ---------------------------------------------------------------------------
// Merged LayerNorms (E and SE). grid 16384: sel = blk>>13.
__global__ __launch_bounds__(256) void ln2_k(
    const u16* __restrict__ X0, const float* __restrict__ g0,
    const float* __restrict__ b0, u16* __restrict__ O0,
    const u16* __restrict__ X1, const float* __restrict__ g1,
    const float* __restrict__ b1, u16* __restrict__ O1) {
    int sel = blockIdx.x >> 13;
    int row = blockIdx.x & 8191;
    const u16* X = sel ? X1 : X0;
    const float* gw = sel ? g1 : g0;
    const float* bw = sel ? b1 : b0;
    u16* out = sel ? O1 : O0;
    int tid = threadIdx.x;
    const unsigned* xr = (const unsigned*)(X + (size_t)row * D_);
    unsigned u = xr[tid];
    float x0 = bf2f((u16)(u & 0xffff)), x1 = bf2f((u16)(u >> 16));
    float s = x0 + x1, sq = x0 * x0 + x1 * x1;
    __shared__ float rs[4], rq[4];
    for (int o = 32; o; o >>= 1) { s += __shfl_down(s, o); sq += __shfl_down(sq, o); }
    int wid = tid >> 6, lane = tid & 63;
    if (lane == 0) { rs[wid] = s; rq[wid] = sq; }
    __syncthreads();
    if (tid == 0) {
        float ts = 0, tq = 0;
        for (int w = 0; w < 4; ++w) { ts += rs[w]; tq += rq[w]; }
        rs[0] = ts; rq[0] = tq;
    }
    __syncthreads();
    float mean = rs[0] * (1.0f / D_);
    float var  = rq[0] * (1.0f / D_) - mean * mean;
    float r = rsqrtf(var + 1e-5f);
    float2 g2 = *(const float2*)(gw + 2 * tid);
    float2 b2 = *(const float2*)(bw + 2 * tid);
    float y0 = (x0 - mean) * r * g2.x + b2.x;
    float y1 = (x1 - mean) * r * g2.y + b2.y;
    ((unsigned*)(out + (size_t)row * D_))[tid] = pack2(y0, y1);
}

// ---------------------------------------------------------------------------
// Merged Q + CTX + KV GEMMs. grid 1536: sel = idx/512.
// sel 0: Q = E@Wq * QSCALE2 (bf16); sel 1: CTX = PLH@Wpl2 + E (bf16);
// sel 2: K = SE@Wk (bf16 row-major) and Vt = SE@Wv (bf16 transposed scatter).
__global__ __launch_bounds__(256) void qcv_k(
    const u16* __restrict__ E, const u16* __restrict__ PLH,
    const u16* __restrict__ SE,
    const u16* __restrict__ Wq, const u16* __restrict__ Wpl2,
    const u16* __restrict__ Wk, const u16* __restrict__ Wv,
    const float* __restrict__ qb, const float* __restrict__ plb2,
    const float* __restrict__ kb, const float* __restrict__ vb,
    u16* __restrict__ Qo, u16* __restrict__ CTXo,
    u16* __restrict__ Ko, u16* __restrict__ Vo) {
    __shared__ u16 As[2][8192];
    __shared__ u16 B1s[2][4096];
    __shared__ u16 B2s[2][4096];
    int idx = blockIdx.x;
    int sel = idx >> 9;
    int L = idx & 511;
    int tid = threadIdx.x, w = tid >> 6, l = tid & 63;
    int lr = l & 15, g = l >> 4;
    int W = (L & 7) * 64 + (L >> 3);
    int m0 = (W >> 3) * 128, n0 = (W & 7) * 64;
    int wr = w >> 1, wc = w & 1;

    const u16* A  = (sel == 0) ? E : (sel == 1) ? PLH : SE;
    const u16* Bt = (sel == 0) ? Wq : (sel == 1) ? Wpl2 : Wk;

    f32x4 acc[4][2] = {};
    f32x4 av[4][2] = {};

    auto stage = [&](int buf, int k0) {
#pragma unroll
        for (int j = 0; j < 4; ++j) {
            int i = tid + 256 * j;
            int gg = i >> 7, row = i & 127;
            g2l16((char*)As[buf] + (size_t)i * 16,
                  A + (size_t)(m0 + row) * 512 + k0 + gg * 8);
        }
#pragma unroll
        for (int j = 0; j < 2; ++j) {
            int i = tid + 256 * j;
            int gg = i >> 6, n = i & 63;
            g2l16((char*)B1s[buf] + (size_t)i * 16,
                  Bt + (size_t)(n0 + n) * 512 + k0 + gg * 8);
            if (sel == 2)
                g2l16((char*)B2s[buf] + (size_t)i * 16,
                      Wv + (size_t)(n0 + n) * 512 + k0 + gg * 8);
        }
    };

    stage(0, 0);
    __syncthreads();
    int cur = 0;
    for (int t = 0; t < 8; ++t) {
        if (t < 7) stage(cur ^ 1, (t + 1) * 64);
        const char* Ab  = (const char*)As[cur];
        const char* B1b = (const char*)B1s[cur];
        const char* B2b = (const char*)B2s[cur];
#pragma unroll
        for (int kk = 0; kk < 2; ++kk) {
            short8 af[4], b1f[2], b2f[2];
#pragma unroll
            for (int m = 0; m < 4; ++m)
                af[m] = *(const short8*)(Ab + (kk * 4 + g) * 2048 +
                                         (wr * 64 + m * 16 + lr) * 16);
#pragma unroll
            for (int n = 0; n < 2; ++n) {
                b1f[n] = *(const short8*)(B1b + (kk * 4 + g) * 1024 +
                                          (wc * 32 + n * 16 + lr) * 16);
                if (sel == 2)
                    b2f[n] = *(const short8*)(B2b + (kk * 4 + g) * 1024 +
                                              (wc * 32 + n * 16 + lr) * 16);
            }
            __builtin_amdgcn_s_setprio(1);
#pragma unroll
            for (int m = 0; m < 4; ++m)
#pragma unroll
                for (int n = 0; n < 2; ++n) {
                    acc[m][n] = __builtin_amdgcn_mfma_f32_16x16x32_bf16(
                        af[m], b1f[n], acc[m][n], 0, 0, 0);
                    if (sel == 2)
                        av[m][n] = __builtin_amdgcn_mfma_f32_16x16x32_bf16(
                            af[m], b2f[n], av[m][n], 0, 0, 0);
                }
            __builtin_amdgcn_s_setprio(0);
        }
        __syncthreads();
        cur ^= 1;
    }

    const float* bias1 = (sel == 0) ? qb : (sel == 1) ? plb2 : kb;
    float bs[2] = {bias1[n0 + wc * 32 + lr], bias1[n0 + wc * 32 + 16 + lr]};
    if (sel == 0) {
#pragma unroll
        for (int m = 0; m < 4; ++m)
#pragma unroll
            for (int n = 0; n < 2; ++n) {
                int R0 = m0 + wr * 64 + m * 16 + 4 * g;
                int col = n0 + wc * 32 + n * 16 + lr;
#pragma unroll
                for (int j = 0; j < 4; ++j)
                    Qo[(size_t)(R0 + j) * 512 + col] =
                        f2bf((acc[m][n][j] + bs[n]) * QSCALE2);
            }
    } else if (sel == 1) {
#pragma unroll
        for (int m = 0; m < 4; ++m)
#pragma unroll
            for (int n = 0; n < 2; ++n) {
                int R0 = m0 + wr * 64 + m * 16 + 4 * g;
                int col = n0 + wc * 32 + n * 16 + lr;
#pragma unroll
                for (int j = 0; j < 4; ++j) {
                    float v = acc[m][n][j] + bs[n] +
                              bf2f(E[(size_t)(R0 + j) * 512 + col]);
                    CTXo[(size_t)(R0 + j) * 512 + col] = f2bf(v);
                }
            }
    } else {
        float vbs[2] = {vb[n0 + wc * 32 + lr], vb[n0 + wc * 32 + 16 + lr]};
#pragma unroll
        for (int m = 0; m < 4; ++m)
#pragma unroll
            for (int n = 0; n < 2; ++n) {
                int R0 = m0 + wr * 64 + m * 16 + 4 * g;
                int col = n0 + wc * 32 + n * 16 + lr;
#pragma unroll
                for (int j = 0; j < 4; ++j)
                    Ko[(size_t)(R0 + j) * 512 + col] = f2bf(acc[m][n][j] + bs[n]);
                int bb = R0 >> 10, ss = R0 & 1023, hh = col >> 6, dd = col & 63;
                uint2 pk;
                pk.x = pack2(av[m][n][0] + vbs[n], av[m][n][1] + vbs[n]);
                pk.y = pack2(av[m][n][2] + vbs[n], av[m][n][3] + vbs[n]);
                u16* dst = Vo + ((size_t)(bb * 8 + hh) * 64 + dd) * 1024 + ss;
                *(uint2*)dst = pk;
            }
    }
}

// ---------------------------------------------------------------------------
// fused sigma + dustbin heads from bf16 CTX. One wave per row.
__global__ __launch_bounds__(256) void head_k(const u16* __restrict__ ctx,
        const float* __restrict__ sw, const float* __restrict__ sbb,
        const float* __restrict__ dw, const float* __restrict__ dbb,
        float* __restrict__ sig, float* __restrict__ dbo) {
    int w = threadIdx.x >> 6, lane = threadIdx.x & 63;
    int row = blockIdx.x * 4 + w;
    const u16* xr = ctx + (size_t)row * D_;
    short8 xv = *(const short8*)(xr + lane * 8);
    float xs[8];
#pragma unroll
    for (int i = 0; i < 8; ++i) xs[i] = bf2f((u16)xv[i]);
    float4 wa = *(const float4*)(sw + lane * 8);
    float4 wb = *(const float4*)(sw + lane * 8 + 4);
    float sacc = xs[0] * wa.x + xs[1] * wa.y + xs[2] * wa.z + xs[3] * wa.w +
                 xs[4] * wb.x + xs[5] * wb.y + xs[6] * wb.z + xs[7] * wb.w;
    float d_[8] = {};
    const float* dr = dw + (size_t)lane * 8 * NH_;
#pragma unroll
    for (int i = 0; i < 8; ++i)
#pragma unroll
        for (int hh = 0; hh < 8; ++hh) d_[hh] += xs[i] * dr[i * NH_ + hh];
    for (int o = 32; o; o >>= 1) {
        sacc += __shfl_down(sacc, o);
#pragma unroll
        for (int hh = 0; hh < 8; ++hh) d_[hh] += __shfl_down(d_[hh], o);
    }
    if (lane == 0) {
        float z = sacc + sbb[0];
        sig[row] = 0.03f + 0.32f / (1.0f + __expf(-z));
        float* dd = dbo + (size_t)row * NH_;
#pragma unroll
        for (int hh = 0; hh < 8; ++hh) dd[hh] = d_[hh] + dbb[hh];
    }
}

// ---------------------------------------------------------------------------
// Staged MFMA flash attention, KVBLK=64, exp2 softmax, 512-thread blocks.
// NEW: K rows staged in bit-permuted order sigma so QK^T's C-layout lands
// exactly in PV's B-fragment layout -> P never leaves registers (no P-LDS).
// sigma: dest position r [b5 b4 b3 b2 b1 b0] holds key s' = [b5 b3 b2 b4 b1 b0].
// Softmax is order-agnostic; V stays in natural s order (P's k-order is
// natural s'). LDS: 44 KB.
__global__ __launch_bounds__(512) void attn_k(
    const u16* __restrict__ Q, const u16* __restrict__ K,
    const u16* __restrict__ Vt, const float* __restrict__ sig,
    const float* __restrict__ dbl, const float* __restrict__ bev,
    const float* __restrict__ sxy, const void* __restrict__ mask,
    const int* __restrict__ mode, u16* __restrict__ OUT,
    float* __restrict__ dbp) {
    int L = blockIdx.x;
    int W = (L & 7) * 64 + (L >> 3);   // XCD swizzle: XCD x owns batch x
    int b = W >> 6, h = (W >> 3) & 7, tblk = W & 7;
    int tid = threadIdx.x, w = tid >> 6, l = tid & 63;
    int lr = l & 15, g = l >> 4;

    __shared__ u16 Kbuf[2][4096];      // 8 KB each: slab gd(0..7) x 64 pos x 16B
    __shared__ u16 Vbuf[2][4096];      // 8 KB each: slab gs(0..7) x 64 d x 16B
    __shared__ float2 SXY[1024];       // (-2x, -2y)
    __shared__ float  SZ[1024];        // x^2+y^2

    const float2* xp = (const float2*)(sxy + (size_t)b * S_ * 2);
#pragma unroll
    for (int j = 0; j < 2; ++j) {
        int idx = tid + 512 * j;
        float2 v = xp[idx];
        SXY[idx] = make_float2(-2.0f * v.x, -2.0f * v.y);
        SZ[idx] = v.x * v.x + v.y * v.y;
    }

    int trow = b * T_ + tblk * 128 + w * 16 + lr;
    float s_ = sig[trow];
    float bx = bev[(size_t)trow * 2], by = bev[(size_t)trow * 2 + 1];
    float dbv2 = dbl[(size_t)trow * NH_ + h] * INVLN2;
    int md = *mode;
    bool vld = is_valid(mask, md, trow) != 0;
    float grow  = vld ? (-11.5415603271117f / fmaxf(s_ * s_, 1e-6f)) : 0.0f;
    float Abase = vld ? grow * (bx * bx + by * by) : -10000.0f;

    const u16* qp = Q + (size_t)trow * 512 + h * 64 + g * 8;
    short8 q0 = *(const short8*)qp;
    short8 q1 = *(const short8*)(qp + 32);
    if (!vld) { q0 = short8{}; q1 = short8{}; }

    const u16* Kp = K + (size_t)b * S_ * 512 + h * 64;
    const u16* Vp = Vt + (size_t)(b * 8 + h) * 64 * 1024;

    // permuted K source row for this thread's staging slot
    int rpos = tid & 63;
    int sK = ((rpos >> 5) & 1) * 32 + ((rpos >> 2) & 3) * 8 +
             ((rpos >> 4) & 1) * 4 + (rpos & 3);
    int gK = tid >> 6;      // K d-granule = wave id
    int gV = tid >> 6;      // V s-granule
    int dV = tid & 63;

    auto stageKV = [&](int buf, int s0) {
        g2l16((char*)Kbuf[buf] + (size_t)tid * 16,
              Kp + (size_t)(s0 + sK) * 512 + gK * 8);
        g2l16((char*)Vbuf[buf] + (size_t)tid * 16,
              Vp + (size_t)dV * 1024 + s0 + gV * 8);
    };

    float m_st = dbv2, l_st = 1.0f;
    f32x4 o0 = {}, o1 = {}, o2 = {}, o3 = {};

    stageKV(0, 0);
    __syncthreads();
    int cur = 0;
    for (int c = 0; c < 16; ++c) {
        int s0c = c * 64;
        if (c < 15) stageKV(cur ^ 1, s0c + 64);

        const char* Kc = (const char*)Kbuf[cur];
        const char* Vc = (const char*)Vbuf[cur];

        // QK^T: 4 position-subtiles x 2 k-halves
        f32x4 p[4];
        f32x4 z4 = {};
        __builtin_amdgcn_s_setprio(1);
#pragma unroll
        for (int sub = 0; sub < 4; ++sub) {
            short8 kf0 = *(const short8*)(Kc + (0 + g) * 1024 + (sub * 16 + lr) * 16);
            short8 kf1 = *(const short8*)(Kc + (4 + g) * 1024 + (sub * 16 + lr) * 16);
            p[sub] = __builtin_amdgcn_mfma_f32_16x16x32_bf16(kf0, q0, z4, 0, 0, 0);
            p[sub] = __builtin_amdgcn_mfma_f32_16x16x32_bf16(kf1, q1, p[sub], 0, 0, 0);
        }
        __builtin_amdgcn_s_setprio(0);

        // logits (log2 domain). Slot (sub,g,j) holds actual key
        // s' = 32*(sub>>1) + 8g + 4*(sub&1) + j  -> 4 consecutive per sub.
        float pe[16];
        float cmax = -3.0e38f;
#pragma unroll
        for (int sub = 0; sub < 4; ++sub) {
            int sl = s0c + ((sub & 2) << 4) + 8 * g + ((sub & 1) << 2);
            float4 xy01 = *(const float4*)&SXY[sl];
            float4 xy23 = *(const float4*)&SXY[sl + 2];
            float4 zz   = *(const float4*)&SZ[sl];
            float X[4] = {xy01.x, xy01.z, xy23.x, xy23.z};
            float Y[4] = {xy01.y, xy01.w, xy23.y, xy23.w};
            float Z[4] = {zz.x, zz.y, zz.z, zz.w};
#pragma unroll
            for (int i2 = 0; i2 < 4; ++i2) {
                float wg = fmaf(bx, X[i2], fmaf(by, Y[i2], Z[i2]));
                float lg = fmaf(grow, wg, p[sub][i2] + Abase);
                pe[sub * 4 + i2] = lg;
                cmax = fmaxf(cmax, lg);
            }
        }
        cmax = fmaxf(cmax, __shfl_xor(cmax, 16));
        cmax = fmaxf(cmax, __shfl_xor(cmax, 32));

        if (!__all(cmax <= m_st + 11.5f)) {      // defer-max (log2 domain)
            float m_new = fmaxf(m_st, cmax);
            float scl = fexp2(m_st - m_new);
            l_st *= scl;
            o0 *= scl; o1 *= scl; o2 *= scl; o3 *= scl;
            m_st = m_new;
        }
        float ps = 0.0f;
#pragma unroll
        for (int r = 0; r < 16; ++r) { pe[r] = fexp2(pe[r] - m_st); ps += pe[r]; }
        ps += __shfl_xor(ps, 16);
        ps += __shfl_xor(ps, 32);
        l_st += ps;

        // P -> B-fragments entirely in-register: lane g holds s' = 8g..8g+7
        // (pe[0..7]) and 32+8g..32+8g+7 (pe[8..15]) in natural order.
        union { uint4 u; short8 s8; } pf0, pf1;
        pf0.u.x = pack2(pe[0], pe[1]);  pf0.u.y = pack2(pe[2], pe[3]);
        pf0.u.z = pack2(pe[4], pe[5]);  pf0.u.w = pack2(pe[6], pe[7]);
        pf1.u.x = pack2(pe[8], pe[9]);  pf1.u.y = pack2(pe[10], pe[11]);
        pf1.u.z = pack2(pe[12], pe[13]); pf1.u.w = pack2(pe[14], pe[15]);

        // PV: 4 d-frags x 2 k-chunks
        __builtin_amdgcn_s_setprio(1);
        short8 vf;
        vf = *(const short8*)(Vc + (0 + g) * 1024 + (0 * 16 + lr) * 16);
        o0 = __builtin_amdgcn_mfma_f32_16x16x32_bf16(vf, pf0.s8, o0, 0, 0, 0);
        vf = *(const short8*)(Vc + (4 + g) * 1024 + (0 * 16 + lr) * 16);
        o0 = __builtin_amdgcn_mfma_f32_16x16x32_bf16(vf, pf1.s8, o0, 0, 0, 0);
        vf = *(const short8*)(Vc + (0 + g) * 1024 + (1 * 16 + lr) * 16);
        o1 = __builtin_amdgcn_mfma_f32_16x16x32_bf16(vf, pf0.s8, o1, 0, 0, 0);
        vf = *(const short8*)(Vc + (4 + g) * 1024 + (1 * 16 + lr) * 16);
        o1 = __builtin_amdgcn_mfma_f32_16x16x32_bf16(vf, pf1.s8, o1, 0, 0, 0);
        vf = *(const short8*)(Vc + (0 + g) * 1024 + (2 * 16 + lr) * 16);
        o2 = __builtin_amdgcn_mfma_f32_16x16x32_bf16(vf, pf0.s8, o2, 0, 0, 0);
        vf = *(const short8*)(Vc + (4 + g) * 1024 + (2 * 16 + lr) * 16);
        o2 = __builtin_amdgcn_mfma_f32_16x16x32_bf16(vf, pf1.s8, o2, 0, 0, 0);
        vf = *(const short8*)(Vc + (0 + g) * 1024 + (3 * 16 + lr) * 16);
        o3 = __builtin_amdgcn_mfma_f32_16x16x32_bf16(vf, pf0.s8, o3, 0, 0, 0);
        vf = *(const short8*)(Vc + (4 + g) * 1024 + (3 * 16 + lr) * 16);
        o3 = __builtin_amdgcn_mfma_f32_16x16x32_bf16(vf, pf1.s8, o3, 0, 0, 0);
        __builtin_amdgcn_s_setprio(0);

        __syncthreads();
        cur ^= 1;
    }

    float inv = 1.0f / l_st;
    u16* ob = OUT + (size_t)trow * 512 + h * 64;
    {
        uint2 pk;
        pk.x = pack2(o0[0] * inv, o0[1] * inv); pk.y = pack2(o0[2] * inv, o0[3] * inv);
        *(uint2*)(ob + 0 * 16 + 4 * g) = pk;
        pk.x = pack2(o1[0] * inv, o1[1] * inv); pk.y = pack2(o1[2] * inv, o1[3] * inv);
        *(uint2*)(ob + 1 * 16 + 4 * g) = pk;
        pk.x = pack2(o2[0] * inv, o2[1] * inv); pk.y = pack2(o2[2] * inv, o2[3] * inv);
        *(uint2*)(ob + 2 * 16 + 4 * g) = pk;
        pk.x = pack2(o3[0] * inv, o3[1] * inv); pk.y = pack2(o3[2] * inv, o3[3] * inv);
        *(uint2*)(ob + 3 * 16 + 4 * g) = pk;
    }
    if (g == 0) dbp[(size_t)trow * NH_ + h] = fexp2(dbv2 - m_st) * inv;
}

// ---------------------------------------------------------------------------
// confidence + invalid-loss partials
__global__ __launch_bounds__(256) void conf_k(const float* __restrict__ dbp,
                                              const void* __restrict__ mask,
                                              const int* __restrict__ mode,
                                              float* __restrict__ confout,
                                              float* __restrict__ scal) {
    int row = blockIdx.x * 256 + threadIdx.x;
    const float* dr = dbp + (size_t)row * NH_;
    float s = 0;
#pragma unroll
    for (int h = 0; h < 8; ++h) s += dr[h];
    float cf = 1.0f - s * (1.0f / NH_);
    confout[row] = cf;
    int md = *mode;
    float inv = is_valid(mask, md, row) ? 0.0f : 1.0f;
    float a = cf * inv, bs = inv;
    __shared__ float ra[4], rb[4];
    for (int o = 32; o; o >>= 1) { a += __shfl_down(a, o); bs += __shfl_down(bs, o); }
    int wid = threadIdx.x >> 6, lane = threadIdx.x & 63;
    if (lane == 0) { ra[wid] = a; rb[wid] = bs; }
    __syncthreads();
    if (threadIdx.x == 0) {
        float ta = 0, tb = 0;
        for (int w = 0; w < 4; ++w) { ta += ra[w]; tb += rb[w]; }
        atomicAdd(&scal[0], ta);
        atomicAdd(&scal[1], tb);
    }
}

// ---------------------------------------------------------------------------
// RF GEMM with fused transposed epilogue: out1 = rf, out0 = ff + conf*rf.
__global__ __launch_bounds__(256) void mm_rf_k(const u16* __restrict__ A,
                                               const u16* __restrict__ Bt,
                                               const float* __restrict__ bias,
                                               float* __restrict__ out0,
                                               const float* __restrict__ ffp,
                                               const float* __restrict__ confp,
                                               float* __restrict__ out1p) {
    __shared__ u16 As[2][8192];
    __shared__ u16 Bs[2][4096];
    int tid = threadIdx.x, w = tid >> 6, l = tid & 63;
    int lr = l & 15, g = l >> 4;
    int L = blockIdx.x;
    int W = (L & 7) * 64 + (L >> 3);
    int m0 = (W >> 3) * 128, n0 = (W & 7) * 64;
    int wr = w >> 1, wc = w & 1;

    f32x4 acc[4][2] = {};

    auto stage = [&](int buf, int k0) {
#pragma unroll
        for (int j = 0; j < 4; ++j) {
            int i = tid + 256 * j;
            int gg = i >> 7, row = i & 127;
            g2l16((char*)As[buf] + (size_t)i * 16,
                  A + (size_t)(m0 + row) * 512 + k0 + gg * 8);
        }
#pragma unroll
        for (int j = 0; j < 2; ++j) {
            int i = tid + 256 * j;
            int gg = i >> 6, n = i & 63;
            g2l16((char*)Bs[buf] + (size_t)i * 16,
                  Bt + (size_t)(n0 + n) * 512 + k0 + gg * 8);
        }
    };

    stage(0, 0);
    __syncthreads();
    int cur = 0;
    for (int t = 0; t < 8; ++t) {
        if (t < 7) stage(cur ^ 1, (t + 1) * 64);
        const char* Ab = (const char*)As[cur];
        const char* Bb = (const char*)Bs[cur];
#pragma unroll
        for (int kk = 0; kk < 2; ++kk) {
            short8 af[4], bf[2];
#pragma unroll
            for (int m = 0; m < 4; ++m)
                af[m] = *(const short8*)(Ab + (kk * 4 + g) * 2048 +
                                         (wr * 64 + m * 16 + lr) * 16);
#pragma unroll
            for (int n = 0; n < 2; ++n)
                bf[n] = *(const short8*)(Bb + (kk * 4 + g) * 1024 +
                                         (wc * 32 + n * 16 + lr) * 16);
            __builtin_amdgcn_s_setprio(1);
#pragma unroll
            for (int m = 0; m < 4; ++m)
#pragma unroll
                for (int n = 0; n < 2; ++n)
                    acc[m][n] = __builtin_amdgcn_mfma_f32_16x16x32_bf16(
                        af[m], bf[n], acc[m][n], 0, 0, 0);
            __builtin_amdgcn_s_setprio(0);
        }
        __syncthreads();
        cur ^= 1;
    }

    float bs[2] = {bias[n0 + wc * 32 + lr], bias[n0 + wc * 32 + 16 + lr]};
#pragma unroll
    for (int m = 0; m < 4; ++m)
#pragma unroll
        for (int n = 0; n < 2; ++n) {
            int R0  = m0 + wr * 64 + m * 16 + 4 * g;
            int col = n0 + wc * 32 + n * 16 + lr;
            int bb = R0 >> 10, t0p = R0 & 1023;
            size_t base = (size_t)bb * C_ * T_ + (size_t)col * T_ + t0p;
            float4 rf;
            rf.x = acc[m][n][0] + bs[n]; rf.y = acc[m][n][1] + bs[n];
            rf.z = acc[m][n][2] + bs[n]; rf.w = acc[m][n][3] + bs[n];
            float4 ffv = *(const float4*)(ffp + base);
            float4 cfv = *(const float4*)(confp + bb * T_ + t0p);
            float4 o0v;
            o0v.x = ffv.x + cfv.x * rf.x; o0v.y = ffv.y + cfv.y * rf.y;
            o0v.z = ffv.z + cfv.z * rf.z; o0v.w = ffv.w + cfv.w * rf.w;
            *(float4*)(out1p + base) = rf;
            *(float4*)(out0 + base) = o0v;
        }
}

__global__ void loss_k(const float* __restrict__ scal, float* __restrict__ out) {
    out[0] = scal[0] / fmaxf(scal[1], 1.0f) * 0.05f;
}

// ---------------------------------------------------------------------------
extern "C" void kernel_launch(void* const* d_in, const int* in_sizes, int n_in,
                              void* d_out, int out_size, void* d_ws, size_t ws_size,
                              hipStream_t stream) {
    const float* front_feat = (const float*)d_in[0];
    const float* sat_tokens = (const float*)d_in[1];
    const float* sat_xy     = (const float*)d_in[2];
    const float* bev_xy     = (const float*)d_in[3];
    const void*  mask       = d_in[4];
    const float* plucker    = (const float*)d_in[5];
    const float* fa_w = (const float*)d_in[6];
    const float* fa_b = (const float*)d_in[7];
    const float* fa_g = (const float*)d_in[8];
    const float* fa_lb = (const float*)d_in[9];
    const float* sa_w = (const float*)d_in[10];
    const float* sa_b = (const float*)d_in[11];
    const float* sa_g = (const float*)d_in[12];
    const float* sa_lb = (const float*)d_in[13];
    const float* q_w = (const float*)d_in[14];
    const float* q_b = (const float*)d_in[15];
    const float* k_w = (const float*)d_in[16];
    const float* k_b = (const float*)d_in[17];
    const float* v_w = (const float*)d_in[18];
    const float* v_b = (const float*)d_in[19];
    const float* pl_w1 = (const float*)d_in[20];
    const float* pl_b1 = (const float*)d_in[21];
    const float* pl_w2 = (const float*)d_in[22];
    const float* pl_b2 = (const float*)d_in[23];
    const float* sig_w = (const float*)d_in[24];
    const float* sig_b = (const float*)d_in[25];
    const float* db_w = (const float*)d_in[26];
    const float* db_b = (const float*)d_in[27];
    const float* out_w = (const float*)d_in[28];
    const float* out_b = (const float*)d_in[29];

    char* w8 = (char*)d_ws;
    u16* H0 = (u16*)(w8);                        // 8 MB bf16 slots
    u16* H1 = (u16*)(w8 + 8388608ull * 1);
    u16* H2 = (u16*)(w8 + 8388608ull * 2);
    u16* H3 = (u16*)(w8 + 8388608ull * 3);
    u16* H4 = (u16*)(w8 + 8388608ull * 4);
    u16* H5 = (u16*)(w8 + 8388608ull * 5);
    u16* H6 = (u16*)(w8 + 8388608ull * 6);
    u16* WT = (u16*)(w8 + 8388608ull * 7);       // 7 x 0.5 MB
    char* sm = w8 + 8388608ull * 7 + 3670016ull;
    float* w_sigma = (float*)sm;
    float* w_db    = w_sigma + BT_;
    float* w_dbp   = w_db + (size_t)BT_ * NH_;
    float* w_scal  = w_dbp + (size_t)BT_ * NH_;
    int*   w_mode  = (int*)(w_scal + 2);

    u16* Wfa = WT;                 u16* Wpl2 = WT + 262144ull * 1;
    u16* Wq  = WT + 262144ull * 2; u16* Wsa  = WT + 262144ull * 3;
    u16* Wk  = WT + 262144ull * 4; u16* Wv   = WT + 262144ull * 5;
    u16* Wo  = WT + 262144ull * 6;

    float* out0 = (float*)d_out;
    float* out1 = out0 + (size_t)B_ * C_ * T_;
    float* outc = out1 + (size_t)B_ * C_ * T_;
    float* outl = outc + (size_t)B_ * T_;

    dim3 blk(256);

    // 1. prep: mode + weight transposes + front transpose (H0) + sat cvt (H5)
    //    + plucker hidden (H2)
    prep_k<<<dim3(9985), blk, 0, stream>>>(
        front_feat, sat_tokens, plucker,
        fa_w, pl_w2, q_w, sa_w, k_w, v_w, out_w, WT,
        H0, H5, pl_w1, pl_b1, H2,
        (const unsigned*)mask, w_mode, w_scal);
    // 2. E_pre (H0@Wfa -> H6) and SAT_pre (H5@Wsa -> H4) in one launch
    mm_pre_k<<<dim3(1024), blk, 0, stream>>>(H0, Wfa, fa_b, H6,
                                             H5, Wsa, sa_b, H4);
    // 3. both LayerNorms: LN(H6)->H1 (E), LN(H4)->H3 (SE)
    ln2_k<<<dim3(16384), blk, 0, stream>>>(H6, fa_g, fa_lb, H1,
                                           H4, sa_g, sa_lb, H3);
    // 4. Q (H1->H5), CTX (H2+H1->H6), K/Vt (H3->H0/H4) in one launch
    qcv_k<<<dim3(1536), blk, 0, stream>>>(H1, H2, H3,
                                          Wq, Wpl2, Wk, Wv,
                                          q_b, pl_b2, k_b, v_b,
                                          H5, H6, H0, H4);
    // 5. sigma + dustbin heads from CTX (H6)
    head_k<<<dim3(BT_ / 4), blk, 0, stream>>>(H6, sig_w, sig_b, db_w, db_b,
                                              w_sigma, w_db);
    // 6. attention: Q=H5, K=H0, Vt=H4 -> OUT=H2
    attn_k<<<dim3(512), dim3(512), 0, stream>>>(
        H5, H0, H4, w_sigma, w_db, bev_xy, sat_xy, mask, w_mode, H2, w_dbp);
    // 7. confidence
    conf_k<<<dim3(BT_ / 256), blk, 0, stream>>>(w_dbp, mask, w_mode, outc, w_scal);
    // 8. RF GEMM + fused transposed epilogue
    mm_rf_k<<<dim3(512), blk, 0, stream>>>(H2, Wo, out_b, out0,
                                           front_feat, outc, out1);
    // 9. loss scalar
    loss_k<<<1, 1, 0, stream>>>(w_scal, outl);
}